// Round 10
// baseline (366.489 us; speedup 1.0000x reference)
//
#include <hip/hip_runtime.h>
#include <hip/hip_fp16.h>

typedef __attribute__((ext_vector_type(8))) _Float16 half8;
typedef __attribute__((ext_vector_type(2))) _Float16 h2f;
typedef __attribute__((ext_vector_type(4))) float f32x4;

#define NP 1369
#define KP 1376          /* padded row stride: 43 tiles of 32 */
#define NKT 43
#define ROWS_A 15360     /* 768 sbk * 20 t  */
#define ROWS_D 14592     /* 768 sbk * 19 dt */

/* ws layout (ushort units). total incl tsum = 84,036,608 B <= 84.25MB proven */
#define PA_OFF   0
#define PD_OFF   (ROWS_A * KP)          /* now holds Hraw fp32 15360x256 (15.7MB of 40.2MB) */
#define PWH_OFF  (PD_OFF + ROWS_D * KP)
#define PWD_OFF  (PWH_OFF + NKT * 16 * 512)
#define PW2_OFF  (PWD_OFF + NKT * 16 * 512)
#define PWD2_OFF (PW2_OFF + 8 * 16 * 512)
#define TSUM_OFF (PWD2_OFF + 8 * 8 * 512)   /* 768 floats follow */

__device__ __forceinline__ unsigned short f2h(float f) {
    __half h = __float2half(f);
    return __half_as_ushort(h);
}
__device__ __forceinline__ h2f u2h2(unsigned int u) {
    h2f r; __builtin_memcpy(&r, &u, 4); return r;
}

// ============ k0: pack weights (fp16 B-frags) + tsum baselines ============
__global__ __launch_bounds__(256)
void k0_pack(const float* __restrict__ w_h1, const float* __restrict__ wd1,
             const float* __restrict__ wm1,  const float* __restrict__ ws1,
             const float* __restrict__ wd2,  const float* __restrict__ digit,
             unsigned short* __restrict__ wsu, float* __restrict__ tsum)
{
    const int tid = threadIdx.x;
    if (blockIdx.x >= 3136) {            // tsum blocks: 4 sbk per block
        const int sbk = (blockIdx.x - 3136) * 4 + (tid >> 6);
        const int l = tid & 63;
        const float* tp = digit + (size_t)sbk * 784;
        float s = 0.f;
        for (int i = l; i < 784; i += 64) s += tp[i];
        for (int o = 32; o; o >>= 1) s += __shfl_xor(s, o, 64);
        if (l == 0) tsum[sbk] = 0.5f * s;
        return;
    }
    int idx = blockIdx.x * 256 + tid;      // 0..802815
    int local, mode;
    unsigned short* dst;
    if (idx < 352256)      { mode = 0; local = idx;          dst = wsu + PWH_OFF; }
    else if (idx < 704512) { mode = 1; local = idx - 352256; dst = wsu + PWD_OFF; }
    else if (idx < 770048) { mode = 2; local = idx - 704512; dst = wsu + PW2_OFF; }
    else                   { mode = 3; local = idx - 770048; dst = wsu + PWD2_OFF; }
    int j = local & 7, lane = (local >> 3) & 63, rest = local >> 9;
    int NTn = (mode == 3) ? 8 : 16;
    int nt = rest % NTn, kt = rest / NTn;
    int k = kt * 32 + ((lane >> 4) << 3) + j;
    int n = nt * 16 + (lane & 15);
    float v = 0.f;
    if (mode == 0)      { if (k < NP) v = w_h1[k * 256 + n]; }
    else if (mode == 1) { if (k < NP) v = wd1[k * 256 + n]; }
    else if (mode == 2) { v = (n < 128) ? wm1[k * 128 + n] : ws1[k * 128 + (n - 128)]; }
    else                { v = wd2[k * 128 + n]; }
    dst[local] = f2h(v);
}

// ============ k1a: correlation as im2col MFMA GEMM (R8 funnel version) ============
// grid 960 = (b 16) x (t 20) x (ntile 3); block 256 (4 waves). 38.4KB LDS -> 4 blocks/CU.
__global__ __launch_bounds__(256, 4)
void k1a_corr(const float* __restrict__ frames, const float* __restrict__ digit,
              const float* __restrict__ tsum, unsigned short* __restrict__ wsu)
{
    __shared__ __align__(16) unsigned short Bs[28 * 512];  // 28,672 B
    __shared__ __align__(16) unsigned int frd[64 * 36];    // fp16 frame pairs, 9,216 B
    __shared__ float Cn[16];

    const int tid = threadIdx.x, l = tid & 63, w = tid >> 6;
    const int nt = blockIdx.x % 3;
    const int t  = (blockIdx.x / 3) % 20;
    const int bb = blockIdx.x / 60;
    const int N0 = nt * 16;

    for (int slot = tid; slot < 1792; slot += 256) {
        int kt = slot >> 6, sl = slot & 63;
        int n  = N0 + (sl & 15);
        int v0 = (sl >> 4) << 3;
        int sbk_n = ((n / 3) * 16 + bb) * 3 + (n % 3);
        const float* tp = digit + (size_t)sbk_n * 784 + kt * 28 + v0;
        float4 fa = *(const float4*)tp;
        float4 fb = (v0 <= 16) ? *(const float4*)(tp + 4) : make_float4(0.f, 0.f, 0.f, 0.f);
        uint4 pk;
        pk.x = (unsigned)f2h(fa.x) | ((unsigned)f2h(fa.y) << 16);
        pk.y = (unsigned)f2h(fa.z) | ((unsigned)f2h(fa.w) << 16);
        pk.z = (unsigned)f2h(fb.x) | ((unsigned)f2h(fb.y) << 16);
        pk.w = (unsigned)f2h(fb.z) | ((unsigned)f2h(fb.w) << 16);
        *(uint4*)(Bs + slot * 8) = pk;
    }
    if (tid < 16) {
        int n = N0 + tid;
        int sbk_n = ((n / 3) * 16 + bb) * 3 + (n % 3);
        Cn[tid] = tsum[sbk_n];
    }
    frd[(tid >> 2) * 36 + 32 + (tid & 3)] = 0u;
    {
        const float4* fp4 = (const float4*)(frames + (size_t)(bb * 20 + t) * 4096);
        for (int idx = tid; idx < 1024; idx += 256) {
            float4 v = fp4[idx];
            int r = idx >> 4, c4 = idx & 15;
            unsigned lo = (unsigned)f2h(v.x) | ((unsigned)f2h(v.y) << 16);
            unsigned hi = (unsigned)f2h(v.z) | ((unsigned)f2h(v.w) << 16);
            *(uint2*)&frd[r * 36 + c4 * 2] = make_uint2(lo, hi);
        }
    }
    __syncthreads();

    const int c15 = l & 15, quad = l >> 4, v0q = quad << 3;
    const int cntw = (89 - w) / 4;        // 22,22,21,21 tiles per wave

    for (int m0 = 0; m0 < cntw; m0 += 8) {
        const int tc = (cntw - m0 < 8) ? (cntw - m0) : 8;
        int baseb[8]; unsigned shv[8];
#pragma unroll
        for (int it = 0; it < 8; ++it) {
            int tI = w + 4 * (m0 + it);
            int p  = tI * 16 + c15;
            int pc = p > 1368 ? 1368 : p;
            int i  = pc / 37;
            int jj = pc - i * 37;
            int c  = jj + v0q;
            baseb[it] = i * 144 + (c >> 1) * 4;
            shv[it]   = (unsigned)((c & 1) << 4);
        }
        f32x4 acc[8];
#pragma unroll
        for (int it = 0; it < 8; ++it) acc[it] = (f32x4){0.f, 0.f, 0.f, 0.f};

        for (int kt = 0; kt < 28; ++kt) {
            half8 bf = *(const half8*)(Bs + kt * 512 + l * 8);
            const char* fbase = (const char*)frd + kt * 144;
#pragma unroll
            for (int it = 0; it < 8; ++it) {
                if (it < tc) {
                    const char* ap = fbase + baseb[it];
                    unsigned w0 = *(const unsigned*)(ap);
                    unsigned w1 = *(const unsigned*)(ap + 4);
                    unsigned w2 = *(const unsigned*)(ap + 8);
                    unsigned w3 = *(const unsigned*)(ap + 12);
                    unsigned w4 = *(const unsigned*)(ap + 16);
                    unsigned sh = shv[it];
                    union { unsigned u[4]; half8 h8; } af;
                    af.u[0] = (unsigned)(((((unsigned long long)w1) << 32) | w0) >> sh);
                    af.u[1] = (unsigned)(((((unsigned long long)w2) << 32) | w1) >> sh);
                    af.u[2] = (unsigned)(((((unsigned long long)w3) << 32) | w2) >> sh);
                    af.u[3] = (unsigned)(((((unsigned long long)w4) << 32) | w3) >> sh);
                    acc[it] = __builtin_amdgcn_mfma_f32_16x16x32_f16(af.h8, bf, acc[it], 0, 0, 0);
                }
            }
        }
        const float C = Cn[c15];
        const int n = N0 + c15;
        const int sbk_n = ((n / 3) * 16 + bb) * 3 + (n % 3);
        unsigned short* orow = wsu + PA_OFF + (size_t)(sbk_n * 20 + t) * KP;
#pragma unroll
        for (int it = 0; it < 8; ++it) {
            if (it < tc) {
                int tI = w + 4 * (m0 + it);
                int p0 = tI * 16 + quad * 4;
                if (p0 + 3 <= 1368) {
                    ushort4 st;
                    st.x = f2h(acc[it][0] - C); st.y = f2h(acc[it][1] - C);
                    st.z = f2h(acc[it][2] - C); st.w = f2h(acc[it][3] - C);
                    *(ushort4*)(orow + p0) = st;
                } else {
#pragma unroll
                    for (int r = 0; r < 4; ++r)
                        if (p0 + r <= 1368) orow[p0 + r] = f2h(acc[it][r] - C);
                }
            }
        }
    }
}

// ============ k2_gemmB: raw @ wd1 -> Hraw fp32 (runs BEFORE softmax) ============
__global__ __launch_bounds__(256)
void k2_gemmB(unsigned short* __restrict__ wsu)
{
    const int tid = threadIdx.x, l = tid & 63, w = tid >> 6;
    const int c15 = l & 15, quad = l >> 4;
    const int M0 = blockIdx.x * 64;
    const unsigned short* Abase = wsu + PA_OFF;
    const unsigned short* PW = wsu + PWD_OFF;
    float* HR = (float*)(wsu + PD_OFF);

    f32x4 acc[16];
#pragma unroll
    for (int n = 0; n < 16; ++n) acc[n] = (f32x4){0.f, 0.f, 0.f, 0.f};

    const unsigned short* arow = Abase + (size_t)(M0 + w * 16 + c15) * KP + quad * 8;
    for (int kt = 0; kt < NKT; ++kt) {
        half8 af = *(const half8*)(arow + kt * 32);
        const unsigned short* bkt = PW + (size_t)kt * 8192 + l * 8;
#pragma unroll
        for (int nt = 0; nt < 16; ++nt) {
            half8 bf = *(const half8*)(bkt + nt * 512);
            acc[nt] = __builtin_amdgcn_mfma_f32_16x16x32_f16(af, bf, acc[nt], 0, 0, 0);
        }
    }
#pragma unroll
    for (int nt = 0; nt < 16; ++nt) {
        const int col = nt * 16 + c15;
#pragma unroll
        for (int r = 0; r < 4; ++r) {
            const int row = M0 + w * 16 + quad * 4 + r;
            HR[(size_t)row * 256 + col] = acc[nt][r];
        }
    }
}

// ============ k1b: wave-per-row softmax in place (no LDS, no barriers) ============
// grid 3840; block 256 = 4 waves, wave wv owns row blockIdx*4+wv.
__global__ __launch_bounds__(256)
void k1b_sm(unsigned short* __restrict__ wsu)
{
    const int l = threadIdx.x & 63, wv = threadIdx.x >> 6;
    const int row = blockIdx.x * 4 + wv;
    unsigned* rp = (unsigned*)(wsu + PA_OFF + (size_t)row * KP);

    float f0[11], f1[11];
    float mx = -3.0e38f;
#pragma unroll
    for (int i = 0; i < 11; ++i) {
        int q = l + i * 64;
        unsigned u = (q < 685) ? rp[q] : 0u;
        h2f h = u2h2(u);
        f0[i] = (q < 685) ? (float)h[0] : -3.0e38f;
        f1[i] = (q < 684) ? (float)h[1] : -3.0e38f;   // half 1369 is pad
        mx = fmaxf(mx, fmaxf(f0[i], f1[i]));
    }
    for (int o = 32; o; o >>= 1) mx = fmaxf(mx, __shfl_xor(mx, o, 64));
    float e0[11], e1[11], sum = 0.f;
#pragma unroll
    for (int i = 0; i < 11; ++i) {
        e0[i] = __expf(f0[i] - mx);
        e1[i] = __expf(f1[i] - mx);
        sum += e0[i] + e1[i];
    }
    for (int o = 32; o; o >>= 1) sum += __shfl_xor(sum, o, 64);
    const float inv = 1.0f / sum;
#pragma unroll
    for (int i = 0; i < 11; ++i) {
        int q = l + i * 64;
        if (q < 685)
            rp[q] = (unsigned)f2h(e0[i] * inv) | ((unsigned)f2h(e1[i] * inv) << 16);
    }
}

// ============ k2_gemmA: probs @ w_h1 + bias, relu -> fp16 in place ============
__global__ __launch_bounds__(256)
void k2_gemmA(unsigned short* __restrict__ wsu, const float* __restrict__ b_h1)
{
    const int tid = threadIdx.x, l = tid & 63, w = tid >> 6;
    const int c15 = l & 15, quad = l >> 4;
    const int M0 = blockIdx.x * 64;
    unsigned short* Abase = wsu + PA_OFF;
    const unsigned short* PW = wsu + PWH_OFF;

    f32x4 acc[16];
#pragma unroll
    for (int n = 0; n < 16; ++n) acc[n] = (f32x4){0.f, 0.f, 0.f, 0.f};

    const unsigned short* arow = Abase + (size_t)(M0 + w * 16 + c15) * KP + quad * 8;
    for (int kt = 0; kt < NKT; ++kt) {
        half8 af = *(const half8*)(arow + kt * 32);
        const unsigned short* bkt = PW + (size_t)kt * 8192 + l * 8;
#pragma unroll
        for (int nt = 0; nt < 16; ++nt) {
            half8 bf = *(const half8*)(bkt + nt * 512);
            acc[nt] = __builtin_amdgcn_mfma_f32_16x16x32_f16(af, bf, acc[nt], 0, 0, 0);
        }
    }
#pragma unroll
    for (int nt = 0; nt < 16; ++nt) {
        const int col = nt * 16 + c15;
        const float bv = b_h1[col];
#pragma unroll
        for (int r = 0; r < 4; ++r) {
            const int row = M0 + w * 16 + quad * 4 + r;
            float v = acc[nt][r] + bv;
            v = v > 0.f ? v : 0.f;
            Abase[(size_t)row * KP + col] = f2h(v);
        }
    }
}

// ============ k2_heads: second GEMM (K=256) + in-register final heads ============
// PATHA: A = hidden fp16 rows in PA. !PATHA: A built on the fly from Hraw fp32 diffs.
template <bool PATHA>
__global__ __launch_bounds__(256)
void k2_heads(unsigned short* __restrict__ wsu,
              const float* __restrict__ b1a, const float* __restrict__ b1b,
              const float* __restrict__ w2a, const float* __restrict__ b2a,
              const float* __restrict__ w2b, const float* __restrict__ b2b,
              const float* __restrict__ bd1, float* __restrict__ out)
{
    constexpr int NT2 = PATHA ? 16 : 8;
    const int tid = threadIdx.x, l = tid & 63, w = tid >> 6;
    const int c = l & 15, quad = l >> 4;
    const int M0 = blockIdx.x * 64;
    const unsigned short* PW = wsu + (PATHA ? PW2_OFF : PWD2_OFF);

    f32x4 acc[NT2];
#pragma unroll
    for (int n = 0; n < NT2; ++n) acc[n] = (f32x4){0.f, 0.f, 0.f, 0.f};

    const int row = M0 + w * 16 + c;
    const unsigned short* arow = nullptr;
    const float* h1p = nullptr; const float* h0p = nullptr;
    if (PATHA) {
        arow = wsu + PA_OFF + (size_t)row * KP + quad * 8;
    } else {
        const float* HR = (const float*)(wsu + PD_OFF);
        const int sbk = row / 19, dt = row % 19;
        h0p = HR + (size_t)(sbk * 20 + dt) * 256 + quad * 8;
        h1p = h0p + 256;
    }

    for (int kt = 0; kt < 8; ++kt) {
        half8 af;
        if (PATHA) {
            af = *(const half8*)(arow + kt * 32);
        } else {
            float4 a1 = *(const float4*)(h1p + kt * 32);
            float4 a1b = *(const float4*)(h1p + kt * 32 + 4);
            float4 a0 = *(const float4*)(h0p + kt * 32);
            float4 a0b = *(const float4*)(h0p + kt * 32 + 4);
            float4 bb = *(const float4*)(bd1 + kt * 32 + quad * 8);
            float4 bb2 = *(const float4*)(bd1 + kt * 32 + quad * 8 + 4);
            float v0 = fmaxf(a1.x - a0.x + bb.x, 0.f);
            float v1 = fmaxf(a1.y - a0.y + bb.y, 0.f);
            float v2 = fmaxf(a1.z - a0.z + bb.z, 0.f);
            float v3 = fmaxf(a1.w - a0.w + bb.w, 0.f);
            float v4 = fmaxf(a1b.x - a0b.x + bb2.x, 0.f);
            float v5 = fmaxf(a1b.y - a0b.y + bb2.y, 0.f);
            float v6 = fmaxf(a1b.z - a0b.z + bb2.z, 0.f);
            float v7 = fmaxf(a1b.w - a0b.w + bb2.w, 0.f);
            union { unsigned u[4]; half8 h8; } pk;
            pk.u[0] = (unsigned)f2h(v0) | ((unsigned)f2h(v1) << 16);
            pk.u[1] = (unsigned)f2h(v2) | ((unsigned)f2h(v3) << 16);
            pk.u[2] = (unsigned)f2h(v4) | ((unsigned)f2h(v5) << 16);
            pk.u[3] = (unsigned)f2h(v6) | ((unsigned)f2h(v7) << 16);
            af = pk.h8;
        }
        const unsigned short* bkt = PW + (size_t)kt * (NT2 * 512) + l * 8;
#pragma unroll
        for (int nt = 0; nt < NT2; ++nt) {
            half8 bf = *(const half8*)(bkt + nt * 512);
            acc[nt] = __builtin_amdgcn_mfma_f32_16x16x32_f16(af, bf, acc[nt], 0, 0, 0);
        }
    }
#pragma unroll
    for (int nt = 0; nt < NT2; ++nt) {
        float bv;
        if (PATHA) bv = (nt < 8) ? b1a[nt * 16 + c] : b1b[(nt - 8) * 16 + c];
        else       bv = b1a[nt * 16 + c];
#pragma unroll
        for (int r = 0; r < 4; ++r) {
            float v = acc[nt][r] + bv;
            acc[nt][r] = v > 0.f ? v : 0.f;
        }
    }
    float pm[2][4], ps[2][4];
#pragma unroll
    for (int d = 0; d < 2; ++d)
#pragma unroll
        for (int r = 0; r < 4; ++r) { pm[d][r] = 0.f; ps[d][r] = 0.f; }
#pragma unroll
    for (int d = 0; d < 2; ++d)
#pragma unroll
        for (int nt = 0; nt < 8; ++nt) {
            const float wmv = w2a[(nt * 16 + c) * 2 + d];
            float wsv = 0.f;
            if (PATHA) wsv = w2b[(nt * 16 + c) * 2 + d];
#pragma unroll
            for (int r = 0; r < 4; ++r) {
                pm[d][r] = fmaf(acc[nt][r], wmv, pm[d][r]);
                if (PATHA) ps[d][r] = fmaf(acc[nt + 8][r], wsv, ps[d][r]);
            }
        }
#pragma unroll
    for (int o = 1; o < 16; o <<= 1)
#pragma unroll
        for (int d = 0; d < 2; ++d)
#pragma unroll
            for (int r = 0; r < 4; ++r) {
                pm[d][r] += __shfl_xor(pm[d][r], o, 64);
                if (PATHA) ps[d][r] += __shfl_xor(ps[d][r], o, 64);
            }
    if (c == 0) {
#pragma unroll
        for (int r = 0; r < 4; ++r) {
            const int orow = M0 + w * 16 + quad * 4 + r;
            if (PATHA) {
                const int sbk = orow / 20, t = orow % 20;
                const int sb = sbk / 3, kk = sbk % 3;
                const int oi = ((sb * 20 + t) * 3 + kk) * 2;
                out[oi + 0] = tanhf(pm[0][r] + b2a[0]);
                out[oi + 1] = tanhf(pm[1][r] + b2a[1]);
                out[30720 + oi + 0] = __expf(ps[0][r] + b2b[0]);
                out[30720 + oi + 1] = __expf(ps[1][r] + b2b[1]);
            } else {
                const int sbk = orow / 19, dt = orow % 19;
                const int sb = sbk / 3, kk = sbk % 3;
                const int oi = 61440 + ((sb * 19 + dt) * 3 + kk) * 2;
                out[oi + 0] = tanhf(pm[0][r] + b2a[0]);
                out[oi + 1] = tanhf(pm[1][r] + b2a[1]);
            }
        }
    }
}

extern "C" void kernel_launch(void* const* d_in, const int* in_sizes, int n_in,
                              void* d_out, int out_size, void* d_ws, size_t ws_size,
                              hipStream_t stream) {
    const float* frames = (const float*)d_in[0];
    const float* digit  = (const float*)d_in[1];
    const float* w_h1   = (const float*)d_in[2];
    const float* b_h1   = (const float*)d_in[3];
    const float* wm1    = (const float*)d_in[4];
    const float* bm1    = (const float*)d_in[5];
    const float* wm2    = (const float*)d_in[6];
    const float* bm2    = (const float*)d_in[7];
    const float* ws1    = (const float*)d_in[8];
    const float* bs1    = (const float*)d_in[9];
    const float* ws2    = (const float*)d_in[10];
    const float* bs2    = (const float*)d_in[11];
    const float* wd1    = (const float*)d_in[12];
    const float* bd1    = (const float*)d_in[13];
    const float* wd2    = (const float*)d_in[14];
    const float* bd2    = (const float*)d_in[15];
    const float* wd3    = (const float*)d_in[16];
    const float* bd3    = (const float*)d_in[17];

    unsigned short* wsu = (unsigned short*)d_ws;
    float* tsum = (float*)(wsu + TSUM_OFF);
    float* o = (float*)d_out;

    k0_pack<<<dim3(3328), dim3(256), 0, stream>>>(w_h1, wd1, wm1, ws1, wd2, digit, wsu, tsum);
    k1a_corr<<<dim3(960), dim3(256), 0, stream>>>(frames, digit, tsum, wsu);
    k2_gemmB<<<dim3(240), dim3(256), 0, stream>>>(wsu);                       // raw -> Hraw (pre-softmax)
    k1b_sm<<<dim3(3840), dim3(256), 0, stream>>>(wsu);                        // softmax in place
    k2_gemmA<<<dim3(240), dim3(256), 0, stream>>>(wsu, b_h1);                 // probs -> hidden
    k2_heads<true><<<dim3(240), dim3(256), 0, stream>>>(wsu, bm1, bs1, wm2, bm2, ws2, bs2, nullptr, o);
    k2_heads<false><<<dim3(228), dim3(256), 0, stream>>>(wsu, bd2, nullptr, wd3, bd3, nullptr, nullptr, bd1, o);
}

// Round 11
// 225.105 us; speedup vs baseline: 1.6281x; 1.6281x over previous
//
#include <hip/hip_runtime.h>
#include <hip/hip_fp16.h>

typedef __attribute__((ext_vector_type(8))) _Float16 half8;
typedef __attribute__((ext_vector_type(2))) _Float16 h2f;
typedef __attribute__((ext_vector_type(4))) float f32x4;

#define NP 1369
#define KP 1376          /* padded row stride: 43 tiles of 32 */
#define NKT 43
#define ROWS_A 15360     /* 768 sbk * 20 t  */
#define ROWS_D 14592     /* 768 sbk * 19 dt */

/* ws layout (ushort units). total incl tsum = 84,036,608 B <= 84.25MB proven */
#define PA_OFF   0
#define PD_OFF   (ROWS_A * KP)          /* holds Hraw fp32 15360x256 (15.7MB of 40.2MB) */
#define PWH_OFF  (PD_OFF + ROWS_D * KP)
#define PWD_OFF  (PWH_OFF + NKT * 16 * 512)
#define PW2_OFF  (PWD_OFF + NKT * 16 * 512)
#define PWD2_OFF (PW2_OFF + 8 * 16 * 512)
#define TSUM_OFF (PWD2_OFF + 8 * 8 * 512)   /* 768 floats follow */

__device__ __forceinline__ unsigned short f2h(float f) {
    __half h = __float2half(f);
    return __half_as_ushort(h);
}
__device__ __forceinline__ h2f u2h2(unsigned int u) {
    h2f r; __builtin_memcpy(&r, &u, 4); return r;
}

// ============ k0: pack weights (fp16 B-frags) + tsum baselines ============
__global__ __launch_bounds__(256)
void k0_pack(const float* __restrict__ w_h1, const float* __restrict__ wd1,
             const float* __restrict__ wm1,  const float* __restrict__ ws1,
             const float* __restrict__ wd2,  const float* __restrict__ digit,
             unsigned short* __restrict__ wsu, float* __restrict__ tsum)
{
    const int tid = threadIdx.x;
    if (blockIdx.x >= 3136) {            // tsum blocks: 4 sbk per block
        const int sbk = (blockIdx.x - 3136) * 4 + (tid >> 6);
        const int l = tid & 63;
        const float* tp = digit + (size_t)sbk * 784;
        float s = 0.f;
        for (int i = l; i < 784; i += 64) s += tp[i];
        for (int o = 32; o; o >>= 1) s += __shfl_xor(s, o, 64);
        if (l == 0) tsum[sbk] = 0.5f * s;
        return;
    }
    int idx = blockIdx.x * 256 + tid;      // 0..802815
    int local, mode;
    unsigned short* dst;
    if (idx < 352256)      { mode = 0; local = idx;          dst = wsu + PWH_OFF; }
    else if (idx < 704512) { mode = 1; local = idx - 352256; dst = wsu + PWD_OFF; }
    else if (idx < 770048) { mode = 2; local = idx - 704512; dst = wsu + PW2_OFF; }
    else                   { mode = 3; local = idx - 770048; dst = wsu + PWD2_OFF; }
    int j = local & 7, lane = (local >> 3) & 63, rest = local >> 9;
    int NTn = (mode == 3) ? 8 : 16;
    int nt = rest % NTn, kt = rest / NTn;
    int k = kt * 32 + ((lane >> 4) << 3) + j;
    int n = nt * 16 + (lane & 15);
    float v = 0.f;
    if (mode == 0)      { if (k < NP) v = w_h1[k * 256 + n]; }
    else if (mode == 1) { if (k < NP) v = wd1[k * 256 + n]; }
    else if (mode == 2) { v = (n < 128) ? wm1[k * 128 + n] : ws1[k * 128 + (n - 128)]; }
    else                { v = wd2[k * 128 + n]; }
    dst[local] = f2h(v);
}

// ============ k1a: correlation as im2col MFMA GEMM (R8 funnel version) ============
__global__ __launch_bounds__(256, 4)
void k1a_corr(const float* __restrict__ frames, const float* __restrict__ digit,
              const float* __restrict__ tsum, unsigned short* __restrict__ wsu)
{
    __shared__ __align__(16) unsigned short Bs[28 * 512];
    __shared__ __align__(16) unsigned int frd[64 * 36];
    __shared__ float Cn[16];

    const int tid = threadIdx.x, l = tid & 63, w = tid >> 6;
    const int nt = blockIdx.x % 3;
    const int t  = (blockIdx.x / 3) % 20;
    const int bb = blockIdx.x / 60;
    const int N0 = nt * 16;

    for (int slot = tid; slot < 1792; slot += 256) {
        int kt = slot >> 6, sl = slot & 63;
        int n  = N0 + (sl & 15);
        int v0 = (sl >> 4) << 3;
        int sbk_n = ((n / 3) * 16 + bb) * 3 + (n % 3);
        const float* tp = digit + (size_t)sbk_n * 784 + kt * 28 + v0;
        float4 fa = *(const float4*)tp;
        float4 fb = (v0 <= 16) ? *(const float4*)(tp + 4) : make_float4(0.f, 0.f, 0.f, 0.f);
        uint4 pk;
        pk.x = (unsigned)f2h(fa.x) | ((unsigned)f2h(fa.y) << 16);
        pk.y = (unsigned)f2h(fa.z) | ((unsigned)f2h(fa.w) << 16);
        pk.z = (unsigned)f2h(fb.x) | ((unsigned)f2h(fb.y) << 16);
        pk.w = (unsigned)f2h(fb.z) | ((unsigned)f2h(fb.w) << 16);
        *(uint4*)(Bs + slot * 8) = pk;
    }
    if (tid < 16) {
        int n = N0 + tid;
        int sbk_n = ((n / 3) * 16 + bb) * 3 + (n % 3);
        Cn[tid] = tsum[sbk_n];
    }
    frd[(tid >> 2) * 36 + 32 + (tid & 3)] = 0u;
    {
        const float4* fp4 = (const float4*)(frames + (size_t)(bb * 20 + t) * 4096);
        for (int idx = tid; idx < 1024; idx += 256) {
            float4 v = fp4[idx];
            int r = idx >> 4, c4 = idx & 15;
            unsigned lo = (unsigned)f2h(v.x) | ((unsigned)f2h(v.y) << 16);
            unsigned hi = (unsigned)f2h(v.z) | ((unsigned)f2h(v.w) << 16);
            *(uint2*)&frd[r * 36 + c4 * 2] = make_uint2(lo, hi);
        }
    }
    __syncthreads();

    const int c15 = l & 15, quad = l >> 4, v0q = quad << 3;
    const int cntw = (89 - w) / 4;

    for (int m0 = 0; m0 < cntw; m0 += 8) {
        const int tc = (cntw - m0 < 8) ? (cntw - m0) : 8;
        int baseb[8]; unsigned shv[8];
#pragma unroll
        for (int it = 0; it < 8; ++it) {
            int tI = w + 4 * (m0 + it);
            int p  = tI * 16 + c15;
            int pc = p > 1368 ? 1368 : p;
            int i  = pc / 37;
            int jj = pc - i * 37;
            int c  = jj + v0q;
            baseb[it] = i * 144 + (c >> 1) * 4;
            shv[it]   = (unsigned)((c & 1) << 4);
        }
        f32x4 acc[8];
#pragma unroll
        for (int it = 0; it < 8; ++it) acc[it] = (f32x4){0.f, 0.f, 0.f, 0.f};

        for (int kt = 0; kt < 28; ++kt) {
            half8 bf = *(const half8*)(Bs + kt * 512 + l * 8);
            const char* fbase = (const char*)frd + kt * 144;
#pragma unroll
            for (int it = 0; it < 8; ++it) {
                if (it < tc) {
                    const char* ap = fbase + baseb[it];
                    unsigned w0 = *(const unsigned*)(ap);
                    unsigned w1 = *(const unsigned*)(ap + 4);
                    unsigned w2 = *(const unsigned*)(ap + 8);
                    unsigned w3 = *(const unsigned*)(ap + 12);
                    unsigned w4 = *(const unsigned*)(ap + 16);
                    unsigned sh = shv[it];
                    union { unsigned u[4]; half8 h8; } af;
                    af.u[0] = (unsigned)(((((unsigned long long)w1) << 32) | w0) >> sh);
                    af.u[1] = (unsigned)(((((unsigned long long)w2) << 32) | w1) >> sh);
                    af.u[2] = (unsigned)(((((unsigned long long)w3) << 32) | w2) >> sh);
                    af.u[3] = (unsigned)(((((unsigned long long)w4) << 32) | w3) >> sh);
                    acc[it] = __builtin_amdgcn_mfma_f32_16x16x32_f16(af.h8, bf, acc[it], 0, 0, 0);
                }
            }
        }
        const float C = Cn[c15];
        const int n = N0 + c15;
        const int sbk_n = ((n / 3) * 16 + bb) * 3 + (n % 3);
        unsigned short* orow = wsu + PA_OFF + (size_t)(sbk_n * 20 + t) * KP;
#pragma unroll
        for (int it = 0; it < 8; ++it) {
            if (it < tc) {
                int tI = w + 4 * (m0 + it);
                int p0 = tI * 16 + quad * 4;
                if (p0 + 3 <= 1368) {
                    ushort4 st;
                    st.x = f2h(acc[it][0] - C); st.y = f2h(acc[it][1] - C);
                    st.z = f2h(acc[it][2] - C); st.w = f2h(acc[it][3] - C);
                    *(ushort4*)(orow + p0) = st;
                } else {
#pragma unroll
                    for (int r = 0; r < 4; ++r)
                        if (p0 + r <= 1368) orow[p0 + r] = f2h(acc[it][r] - C);
                }
            }
        }
    }
}

// ============ k2_gemmB: raw @ wd1 -> Hraw fp32 (LDS-staged, M=64, grid 240) ============
__global__ __launch_bounds__(256)
void k2_gemmB(unsigned short* __restrict__ wsu)
{
    __shared__ __align__(16) unsigned short Bsh[16 * 512];   // 16 KB
    __shared__ __align__(16) unsigned short As[64 * 40];     // 5 KB

    const int tid = threadIdx.x, l = tid & 63, w = tid >> 6;
    const int c15 = l & 15, quad = l >> 4;
    const int M0 = blockIdx.x * 64;
    const unsigned short* Abase = wsu + PA_OFF;
    const unsigned short* PW = wsu + PWD_OFF;
    float* HR = (float*)(wsu + PD_OFF);

    f32x4 acc[16];
#pragma unroll
    for (int n = 0; n < 16; ++n) acc[n] = (f32x4){0.f, 0.f, 0.f, 0.f};

    for (int kt = 0; kt < NKT; ++kt) {
        __syncthreads();
        {   // stage B tile 16KB: 256 thr x 64B
            const int4* src = (const int4*)(PW + (size_t)kt * 8192 + tid * 32);
            int4* dst = (int4*)(Bsh + tid * 32);
#pragma unroll
            for (int c = 0; c < 4; ++c) dst[c] = src[c];
        }
        {   // stage A tile 64 rows x 32 halfs (padded stride 40): 256 thr x 16B
            int row = tid >> 2, seg = tid & 3;
            *(int4*)(As + row * 40 + seg * 8) =
                *(const int4*)(Abase + (size_t)(M0 + row) * KP + kt * 32 + seg * 8);
        }
        __syncthreads();
        half8 af = *(const half8*)(As + (w * 16 + c15) * 40 + quad * 8);
#pragma unroll
        for (int nt = 0; nt < 16; ++nt) {
            half8 bf = *(const half8*)(Bsh + nt * 512 + l * 8);
            acc[nt] = __builtin_amdgcn_mfma_f32_16x16x32_f16(af, bf, acc[nt], 0, 0, 0);
        }
    }
#pragma unroll
    for (int nt = 0; nt < 16; ++nt) {
        const int col = nt * 16 + c15;
#pragma unroll
        for (int r = 0; r < 4; ++r) {
            const int row = M0 + w * 16 + quad * 4 + r;
            HR[(size_t)row * 256 + col] = acc[nt][r];
        }
    }
}

// ============ k1b: wave-per-row softmax in place (no LDS, no barriers) ============
__global__ __launch_bounds__(256)
void k1b_sm(unsigned short* __restrict__ wsu)
{
    const int l = threadIdx.x & 63, wv = threadIdx.x >> 6;
    const int row = blockIdx.x * 4 + wv;
    unsigned* rp = (unsigned*)(wsu + PA_OFF + (size_t)row * KP);

    float f0[11], f1[11];
    float mx = -3.0e38f;
#pragma unroll
    for (int i = 0; i < 11; ++i) {
        int q = l + i * 64;
        unsigned u = (q < 685) ? rp[q] : 0u;
        h2f h = u2h2(u);
        f0[i] = (q < 685) ? (float)h[0] : -3.0e38f;
        f1[i] = (q < 684) ? (float)h[1] : -3.0e38f;
        mx = fmaxf(mx, fmaxf(f0[i], f1[i]));
    }
    for (int o = 32; o; o >>= 1) mx = fmaxf(mx, __shfl_xor(mx, o, 64));
    float e0[11], e1[11], sum = 0.f;
#pragma unroll
    for (int i = 0; i < 11; ++i) {
        e0[i] = __expf(f0[i] - mx);
        e1[i] = __expf(f1[i] - mx);
        sum += e0[i] + e1[i];
    }
    for (int o = 32; o; o >>= 1) sum += __shfl_xor(sum, o, 64);
    const float inv = 1.0f / sum;
#pragma unroll
    for (int i = 0; i < 11; ++i) {
        int q = l + i * 64;
        if (q < 685)
            rp[q] = (unsigned)f2h(e0[i] * inv) | ((unsigned)f2h(e1[i] * inv) << 16);
    }
}

// ============ k2_gemmA: probs @ w_h1 + bias, relu -> fp16 in place (LDS-staged) ============
__global__ __launch_bounds__(256)
void k2_gemmA(unsigned short* __restrict__ wsu, const float* __restrict__ b_h1)
{
    __shared__ __align__(16) unsigned short Bsh[16 * 512];
    __shared__ __align__(16) unsigned short As[64 * 40];

    const int tid = threadIdx.x, l = tid & 63, w = tid >> 6;
    const int c15 = l & 15, quad = l >> 4;
    const int M0 = blockIdx.x * 64;
    unsigned short* Abase = wsu + PA_OFF;
    const unsigned short* PW = wsu + PWH_OFF;

    f32x4 acc[16];
#pragma unroll
    for (int n = 0; n < 16; ++n) acc[n] = (f32x4){0.f, 0.f, 0.f, 0.f};

    for (int kt = 0; kt < NKT; ++kt) {
        __syncthreads();
        {
            const int4* src = (const int4*)(PW + (size_t)kt * 8192 + tid * 32);
            int4* dst = (int4*)(Bsh + tid * 32);
#pragma unroll
            for (int c = 0; c < 4; ++c) dst[c] = src[c];
        }
        {
            int row = tid >> 2, seg = tid & 3;
            *(int4*)(As + row * 40 + seg * 8) =
                *(const int4*)(Abase + (size_t)(M0 + row) * KP + kt * 32 + seg * 8);
        }
        __syncthreads();
        half8 af = *(const half8*)(As + (w * 16 + c15) * 40 + quad * 8);
#pragma unroll
        for (int nt = 0; nt < 16; ++nt) {
            half8 bf = *(const half8*)(Bsh + nt * 512 + l * 8);
            acc[nt] = __builtin_amdgcn_mfma_f32_16x16x32_f16(af, bf, acc[nt], 0, 0, 0);
        }
    }
#pragma unroll
    for (int nt = 0; nt < 16; ++nt) {
        const int col = nt * 16 + c15;
        const float bv = b_h1[col];
#pragma unroll
        for (int r = 0; r < 4; ++r) {
            const int row = M0 + w * 16 + quad * 4 + r;
            float v = acc[nt][r] + bv;
            v = v > 0.f ? v : 0.f;
            Abase[(size_t)row * KP + col] = f2h(v);
        }
    }
}

// ============ k2_heads: second GEMM (K=256, B LDS-staged) + in-register heads ============
template <bool PATHA>
__global__ __launch_bounds__(256)
void k2_heads(unsigned short* __restrict__ wsu,
              const float* __restrict__ b1a, const float* __restrict__ b1b,
              const float* __restrict__ w2a, const float* __restrict__ b2a,
              const float* __restrict__ w2b, const float* __restrict__ b2b,
              const float* __restrict__ bd1, float* __restrict__ out)
{
    constexpr int NT2 = PATHA ? 16 : 8;
    __shared__ __align__(16) unsigned short Bsh[NT2 * 512];
    const int tid = threadIdx.x, l = tid & 63, w = tid >> 6;
    const int c = l & 15, quad = l >> 4;
    const int M0 = blockIdx.x * 64;
    const unsigned short* PW = wsu + (PATHA ? PW2_OFF : PWD2_OFF);

    f32x4 acc[NT2];
#pragma unroll
    for (int n = 0; n < NT2; ++n) acc[n] = (f32x4){0.f, 0.f, 0.f, 0.f};

    const int row = M0 + w * 16 + c;
    const unsigned short* arow = nullptr;
    const float* h1p = nullptr; const float* h0p = nullptr;
    if (PATHA) {
        arow = wsu + PA_OFF + (size_t)row * KP + quad * 8;
    } else {
        const float* HR = (const float*)(wsu + PD_OFF);
        const int sbk = row / 19, dt = row % 19;
        h0p = HR + (size_t)(sbk * 20 + dt) * 256 + quad * 8;
        h1p = h0p + 256;
    }

    for (int kt = 0; kt < 8; ++kt) {
        __syncthreads();
        {
            const int4* src = (const int4*)(PW + (size_t)kt * (NT2 * 512) + tid * (NT2 * 2));
            int4* dst = (int4*)(Bsh + tid * (NT2 * 2));
#pragma unroll
            for (int cc = 0; cc < NT2 / 4; ++cc) dst[cc] = src[cc];
        }
        __syncthreads();
        half8 af;
        if (PATHA) {
            af = *(const half8*)(arow + kt * 32);
        } else {
            float4 a1 = *(const float4*)(h1p + kt * 32);
            float4 a1b = *(const float4*)(h1p + kt * 32 + 4);
            float4 a0 = *(const float4*)(h0p + kt * 32);
            float4 a0b = *(const float4*)(h0p + kt * 32 + 4);
            float4 bb = *(const float4*)(bd1 + kt * 32 + quad * 8);
            float4 bb2 = *(const float4*)(bd1 + kt * 32 + quad * 8 + 4);
            float v0 = fmaxf(a1.x - a0.x + bb.x, 0.f);
            float v1 = fmaxf(a1.y - a0.y + bb.y, 0.f);
            float v2 = fmaxf(a1.z - a0.z + bb.z, 0.f);
            float v3 = fmaxf(a1.w - a0.w + bb.w, 0.f);
            float v4 = fmaxf(a1b.x - a0b.x + bb2.x, 0.f);
            float v5 = fmaxf(a1b.y - a0b.y + bb2.y, 0.f);
            float v6 = fmaxf(a1b.z - a0b.z + bb2.z, 0.f);
            float v7 = fmaxf(a1b.w - a0b.w + bb2.w, 0.f);
            union { unsigned u[4]; half8 h8; } pk;
            pk.u[0] = (unsigned)f2h(v0) | ((unsigned)f2h(v1) << 16);
            pk.u[1] = (unsigned)f2h(v2) | ((unsigned)f2h(v3) << 16);
            pk.u[2] = (unsigned)f2h(v4) | ((unsigned)f2h(v5) << 16);
            pk.u[3] = (unsigned)f2h(v6) | ((unsigned)f2h(v7) << 16);
            af = pk.h8;
        }
#pragma unroll
        for (int nt = 0; nt < NT2; ++nt) {
            half8 bf = *(const half8*)(Bsh + nt * 512 + l * 8);
            acc[nt] = __builtin_amdgcn_mfma_f32_16x16x32_f16(af, bf, acc[nt], 0, 0, 0);
        }
    }
#pragma unroll
    for (int nt = 0; nt < NT2; ++nt) {
        float bv;
        if (PATHA) bv = (nt < 8) ? b1a[nt * 16 + c] : b1b[(nt - 8) * 16 + c];
        else       bv = b1a[nt * 16 + c];
#pragma unroll
        for (int r = 0; r < 4; ++r) {
            float v = acc[nt][r] + bv;
            acc[nt][r] = v > 0.f ? v : 0.f;
        }
    }
    float pm[2][4], ps[2][4];
#pragma unroll
    for (int d = 0; d < 2; ++d)
#pragma unroll
        for (int r = 0; r < 4; ++r) { pm[d][r] = 0.f; ps[d][r] = 0.f; }
#pragma unroll
    for (int d = 0; d < 2; ++d)
#pragma unroll
        for (int nt = 0; nt < 8; ++nt) {
            const float wmv = w2a[(nt * 16 + c) * 2 + d];
            float wsv = 0.f;
            if (PATHA) wsv = w2b[(nt * 16 + c) * 2 + d];
#pragma unroll
            for (int r = 0; r < 4; ++r) {
                pm[d][r] = fmaf(acc[nt][r], wmv, pm[d][r]);
                if (PATHA) ps[d][r] = fmaf(acc[nt + 8][r], wsv, ps[d][r]);
            }
        }
#pragma unroll
    for (int o = 1; o < 16; o <<= 1)
#pragma unroll
        for (int d = 0; d < 2; ++d)
#pragma unroll
            for (int r = 0; r < 4; ++r) {
                pm[d][r] += __shfl_xor(pm[d][r], o, 64);
                if (PATHA) ps[d][r] += __shfl_xor(ps[d][r], o, 64);
            }
    if (c == 0) {
#pragma unroll
        for (int r = 0; r < 4; ++r) {
            const int orow = M0 + w * 16 + quad * 4 + r;
            if (PATHA) {
                const int sbk = orow / 20, t = orow % 20;
                const int sb = sbk / 3, kk = sbk % 3;
                const int oi = ((sb * 20 + t) * 3 + kk) * 2;
                out[oi + 0] = tanhf(pm[0][r] + b2a[0]);
                out[oi + 1] = tanhf(pm[1][r] + b2a[1]);
                out[30720 + oi + 0] = __expf(ps[0][r] + b2b[0]);
                out[30720 + oi + 1] = __expf(ps[1][r] + b2b[1]);
            } else {
                const int sbk = orow / 19, dt = orow % 19;
                const int sb = sbk / 3, kk = sbk % 3;
                const int oi = 61440 + ((sb * 19 + dt) * 3 + kk) * 2;
                out[oi + 0] = tanhf(pm[0][r] + b2a[0]);
                out[oi + 1] = tanhf(pm[1][r] + b2a[1]);
            }
        }
    }
}

extern "C" void kernel_launch(void* const* d_in, const int* in_sizes, int n_in,
                              void* d_out, int out_size, void* d_ws, size_t ws_size,
                              hipStream_t stream) {
    const float* frames = (const float*)d_in[0];
    const float* digit  = (const float*)d_in[1];
    const float* w_h1   = (const float*)d_in[2];
    const float* b_h1   = (const float*)d_in[3];
    const float* wm1    = (const float*)d_in[4];
    const float* bm1    = (const float*)d_in[5];
    const float* wm2    = (const float*)d_in[6];
    const float* bm2    = (const float*)d_in[7];
    const float* ws1    = (const float*)d_in[8];
    const float* bs1    = (const float*)d_in[9];
    const float* ws2    = (const float*)d_in[10];
    const float* bs2    = (const float*)d_in[11];
    const float* wd1    = (const float*)d_in[12];
    const float* bd1    = (const float*)d_in[13];
    const float* wd2    = (const float*)d_in[14];
    const float* bd2    = (const float*)d_in[15];
    const float* wd3    = (const float*)d_in[16];
    const float* bd3    = (const float*)d_in[17];

    unsigned short* wsu = (unsigned short*)d_ws;
    float* tsum = (float*)(wsu + TSUM_OFF);
    float* o = (float*)d_out;

    k0_pack<<<dim3(3328), dim3(256), 0, stream>>>(w_h1, wd1, wm1, ws1, wd2, digit, wsu, tsum);
    k1a_corr<<<dim3(960), dim3(256), 0, stream>>>(frames, digit, tsum, wsu);
    k2_gemmB<<<dim3(240), dim3(256), 0, stream>>>(wsu);                       // raw -> Hraw (pre-softmax)
    k1b_sm<<<dim3(3840), dim3(256), 0, stream>>>(wsu);                        // softmax in place
    k2_gemmA<<<dim3(240), dim3(256), 0, stream>>>(wsu, b_h1);                 // probs -> hidden
    k2_heads<true><<<dim3(240), dim3(256), 0, stream>>>(wsu, bm1, bs1, wm2, bm2, ws2, bs2, nullptr, o);
    k2_heads<false><<<dim3(228), dim3(256), 0, stream>>>(wsu, bd2, nullptr, wd3, bd3, nullptr, nullptr, bd1, o);
}

// Round 12
// 216.018 us; speedup vs baseline: 1.6966x; 1.0421x over previous
//
#include <hip/hip_runtime.h>
#include <hip/hip_fp16.h>

typedef __attribute__((ext_vector_type(8))) _Float16 half8;
typedef __attribute__((ext_vector_type(2))) _Float16 h2f;
typedef __attribute__((ext_vector_type(4))) float f32x4;

#define NP 1369
#define KP 1376          /* padded row stride: 43 tiles of 32 */
#define NKT 43
#define ROWS_A 15360     /* 768 sbk * 20 t  */
#define ROWS_D 14592     /* 768 sbk * 19 dt */

/* ws layout (ushort units). total = 84,119,488 B <= 84.25MB proven */
#define PA_OFF   0
#define PD_OFF   (ROWS_A * KP)          /* holds Hraw fp32 15360x256 */
#define PWH_OFF  (PD_OFF + ROWS_D * KP)
#define PWD_OFF  (PWH_OFF + NKT * 16 * 512)
#define PW2_OFF  (PWD_OFF + NKT * 16 * 512)
#define PWD2_OFF (PW2_OFF + 8 * 16 * 512)
#define TSUM_OFF (PWD2_OFF + 8 * 8 * 512)   /* 768 floats */
#define STAT_OFF (TSUM_OFF + 1536)          /* 15360 float2 */

__device__ __forceinline__ unsigned short f2h(float f) {
    __half h = __float2half(f);
    return __half_as_ushort(h);
}
__device__ __forceinline__ h2f u2h2(unsigned int u) {
    h2f r; __builtin_memcpy(&r, &u, 4); return r;
}

// ============ k0: pack weights (fp16 B-frags) + tsum baselines ============
__global__ __launch_bounds__(256)
void k0_pack(const float* __restrict__ w_h1, const float* __restrict__ wd1,
             const float* __restrict__ wm1,  const float* __restrict__ ws1,
             const float* __restrict__ wd2,  const float* __restrict__ digit,
             unsigned short* __restrict__ wsu, float* __restrict__ tsum)
{
    const int tid = threadIdx.x;
    if (blockIdx.x >= 3136) {            // tsum blocks: 4 sbk per block
        const int sbk = (blockIdx.x - 3136) * 4 + (tid >> 6);
        const int l = tid & 63;
        const float* tp = digit + (size_t)sbk * 784;
        float s = 0.f;
        for (int i = l; i < 784; i += 64) s += tp[i];
        for (int o = 32; o; o >>= 1) s += __shfl_xor(s, o, 64);
        if (l == 0) tsum[sbk] = 0.5f * s;
        return;
    }
    int idx = blockIdx.x * 256 + tid;      // 0..802815
    int local, mode;
    unsigned short* dst;
    if (idx < 352256)      { mode = 0; local = idx;          dst = wsu + PWH_OFF; }
    else if (idx < 704512) { mode = 1; local = idx - 352256; dst = wsu + PWD_OFF; }
    else if (idx < 770048) { mode = 2; local = idx - 704512; dst = wsu + PW2_OFF; }
    else                   { mode = 3; local = idx - 770048; dst = wsu + PWD2_OFF; }
    int j = local & 7, lane = (local >> 3) & 63, rest = local >> 9;
    int NTn = (mode == 3) ? 8 : 16;
    int nt = rest % NTn, kt = rest / NTn;
    int k = kt * 32 + ((lane >> 4) << 3) + j;
    int n = nt * 16 + (lane & 15);
    float v = 0.f;
    if (mode == 0)      { if (k < NP) v = w_h1[k * 256 + n]; }
    else if (mode == 1) { if (k < NP) v = wd1[k * 256 + n]; }
    else if (mode == 2) { v = (n < 128) ? wm1[k * 128 + n] : ws1[k * 128 + (n - 128)]; }
    else                { v = wd2[k * 128 + n]; }
    dst[local] = f2h(v);
}

// ============ k1a: im2col MFMA correlation, N=48 resident ============
// grid 640 = (b 16) x (t 20) x (M-half 2); block 512 (8 waves). LDS 95.4KB -> 1 block/CU.
__global__ __launch_bounds__(512)
void k1a_corr(const float* __restrict__ frames, const float* __restrict__ digit,
              const float* __restrict__ tsum, unsigned short* __restrict__ wsu)
{
    __shared__ __align__(16) unsigned short Bs[28 * 3 * 512];  // 86,016 B
    __shared__ __align__(16) unsigned int frd[64 * 36];        // 9,216 B
    __shared__ float Cn[48];

    const int tid = threadIdx.x, l = tid & 63, w = tid >> 6;
    const int mh = blockIdx.x & 1;
    const int bt = blockIdx.x >> 1;
    const int t  = bt % 20;
    const int bb = bt / 20;

    // ---- stage all 48 templates: 5376 slot-groups of 8 halfs ----
    for (int s = tid; s < 5376; s += 512) {
        int kt = s / 192;
        int rem = s - kt * 192;
        int nt = rem >> 6, sl = rem & 63;
        int nl = nt * 16 + (sl & 15);
        int v0 = (sl >> 4) << 3;
        int sbk_n = ((nl / 3) * 16 + bb) * 3 + (nl % 3);
        const float* tp = digit + (size_t)sbk_n * 784 + kt * 28 + v0;
        float4 fa = *(const float4*)tp;
        float4 fb = (v0 <= 16) ? *(const float4*)(tp + 4) : make_float4(0.f, 0.f, 0.f, 0.f);
        uint4 pk;
        pk.x = (unsigned)f2h(fa.x) | ((unsigned)f2h(fa.y) << 16);
        pk.y = (unsigned)f2h(fa.z) | ((unsigned)f2h(fa.w) << 16);
        pk.z = (unsigned)f2h(fb.x) | ((unsigned)f2h(fb.y) << 16);
        pk.w = (unsigned)f2h(fb.z) | ((unsigned)f2h(fb.w) << 16);
        *(uint4*)(Bs + s * 8) = pk;
    }
    if (tid < 48) {
        int sbk_n = ((tid / 3) * 16 + bb) * 3 + (tid % 3);
        Cn[tid] = tsum[sbk_n];
    }
    if (tid < 256) frd[(tid >> 2) * 36 + 32 + (tid & 3)] = 0u;
    {
        const float4* fp4 = (const float4*)(frames + (size_t)(bb * 20 + t) * 4096);
        for (int idx = tid; idx < 1024; idx += 512) {
            float4 v = fp4[idx];
            int r = idx >> 4, c4 = idx & 15;
            unsigned lo = (unsigned)f2h(v.x) | ((unsigned)f2h(v.y) << 16);
            unsigned hi = (unsigned)f2h(v.z) | ((unsigned)f2h(v.w) << 16);
            *(uint2*)&frd[r * 36 + c4 * 2] = make_uint2(lo, hi);
        }
    }
    __syncthreads();

    const int c15 = l & 15, quad = l >> 4, v0q = quad << 3;
    const int cnt = (50 - w) / 8;        // waves 0-2: 6 tiles, 3-7: 5 tiles (43 total)

    int baseb[6]; unsigned shv[6];
#pragma unroll
    for (int it = 0; it < 6; ++it) {
        int tI = mh * 43 + w + 8 * it;
        int p  = tI * 16 + c15;
        int pc = p > 1368 ? 1368 : p;
        int i  = pc / 37;
        int jj = pc - i * 37;
        int c  = jj + v0q;
        baseb[it] = i * 144 + (c >> 1) * 4;
        shv[it]   = (unsigned)((c & 1) << 4);
    }
    f32x4 acc[6][3];
#pragma unroll
    for (int it = 0; it < 6; ++it)
#pragma unroll
        for (int nt = 0; nt < 3; ++nt) acc[it][nt] = (f32x4){0.f, 0.f, 0.f, 0.f};

    for (int kt = 0; kt < 28; ++kt) {
        half8 bf0 = *(const half8*)(Bs + kt * 1536 + 0 * 512 + l * 8);
        half8 bf1 = *(const half8*)(Bs + kt * 1536 + 1 * 512 + l * 8);
        half8 bf2 = *(const half8*)(Bs + kt * 1536 + 2 * 512 + l * 8);
        const char* fbase = (const char*)frd + kt * 144;
#pragma unroll
        for (int it = 0; it < 6; ++it) {
            if (it < cnt) {
                const char* ap = fbase + baseb[it];
                unsigned w0 = *(const unsigned*)(ap);
                unsigned w1 = *(const unsigned*)(ap + 4);
                unsigned w2 = *(const unsigned*)(ap + 8);
                unsigned w3 = *(const unsigned*)(ap + 12);
                unsigned w4 = *(const unsigned*)(ap + 16);
                unsigned sh = shv[it];
                union { unsigned u[4]; half8 h8; } af;
                af.u[0] = (unsigned)(((((unsigned long long)w1) << 32) | w0) >> sh);
                af.u[1] = (unsigned)(((((unsigned long long)w2) << 32) | w1) >> sh);
                af.u[2] = (unsigned)(((((unsigned long long)w3) << 32) | w2) >> sh);
                af.u[3] = (unsigned)(((((unsigned long long)w4) << 32) | w3) >> sh);
                acc[it][0] = __builtin_amdgcn_mfma_f32_16x16x32_f16(af.h8, bf0, acc[it][0], 0, 0, 0);
                acc[it][1] = __builtin_amdgcn_mfma_f32_16x16x32_f16(af.h8, bf1, acc[it][1], 0, 0, 0);
                acc[it][2] = __builtin_amdgcn_mfma_f32_16x16x32_f16(af.h8, bf2, acc[it][2], 0, 0, 0);
            }
        }
    }
    // ---- epilogue: conv - C -> fp16 rows of PA (3 sbk rows per it) ----
#pragma unroll
    for (int it = 0; it < 6; ++it) {
        if (it < cnt) {
            int tI = mh * 43 + w + 8 * it;
            int p0 = tI * 16 + quad * 4;
#pragma unroll
            for (int nt = 0; nt < 3; ++nt) {
                int nl = nt * 16 + c15;
                int sbk_n = ((nl / 3) * 16 + bb) * 3 + (nl % 3);
                const float C = Cn[nl];
                unsigned short* orow = wsu + PA_OFF + (size_t)(sbk_n * 20 + t) * KP;
                if (p0 + 3 <= 1368) {
                    ushort4 st;
                    st.x = f2h(acc[it][nt][0] - C); st.y = f2h(acc[it][nt][1] - C);
                    st.z = f2h(acc[it][nt][2] - C); st.w = f2h(acc[it][nt][3] - C);
                    *(ushort4*)(orow + p0) = st;
                } else {
#pragma unroll
                    for (int r = 0; r < 4; ++r)
                        if (p0 + r <= 1368) orow[p0 + r] = f2h(acc[it][nt][r] - C);
                }
            }
        }
    }
}

// ============ k2_gemmB: raw @ wd1 -> Hraw fp32 (LDS-staged, M=64, grid 240) ============
__global__ __launch_bounds__(256)
void k2_gemmB(unsigned short* __restrict__ wsu)
{
    __shared__ __align__(16) unsigned short Bsh[16 * 512];
    __shared__ __align__(16) unsigned short As[64 * 40];

    const int tid = threadIdx.x, l = tid & 63, w = tid >> 6;
    const int c15 = l & 15, quad = l >> 4;
    const int M0 = blockIdx.x * 64;
    const unsigned short* Abase = wsu + PA_OFF;
    const unsigned short* PW = wsu + PWD_OFF;
    float* HR = (float*)(wsu + PD_OFF);

    f32x4 acc[16];
#pragma unroll
    for (int n = 0; n < 16; ++n) acc[n] = (f32x4){0.f, 0.f, 0.f, 0.f};

    for (int kt = 0; kt < NKT; ++kt) {
        __syncthreads();
        {
            const int4* src = (const int4*)(PW + (size_t)kt * 8192 + tid * 32);
            int4* dst = (int4*)(Bsh + tid * 32);
#pragma unroll
            for (int c = 0; c < 4; ++c) dst[c] = src[c];
        }
        {
            int row = tid >> 2, seg = tid & 3;
            *(int4*)(As + row * 40 + seg * 8) =
                *(const int4*)(Abase + (size_t)(M0 + row) * KP + kt * 32 + seg * 8);
        }
        __syncthreads();
        half8 af = *(const half8*)(As + (w * 16 + c15) * 40 + quad * 8);
#pragma unroll
        for (int nt = 0; nt < 16; ++nt) {
            half8 bf = *(const half8*)(Bsh + nt * 512 + l * 8);
            acc[nt] = __builtin_amdgcn_mfma_f32_16x16x32_f16(af, bf, acc[nt], 0, 0, 0);
        }
    }
#pragma unroll
    for (int nt = 0; nt < 16; ++nt) {
        const int col = nt * 16 + c15;
#pragma unroll
        for (int r = 0; r < 4; ++r) {
            const int row = M0 + w * 16 + quad * 4 + r;
            HR[(size_t)row * 256 + col] = acc[nt][r];
        }
    }
}

// ============ k1b_stats: per-row softmax stats (mx, 1/sum) -> stats buf ============
__global__ __launch_bounds__(256)
void k1b_stats(const unsigned short* __restrict__ wsu, float2* __restrict__ stats)
{
    const int l = threadIdx.x & 63, wv = threadIdx.x >> 6;
    const int row = blockIdx.x * 4 + wv;
    const unsigned* rp = (const unsigned*)(wsu + PA_OFF + (size_t)row * KP);

    float f0[11], f1[11];
    float mx = -3.0e38f;
#pragma unroll
    for (int i = 0; i < 11; ++i) {
        int q = l + i * 64;
        unsigned u = (q < 685) ? rp[q] : 0u;
        h2f h = u2h2(u);
        f0[i] = (q < 685) ? (float)h[0] : -3.0e38f;
        f1[i] = (q < 684) ? (float)h[1] : -3.0e38f;
        mx = fmaxf(mx, fmaxf(f0[i], f1[i]));
    }
    for (int o = 32; o; o >>= 1) mx = fmaxf(mx, __shfl_xor(mx, o, 64));
    float sum = 0.f;
#pragma unroll
    for (int i = 0; i < 11; ++i)
        sum += __expf(f0[i] - mx) + __expf(f1[i] - mx);
    for (int o = 32; o; o >>= 1) sum += __shfl_xor(sum, o, 64);
    if (l == 0) stats[row] = make_float2(mx, 1.0f / sum);
}

// ============ k2_gemmA: softmax-on-the-fly @ w_h1 + bias, relu -> fp16 in place ============
__global__ __launch_bounds__(256)
void k2_gemmA(unsigned short* __restrict__ wsu, const float* __restrict__ b_h1,
              const float2* __restrict__ stats)
{
    __shared__ __align__(16) unsigned short Bsh[16 * 512];
    __shared__ __align__(16) unsigned short As[64 * 40];

    const int tid = threadIdx.x, l = tid & 63, w = tid >> 6;
    const int c15 = l & 15, quad = l >> 4;
    const int M0 = blockIdx.x * 64;
    unsigned short* Abase = wsu + PA_OFF;
    const unsigned short* PW = wsu + PWH_OFF;

    const int srow = tid >> 2, sseg = tid & 3;
    const float2 st = stats[M0 + srow];

    f32x4 acc[16];
#pragma unroll
    for (int n = 0; n < 16; ++n) acc[n] = (f32x4){0.f, 0.f, 0.f, 0.f};

    for (int kt = 0; kt < NKT; ++kt) {
        __syncthreads();
        {
            const int4* src = (const int4*)(PW + (size_t)kt * 8192 + tid * 32);
            int4* dst = (int4*)(Bsh + tid * 32);
#pragma unroll
            for (int c = 0; c < 4; ++c) dst[c] = src[c];
        }
        {   // stage A with exp((raw - mx) ) * inv applied
            uint4 rv = *(const uint4*)(Abase + (size_t)(M0 + srow) * KP + kt * 32 + sseg * 8);
            unsigned* rp = (unsigned*)&rv;
            uint4 ov;
            unsigned* op = (unsigned*)&ov;
#pragma unroll
            for (int q2 = 0; q2 < 4; ++q2) {
                h2f h = u2h2(rp[q2]);
                float e0 = __expf((float)h[0] - st.x) * st.y;
                float e1 = __expf((float)h[1] - st.x) * st.y;
                op[q2] = (unsigned)f2h(e0) | ((unsigned)f2h(e1) << 16);
            }
            *(uint4*)(As + srow * 40 + sseg * 8) = ov;
        }
        __syncthreads();
        half8 af = *(const half8*)(As + (w * 16 + c15) * 40 + quad * 8);
#pragma unroll
        for (int nt = 0; nt < 16; ++nt) {
            half8 bf = *(const half8*)(Bsh + nt * 512 + l * 8);
            acc[nt] = __builtin_amdgcn_mfma_f32_16x16x32_f16(af, bf, acc[nt], 0, 0, 0);
        }
    }
#pragma unroll
    for (int nt = 0; nt < 16; ++nt) {
        const int col = nt * 16 + c15;
        const float bv = b_h1[col];
#pragma unroll
        for (int r = 0; r < 4; ++r) {
            const int row = M0 + w * 16 + quad * 4 + r;
            float v = acc[nt][r] + bv;
            v = v > 0.f ? v : 0.f;
            Abase[(size_t)row * KP + col] = f2h(v);
        }
    }
}

// ============ k2_heads: second GEMM (K=256, B LDS-staged) + in-register heads ============
template <bool PATHA>
__global__ __launch_bounds__(256)
void k2_heads(unsigned short* __restrict__ wsu,
              const float* __restrict__ b1a, const float* __restrict__ b1b,
              const float* __restrict__ w2a, const float* __restrict__ b2a,
              const float* __restrict__ w2b, const float* __restrict__ b2b,
              const float* __restrict__ bd1, float* __restrict__ out)
{
    constexpr int NT2 = PATHA ? 16 : 8;
    __shared__ __align__(16) unsigned short Bsh[NT2 * 512];
    const int tid = threadIdx.x, l = tid & 63, w = tid >> 6;
    const int c = l & 15, quad = l >> 4;
    const int M0 = blockIdx.x * 64;
    const unsigned short* PW = wsu + (PATHA ? PW2_OFF : PWD2_OFF);

    f32x4 acc[NT2];
#pragma unroll
    for (int n = 0; n < NT2; ++n) acc[n] = (f32x4){0.f, 0.f, 0.f, 0.f};

    const int row = M0 + w * 16 + c;
    const unsigned short* arow = nullptr;
    const float* h1p = nullptr; const float* h0p = nullptr;
    if (PATHA) {
        arow = wsu + PA_OFF + (size_t)row * KP + quad * 8;
    } else {
        const float* HR = (const float*)(wsu + PD_OFF);
        const int sbk = row / 19, dt = row % 19;
        h0p = HR + (size_t)(sbk * 20 + dt) * 256 + quad * 8;
        h1p = h0p + 256;
    }

    for (int kt = 0; kt < 8; ++kt) {
        __syncthreads();
        {
            const int4* src = (const int4*)(PW + (size_t)kt * (NT2 * 512) + tid * (NT2 * 2));
            int4* dst = (int4*)(Bsh + tid * (NT2 * 2));
#pragma unroll
            for (int cc = 0; cc < NT2 / 4; ++cc) dst[cc] = src[cc];
        }
        __syncthreads();
        half8 af;
        if (PATHA) {
            af = *(const half8*)(arow + kt * 32);
        } else {
            float4 a1 = *(const float4*)(h1p + kt * 32);
            float4 a1b = *(const float4*)(h1p + kt * 32 + 4);
            float4 a0 = *(const float4*)(h0p + kt * 32);
            float4 a0b = *(const float4*)(h0p + kt * 32 + 4);
            float4 bb = *(const float4*)(bd1 + kt * 32 + quad * 8);
            float4 bb2 = *(const float4*)(bd1 + kt * 32 + quad * 8 + 4);
            float v0 = fmaxf(a1.x - a0.x + bb.x, 0.f);
            float v1 = fmaxf(a1.y - a0.y + bb.y, 0.f);
            float v2 = fmaxf(a1.z - a0.z + bb.z, 0.f);
            float v3 = fmaxf(a1.w - a0.w + bb.w, 0.f);
            float v4 = fmaxf(a1b.x - a0b.x + bb2.x, 0.f);
            float v5 = fmaxf(a1b.y - a0b.y + bb2.y, 0.f);
            float v6 = fmaxf(a1b.z - a0b.z + bb2.z, 0.f);
            float v7 = fmaxf(a1b.w - a0b.w + bb2.w, 0.f);
            union { unsigned u[4]; half8 h8; } pk;
            pk.u[0] = (unsigned)f2h(v0) | ((unsigned)f2h(v1) << 16);
            pk.u[1] = (unsigned)f2h(v2) | ((unsigned)f2h(v3) << 16);
            pk.u[2] = (unsigned)f2h(v4) | ((unsigned)f2h(v5) << 16);
            pk.u[3] = (unsigned)f2h(v6) | ((unsigned)f2h(v7) << 16);
            af = pk.h8;
        }
#pragma unroll
        for (int nt = 0; nt < NT2; ++nt) {
            half8 bf = *(const half8*)(Bsh + nt * 512 + l * 8);
            acc[nt] = __builtin_amdgcn_mfma_f32_16x16x32_f16(af, bf, acc[nt], 0, 0, 0);
        }
    }
#pragma unroll
    for (int nt = 0; nt < NT2; ++nt) {
        float bv;
        if (PATHA) bv = (nt < 8) ? b1a[nt * 16 + c] : b1b[(nt - 8) * 16 + c];
        else       bv = b1a[nt * 16 + c];
#pragma unroll
        for (int r = 0; r < 4; ++r) {
            float v = acc[nt][r] + bv;
            acc[nt][r] = v > 0.f ? v : 0.f;
        }
    }
    float pm[2][4], ps[2][4];
#pragma unroll
    for (int d = 0; d < 2; ++d)
#pragma unroll
        for (int r = 0; r < 4; ++r) { pm[d][r] = 0.f; ps[d][r] = 0.f; }
#pragma unroll
    for (int d = 0; d < 2; ++d)
#pragma unroll
        for (int nt = 0; nt < 8; ++nt) {
            const float wmv = w2a[(nt * 16 + c) * 2 + d];
            float wsv = 0.f;
            if (PATHA) wsv = w2b[(nt * 16 + c) * 2 + d];
#pragma unroll
            for (int r = 0; r < 4; ++r) {
                pm[d][r] = fmaf(acc[nt][r], wmv, pm[d][r]);
                if (PATHA) ps[d][r] = fmaf(acc[nt + 8][r], wsv, ps[d][r]);
            }
        }
#pragma unroll
    for (int o = 1; o < 16; o <<= 1)
#pragma unroll
        for (int d = 0; d < 2; ++d)
#pragma unroll
            for (int r = 0; r < 4; ++r) {
                pm[d][r] += __shfl_xor(pm[d][r], o, 64);
                if (PATHA) ps[d][r] += __shfl_xor(ps[d][r], o, 64);
            }
    if (c == 0) {
#pragma unroll
        for (int r = 0; r < 4; ++r) {
            const int orow = M0 + w * 16 + quad * 4 + r;
            if (PATHA) {
                const int sbk = orow / 20, t = orow % 20;
                const int sb = sbk / 3, kk = sbk % 3;
                const int oi = ((sb * 20 + t) * 3 + kk) * 2;
                out[oi + 0] = tanhf(pm[0][r] + b2a[0]);
                out[oi + 1] = tanhf(pm[1][r] + b2a[1]);
                out[30720 + oi + 0] = __expf(ps[0][r] + b2b[0]);
                out[30720 + oi + 1] = __expf(ps[1][r] + b2b[1]);
            } else {
                const int sbk = orow / 19, dt = orow % 19;
                const int sb = sbk / 3, kk = sbk % 3;
                const int oi = 61440 + ((sb * 19 + dt) * 3 + kk) * 2;
                out[oi + 0] = tanhf(pm[0][r] + b2a[0]);
                out[oi + 1] = tanhf(pm[1][r] + b2a[1]);
            }
        }
    }
}

extern "C" void kernel_launch(void* const* d_in, const int* in_sizes, int n_in,
                              void* d_out, int out_size, void* d_ws, size_t ws_size,
                              hipStream_t stream) {
    const float* frames = (const float*)d_in[0];
    const float* digit  = (const float*)d_in[1];
    const float* w_h1   = (const float*)d_in[2];
    const float* b_h1   = (const float*)d_in[3];
    const float* wm1    = (const float*)d_in[4];
    const float* bm1    = (const float*)d_in[5];
    const float* wm2    = (const float*)d_in[6];
    const float* bm2    = (const float*)d_in[7];
    const float* ws1    = (const float*)d_in[8];
    const float* bs1    = (const float*)d_in[9];
    const float* ws2    = (const float*)d_in[10];
    const float* bs2    = (const float*)d_in[11];
    const float* wd1    = (const float*)d_in[12];
    const float* bd1    = (const float*)d_in[13];
    const float* wd2    = (const float*)d_in[14];
    const float* bd2    = (const float*)d_in[15];
    const float* wd3    = (const float*)d_in[16];
    const float* bd3    = (const float*)d_in[17];

    unsigned short* wsu = (unsigned short*)d_ws;
    float* tsum = (float*)(wsu + TSUM_OFF);
    float2* stats = (float2*)(wsu + STAT_OFF);
    float* o = (float*)d_out;

    k0_pack<<<dim3(3328), dim3(256), 0, stream>>>(w_h1, wd1, wm1, ws1, wd2, digit, wsu, tsum);
    k1a_corr<<<dim3(640), dim3(512), 0, stream>>>(frames, digit, tsum, wsu);
    k2_gemmB<<<dim3(240), dim3(256), 0, stream>>>(wsu);                        // raw -> Hraw
    k1b_stats<<<dim3(3840), dim3(256), 0, stream>>>(wsu, stats);               // softmax stats
    k2_gemmA<<<dim3(240), dim3(256), 0, stream>>>(wsu, b_h1, stats);           // fused softmax GEMM
    k2_heads<true><<<dim3(240), dim3(256), 0, stream>>>(wsu, bm1, bs1, wm2, bm2, ws2, bs2, nullptr, o);
    k2_heads<false><<<dim3(228), dim3(256), 0, stream>>>(wsu, bd2, nullptr, wd3, bd3, nullptr, nullptr, bd1, o);
}

// Round 13
// 178.310 us; speedup vs baseline: 2.0553x; 1.2115x over previous
//
#include <hip/hip_runtime.h>
#include <hip/hip_fp16.h>

typedef __attribute__((ext_vector_type(8))) _Float16 half8;
typedef __attribute__((ext_vector_type(2))) _Float16 h2f;
typedef __attribute__((ext_vector_type(4))) float f32x4;

#define NP 1369
#define KP 1376          /* padded row stride: 43 tiles of 32 */
#define NKT 43
#define ROWS_A 15360     /* 768 sbk * 20 t  */
#define ROWS_D 14592     /* 768 sbk * 19 dt */

/* ws layout (ushort units). total = 84,119,488 B <= 84.25MB proven */
#define PA_OFF   0
#define PD_OFF   (ROWS_A * KP)          /* holds Hraw fp32 15360x256 */
#define PWH_OFF  (PD_OFF + ROWS_D * KP)
#define PWD_OFF  (PWH_OFF + NKT * 16 * 512)
#define PW2_OFF  (PWD_OFF + NKT * 16 * 512)
#define PWD2_OFF (PW2_OFF + 8 * 16 * 512)
#define TSUM_OFF (PWD2_OFF + 8 * 8 * 512)   /* 768 floats */
#define STAT_OFF (TSUM_OFF + 1536)          /* 15360 float2 */

__device__ __forceinline__ unsigned short f2h(float f) {
    __half h = __float2half(f);
    return __half_as_ushort(h);
}
__device__ __forceinline__ h2f u2h2(unsigned int u) {
    h2f r; __builtin_memcpy(&r, &u, 4); return r;
}

// ============ k0: pack weights (fp16 B-frags) + tsum baselines ============
__global__ __launch_bounds__(256)
void k0_pack(const float* __restrict__ w_h1, const float* __restrict__ wd1,
             const float* __restrict__ wm1,  const float* __restrict__ ws1,
             const float* __restrict__ wd2,  const float* __restrict__ digit,
             unsigned short* __restrict__ wsu, float* __restrict__ tsum)
{
    const int tid = threadIdx.x;
    if (blockIdx.x >= 3136) {            // tsum blocks: 4 sbk per block
        const int sbk = (blockIdx.x - 3136) * 4 + (tid >> 6);
        const int l = tid & 63;
        const float* tp = digit + (size_t)sbk * 784;
        float s = 0.f;
        for (int i = l; i < 784; i += 64) s += tp[i];
        for (int o = 32; o; o >>= 1) s += __shfl_xor(s, o, 64);
        if (l == 0) tsum[sbk] = 0.5f * s;
        return;
    }
    int idx = blockIdx.x * 256 + tid;      // 0..802815
    int local, mode;
    unsigned short* dst;
    if (idx < 352256)      { mode = 0; local = idx;          dst = wsu + PWH_OFF; }
    else if (idx < 704512) { mode = 1; local = idx - 352256; dst = wsu + PWD_OFF; }
    else if (idx < 770048) { mode = 2; local = idx - 704512; dst = wsu + PW2_OFF; }
    else                   { mode = 3; local = idx - 770048; dst = wsu + PWD2_OFF; }
    int j = local & 7, lane = (local >> 3) & 63, rest = local >> 9;
    int NTn = (mode == 3) ? 8 : 16;
    int nt = rest % NTn, kt = rest / NTn;
    int k = kt * 32 + ((lane >> 4) << 3) + j;
    int n = nt * 16 + (lane & 15);
    float v = 0.f;
    if (mode == 0)      { if (k < NP) v = w_h1[k * 256 + n]; }
    else if (mode == 1) { if (k < NP) v = wd1[k * 256 + n]; }
    else if (mode == 2) { v = (n < 128) ? wm1[k * 128 + n] : ws1[k * 128 + (n - 128)]; }
    else                { v = wd2[k * 128 + n]; }
    dst[local] = f2h(v);
}

// ============ k1a: im2col MFMA correlation, N=48, split-B restaging ============
// grid 640 = (b 16) x (t 20) x (M-half 2); block 512 (8 waves). LDS 52.4KB.
__global__ __launch_bounds__(512)
void k1a_corr(const float* __restrict__ frames, const float* __restrict__ digit,
              const float* __restrict__ tsum, unsigned short* __restrict__ wsu)
{
    __shared__ __align__(16) unsigned short Bs[14 * 3 * 512];  // 43,008 B (half the kt range)
    __shared__ __align__(16) unsigned int frd[64 * 36];        // 9,216 B
    __shared__ float Cn[48];

    const int tid = threadIdx.x, l = tid & 63, w = tid >> 6;
    const int mh = blockIdx.x & 1;
    const int bt = blockIdx.x >> 1;
    const int t  = bt % 20;
    const int bb = bt / 20;

    if (tid < 48) {
        int sbk_n = ((tid / 3) * 16 + bb) * 3 + (tid % 3);
        Cn[tid] = tsum[sbk_n];
    }
    if (tid < 256) frd[(tid >> 2) * 36 + 32 + (tid & 3)] = 0u;
    {
        const float4* fp4 = (const float4*)(frames + (size_t)(bb * 20 + t) * 4096);
        for (int idx = tid; idx < 1024; idx += 512) {
            float4 v = fp4[idx];
            int r = idx >> 4, c4 = idx & 15;
            unsigned lo = (unsigned)f2h(v.x) | ((unsigned)f2h(v.y) << 16);
            unsigned hi = (unsigned)f2h(v.z) | ((unsigned)f2h(v.w) << 16);
            *(uint2*)&frd[r * 36 + c4 * 2] = make_uint2(lo, hi);
        }
    }

    const int c15 = l & 15, quad = l >> 4, v0q = quad << 3;
    const int cnt = (50 - w) / 8;        // waves 0-2: 6 tiles, 3-7: 5 tiles (43 total)

    int baseb[6]; unsigned shv[6];
#pragma unroll
    for (int it = 0; it < 6; ++it) {
        int tI = mh * 43 + w + 8 * it;
        int p  = tI * 16 + c15;
        int pc = p > 1368 ? 1368 : p;
        int i  = pc / 37;
        int jj = pc - i * 37;
        int c  = jj + v0q;
        baseb[it] = i * 144 + (c >> 1) * 4;
        shv[it]   = (unsigned)((c & 1) << 4);
    }
    f32x4 acc[6][3];
#pragma unroll
    for (int it = 0; it < 6; ++it)
#pragma unroll
        for (int nt = 0; nt < 3; ++nt) acc[it][nt] = (f32x4){0.f, 0.f, 0.f, 0.f};

    for (int ph = 0; ph < 2; ++ph) {
        __syncthreads();   // frd/Cn ready (ph0); Bs consumers done (ph1)
        // ---- stage B for kt = ph*14 .. ph*14+13 ----
        for (int s = tid; s < 2688; s += 512) {
            int ktl = s / 192;
            int rem = s - ktl * 192;
            int nt = rem >> 6, sl = rem & 63;
            int nl = nt * 16 + (sl & 15);
            int v0 = (sl >> 4) << 3;
            int kt = ph * 14 + ktl;
            int sbk_n = ((nl / 3) * 16 + bb) * 3 + (nl % 3);
            const float* tp = digit + (size_t)sbk_n * 784 + kt * 28 + v0;
            float4 fa = *(const float4*)tp;
            float4 fb = (v0 <= 16) ? *(const float4*)(tp + 4) : make_float4(0.f, 0.f, 0.f, 0.f);
            uint4 pk;
            pk.x = (unsigned)f2h(fa.x) | ((unsigned)f2h(fa.y) << 16);
            pk.y = (unsigned)f2h(fa.z) | ((unsigned)f2h(fa.w) << 16);
            pk.z = (unsigned)f2h(fb.x) | ((unsigned)f2h(fb.y) << 16);
            pk.w = (unsigned)f2h(fb.z) | ((unsigned)f2h(fb.w) << 16);
            *(uint4*)(Bs + s * 8) = pk;
        }
        __syncthreads();

        for (int ktl = 0; ktl < 14; ++ktl) {
            const int kt = ph * 14 + ktl;
            half8 bf0 = *(const half8*)(Bs + ktl * 1536 + 0 * 512 + l * 8);
            half8 bf1 = *(const half8*)(Bs + ktl * 1536 + 1 * 512 + l * 8);
            half8 bf2 = *(const half8*)(Bs + ktl * 1536 + 2 * 512 + l * 8);
            const char* fbase = (const char*)frd + kt * 144;
#pragma unroll
            for (int it = 0; it < 6; ++it) {
                if (it < cnt) {
                    const char* ap = fbase + baseb[it];
                    unsigned w0 = *(const unsigned*)(ap);
                    unsigned w1 = *(const unsigned*)(ap + 4);
                    unsigned w2 = *(const unsigned*)(ap + 8);
                    unsigned w3 = *(const unsigned*)(ap + 12);
                    unsigned w4 = *(const unsigned*)(ap + 16);
                    unsigned sh = shv[it];
                    union { unsigned u[4]; half8 h8; } af;
                    af.u[0] = (unsigned)(((((unsigned long long)w1) << 32) | w0) >> sh);
                    af.u[1] = (unsigned)(((((unsigned long long)w2) << 32) | w1) >> sh);
                    af.u[2] = (unsigned)(((((unsigned long long)w3) << 32) | w2) >> sh);
                    af.u[3] = (unsigned)(((((unsigned long long)w4) << 32) | w3) >> sh);
                    acc[it][0] = __builtin_amdgcn_mfma_f32_16x16x32_f16(af.h8, bf0, acc[it][0], 0, 0, 0);
                    acc[it][1] = __builtin_amdgcn_mfma_f32_16x16x32_f16(af.h8, bf1, acc[it][1], 0, 0, 0);
                    acc[it][2] = __builtin_amdgcn_mfma_f32_16x16x32_f16(af.h8, bf2, acc[it][2], 0, 0, 0);
                }
            }
        }
    }
    // ---- epilogue: conv - C -> fp16 rows of PA ----
#pragma unroll
    for (int it = 0; it < 6; ++it) {
        if (it < cnt) {
            int tI = mh * 43 + w + 8 * it;
            int p0 = tI * 16 + quad * 4;
#pragma unroll
            for (int nt = 0; nt < 3; ++nt) {
                int nl = nt * 16 + c15;
                int sbk_n = ((nl / 3) * 16 + bb) * 3 + (nl % 3);
                const float C = Cn[nl];
                unsigned short* orow = wsu + PA_OFF + (size_t)(sbk_n * 20 + t) * KP;
                if (p0 + 3 <= 1368) {
                    ushort4 st;
                    st.x = f2h(acc[it][nt][0] - C); st.y = f2h(acc[it][nt][1] - C);
                    st.z = f2h(acc[it][nt][2] - C); st.w = f2h(acc[it][nt][3] - C);
                    *(ushort4*)(orow + p0) = st;
                } else {
#pragma unroll
                    for (int r = 0; r < 4; ++r)
                        if (p0 + r <= 1368) orow[p0 + r] = f2h(acc[it][nt][r] - C);
                }
            }
        }
    }
}

// ============ k1b_stats: per-row softmax stats (mx, 1/sum) -> stats buf ============
__global__ __launch_bounds__(256)
void k1b_stats(const unsigned short* __restrict__ wsu, float2* __restrict__ stats)
{
    const int l = threadIdx.x & 63, wv = threadIdx.x >> 6;
    const int row = blockIdx.x * 4 + wv;
    const unsigned* rp = (const unsigned*)(wsu + PA_OFF + (size_t)row * KP);

    float f0[11], f1[11];
    float mx = -3.0e38f;
#pragma unroll
    for (int i = 0; i < 11; ++i) {
        int q = l + i * 64;
        unsigned u = (q < 685) ? rp[q] : 0u;
        h2f h = u2h2(u);
        f0[i] = (q < 685) ? (float)h[0] : -3.0e38f;
        f1[i] = (q < 684) ? (float)h[1] : -3.0e38f;
        mx = fmaxf(mx, fmaxf(f0[i], f1[i]));
    }
    for (int o = 32; o; o >>= 1) mx = fmaxf(mx, __shfl_xor(mx, o, 64));
    float sum = 0.f;
#pragma unroll
    for (int i = 0; i < 11; ++i)
        sum += __expf(f0[i] - mx) + __expf(f1[i] - mx);
    for (int o = 32; o; o >>= 1) sum += __shfl_xor(sum, o, 64);
    if (l == 0) stats[row] = make_float2(mx, 1.0f / sum);
}

// ============ k2_gemmAB: merged {softmax@w_h1 -> hidden} + {raw@wd1 -> Hraw} ============
// grid 240, block 256, M=64. Per kt: stage BshH+BshD (32KB) + raw/exp A tiles; 32 MFMAs.
__global__ __launch_bounds__(256)
void k2_gemmAB(unsigned short* __restrict__ wsu, const float* __restrict__ b_h1,
               const float2* __restrict__ stats)
{
    __shared__ __align__(16) unsigned short BshH[16 * 512];
    __shared__ __align__(16) unsigned short BshD[16 * 512];
    __shared__ __align__(16) unsigned short AsR[64 * 40];
    __shared__ __align__(16) unsigned short AsE[64 * 40];

    const int tid = threadIdx.x, l = tid & 63, w = tid >> 6;
    const int c15 = l & 15, quad = l >> 4;
    const int M0 = blockIdx.x * 64;
    unsigned short* Abase = wsu + PA_OFF;
    const unsigned short* PWH = wsu + PWH_OFF;
    const unsigned short* PWD = wsu + PWD_OFF;
    float* HR = (float*)(wsu + PD_OFF);

    const int srow = tid >> 2, sseg = tid & 3;
    const float2 st = stats[M0 + srow];

    f32x4 accH[16], accD[16];
#pragma unroll
    for (int n = 0; n < 16; ++n) {
        accH[n] = (f32x4){0.f, 0.f, 0.f, 0.f};
        accD[n] = (f32x4){0.f, 0.f, 0.f, 0.f};
    }

    for (int kt = 0; kt < NKT; ++kt) {
        __syncthreads();
        {   // stage both B tiles (64B/thread each)
            const int4* srcH = (const int4*)(PWH + (size_t)kt * 8192 + tid * 32);
            const int4* srcD = (const int4*)(PWD + (size_t)kt * 8192 + tid * 32);
            int4* dstH = (int4*)(BshH + tid * 32);
            int4* dstD = (int4*)(BshD + tid * 32);
#pragma unroll
            for (int c = 0; c < 4; ++c) { dstH[c] = srcH[c]; dstD[c] = srcD[c]; }
        }
        {   // stage raw A tile + exp-transformed copy (thread-local, no race)
            uint4 rv = *(const uint4*)(Abase + (size_t)(M0 + srow) * KP + kt * 32 + sseg * 8);
            *(uint4*)(AsR + srow * 40 + sseg * 8) = rv;
            unsigned* rp = (unsigned*)&rv;
            uint4 ov;
            unsigned* op = (unsigned*)&ov;
#pragma unroll
            for (int q2 = 0; q2 < 4; ++q2) {
                h2f h = u2h2(rp[q2]);
                float e0 = __expf((float)h[0] - st.x) * st.y;
                float e1 = __expf((float)h[1] - st.x) * st.y;
                op[q2] = (unsigned)f2h(e0) | ((unsigned)f2h(e1) << 16);
            }
            *(uint4*)(AsE + srow * 40 + sseg * 8) = ov;
        }
        __syncthreads();
        half8 afR = *(const half8*)(AsR + (w * 16 + c15) * 40 + quad * 8);
        half8 afE = *(const half8*)(AsE + (w * 16 + c15) * 40 + quad * 8);
#pragma unroll
        for (int nt = 0; nt < 16; ++nt) {
            half8 bfH = *(const half8*)(BshH + nt * 512 + l * 8);
            half8 bfD = *(const half8*)(BshD + nt * 512 + l * 8);
            accH[nt] = __builtin_amdgcn_mfma_f32_16x16x32_f16(afE, bfH, accH[nt], 0, 0, 0);
            accD[nt] = __builtin_amdgcn_mfma_f32_16x16x32_f16(afR, bfD, accD[nt], 0, 0, 0);
        }
    }
#pragma unroll
    for (int nt = 0; nt < 16; ++nt) {
        const int col = nt * 16 + c15;
        const float bv = b_h1[col];
#pragma unroll
        for (int r = 0; r < 4; ++r) {
            const int row = M0 + w * 16 + quad * 4 + r;
            float v = accH[nt][r] + bv;
            Abase[(size_t)row * KP + col] = f2h(v > 0.f ? v : 0.f);
            HR[(size_t)row * 256 + col] = accD[nt][r];
        }
    }
}

// ============ k2_heads: second GEMM (K=256, B LDS-staged) + in-register heads ============
template <bool PATHA>
__global__ __launch_bounds__(256)
void k2_heads(unsigned short* __restrict__ wsu,
              const float* __restrict__ b1a, const float* __restrict__ b1b,
              const float* __restrict__ w2a, const float* __restrict__ b2a,
              const float* __restrict__ w2b, const float* __restrict__ b2b,
              const float* __restrict__ bd1, float* __restrict__ out)
{
    constexpr int NT2 = PATHA ? 16 : 8;
    __shared__ __align__(16) unsigned short Bsh[NT2 * 512];
    const int tid = threadIdx.x, l = tid & 63, w = tid >> 6;
    const int c = l & 15, quad = l >> 4;
    const int M0 = blockIdx.x * 64;
    const unsigned short* PW = wsu + (PATHA ? PW2_OFF : PWD2_OFF);

    f32x4 acc[NT2];
#pragma unroll
    for (int n = 0; n < NT2; ++n) acc[n] = (f32x4){0.f, 0.f, 0.f, 0.f};

    const int row = M0 + w * 16 + c;
    const unsigned short* arow = nullptr;
    const float* h1p = nullptr; const float* h0p = nullptr;
    if (PATHA) {
        arow = wsu + PA_OFF + (size_t)row * KP + quad * 8;
    } else {
        const float* HR = (const float*)(wsu + PD_OFF);
        const int sbk = row / 19, dt = row % 19;
        h0p = HR + (size_t)(sbk * 20 + dt) * 256 + quad * 8;
        h1p = h0p + 256;
    }

    for (int kt = 0; kt < 8; ++kt) {
        __syncthreads();
        {
            const int4* src = (const int4*)(PW + (size_t)kt * (NT2 * 512) + tid * (NT2 * 2));
            int4* dst = (int4*)(Bsh + tid * (NT2 * 2));
#pragma unroll
            for (int cc = 0; cc < NT2 / 4; ++cc) dst[cc] = src[cc];
        }
        __syncthreads();
        half8 af;
        if (PATHA) {
            af = *(const half8*)(arow + kt * 32);
        } else {
            float4 a1 = *(const float4*)(h1p + kt * 32);
            float4 a1b = *(const float4*)(h1p + kt * 32 + 4);
            float4 a0 = *(const float4*)(h0p + kt * 32);
            float4 a0b = *(const float4*)(h0p + kt * 32 + 4);
            float4 bb = *(const float4*)(bd1 + kt * 32 + quad * 8);
            float4 bb2 = *(const float4*)(bd1 + kt * 32 + quad * 8 + 4);
            float v0 = fmaxf(a1.x - a0.x + bb.x, 0.f);
            float v1 = fmaxf(a1.y - a0.y + bb.y, 0.f);
            float v2 = fmaxf(a1.z - a0.z + bb.z, 0.f);
            float v3 = fmaxf(a1.w - a0.w + bb.w, 0.f);
            float v4 = fmaxf(a1b.x - a0b.x + bb2.x, 0.f);
            float v5 = fmaxf(a1b.y - a0b.y + bb2.y, 0.f);
            float v6 = fmaxf(a1b.z - a0b.z + bb2.z, 0.f);
            float v7 = fmaxf(a1b.w - a0b.w + bb2.w, 0.f);
            union { unsigned u[4]; half8 h8; } pk;
            pk.u[0] = (unsigned)f2h(v0) | ((unsigned)f2h(v1) << 16);
            pk.u[1] = (unsigned)f2h(v2) | ((unsigned)f2h(v3) << 16);
            pk.u[2] = (unsigned)f2h(v4) | ((unsigned)f2h(v5) << 16);
            pk.u[3] = (unsigned)f2h(v6) | ((unsigned)f2h(v7) << 16);
            af = pk.h8;
        }
#pragma unroll
        for (int nt = 0; nt < NT2; ++nt) {
            half8 bf = *(const half8*)(Bsh + nt * 512 + l * 8);
            acc[nt] = __builtin_amdgcn_mfma_f32_16x16x32_f16(af, bf, acc[nt], 0, 0, 0);
        }
    }
#pragma unroll
    for (int nt = 0; nt < NT2; ++nt) {
        float bv;
        if (PATHA) bv = (nt < 8) ? b1a[nt * 16 + c] : b1b[(nt - 8) * 16 + c];
        else       bv = b1a[nt * 16 + c];
#pragma unroll
        for (int r = 0; r < 4; ++r) {
            float v = acc[nt][r] + bv;
            acc[nt][r] = v > 0.f ? v : 0.f;
        }
    }
    float pm[2][4], ps[2][4];
#pragma unroll
    for (int d = 0; d < 2; ++d)
#pragma unroll
        for (int r = 0; r < 4; ++r) { pm[d][r] = 0.f; ps[d][r] = 0.f; }
#pragma unroll
    for (int d = 0; d < 2; ++d)
#pragma unroll
        for (int nt = 0; nt < 8; ++nt) {
            const float wmv = w2a[(nt * 16 + c) * 2 + d];
            float wsv = 0.f;
            if (PATHA) wsv = w2b[(nt * 16 + c) * 2 + d];
#pragma unroll
            for (int r = 0; r < 4; ++r) {
                pm[d][r] = fmaf(acc[nt][r], wmv, pm[d][r]);
                if (PATHA) ps[d][r] = fmaf(acc[nt + 8][r], wsv, ps[d][r]);
            }
        }
#pragma unroll
    for (int o = 1; o < 16; o <<= 1)
#pragma unroll
        for (int d = 0; d < 2; ++d)
#pragma unroll
            for (int r = 0; r < 4; ++r) {
                pm[d][r] += __shfl_xor(pm[d][r], o, 64);
                if (PATHA) ps[d][r] += __shfl_xor(ps[d][r], o, 64);
            }
    if (c == 0) {
#pragma unroll
        for (int r = 0; r < 4; ++r) {
            const int orow = M0 + w * 16 + quad * 4 + r;
            if (PATHA) {
                const int sbk = orow / 20, t = orow % 20;
                const int sb = sbk / 3, kk = sbk % 3;
                const int oi = ((sb * 20 + t) * 3 + kk) * 2;
                out[oi + 0] = tanhf(pm[0][r] + b2a[0]);
                out[oi + 1] = tanhf(pm[1][r] + b2a[1]);
                out[30720 + oi + 0] = __expf(ps[0][r] + b2b[0]);
                out[30720 + oi + 1] = __expf(ps[1][r] + b2b[1]);
            } else {
                const int sbk = orow / 19, dt = orow % 19;
                const int sb = sbk / 3, kk = sbk % 3;
                const int oi = 61440 + ((sb * 19 + dt) * 3 + kk) * 2;
                out[oi + 0] = tanhf(pm[0][r] + b2a[0]);
                out[oi + 1] = tanhf(pm[1][r] + b2a[1]);
            }
        }
    }
}

extern "C" void kernel_launch(void* const* d_in, const int* in_sizes, int n_in,
                              void* d_out, int out_size, void* d_ws, size_t ws_size,
                              hipStream_t stream) {
    const float* frames = (const float*)d_in[0];
    const float* digit  = (const float*)d_in[1];
    const float* w_h1   = (const float*)d_in[2];
    const float* b_h1   = (const float*)d_in[3];
    const float* wm1    = (const float*)d_in[4];
    const float* bm1    = (const float*)d_in[5];
    const float* wm2    = (const float*)d_in[6];
    const float* bm2    = (const float*)d_in[7];
    const float* ws1    = (const float*)d_in[8];
    const float* bs1    = (const float*)d_in[9];
    const float* ws2    = (const float*)d_in[10];
    const float* bs2    = (const float*)d_in[11];
    const float* wd1    = (const float*)d_in[12];
    const float* bd1    = (const float*)d_in[13];
    const float* wd2    = (const float*)d_in[14];
    const float* bd2    = (const float*)d_in[15];
    const float* wd3    = (const float*)d_in[16];
    const float* bd3    = (const float*)d_in[17];

    unsigned short* wsu = (unsigned short*)d_ws;
    float* tsum = (float*)(wsu + TSUM_OFF);
    float2* stats = (float2*)(wsu + STAT_OFF);
    float* o = (float*)d_out;

    k0_pack<<<dim3(3328), dim3(256), 0, stream>>>(w_h1, wd1, wm1, ws1, wd2, digit, wsu, tsum);
    k1a_corr<<<dim3(640), dim3(512), 0, stream>>>(frames, digit, tsum, wsu);
    k1b_stats<<<dim3(3840), dim3(256), 0, stream>>>(wsu, stats);               // softmax stats
    k2_gemmAB<<<dim3(240), dim3(256), 0, stream>>>(wsu, b_h1, stats);          // fused hidden+Hraw
    k2_heads<true><<<dim3(240), dim3(256), 0, stream>>>(wsu, bm1, bs1, wm2, bm2, ws2, bs2, nullptr, o);
    k2_heads<false><<<dim3(228), dim3(256), 0, stream>>>(wsu, bd2, nullptr, wd3, bd3, nullptr, nullptr, bd1, o);
}

// Round 14
// 175.658 us; speedup vs baseline: 2.0864x; 1.0151x over previous
//
#include <hip/hip_runtime.h>
#include <hip/hip_fp16.h>

typedef __attribute__((ext_vector_type(8))) _Float16 half8;
typedef __attribute__((ext_vector_type(2))) _Float16 h2f;
typedef __attribute__((ext_vector_type(4))) float f32x4;

#define NP 1369
#define KP 1376          /* padded row stride: 43 tiles of 32 */
#define NKT 43
#define ROWS_A 15360     /* 768 sbk * 20 t  */
#define ROWS_D 14592     /* 768 sbk * 19 dt */

/* ws layout (ushort units). total = 84,119,488 B <= 84.25MB proven */
#define PA_OFF   0
#define PD_OFF   (ROWS_A * KP)          /* holds Hraw fp32 15360x256 */
#define PWH_OFF  (PD_OFF + ROWS_D * KP)
#define PWD_OFF  (PWH_OFF + NKT * 16 * 512)
#define PW2_OFF  (PWD_OFF + NKT * 16 * 512)
#define PWD2_OFF (PW2_OFF + 8 * 16 * 512)
#define TSUM_OFF (PWD2_OFF + 8 * 8 * 512)   /* 768 floats */
#define STAT_OFF (TSUM_OFF + 1536)          /* 15360 float2 */

__device__ __forceinline__ unsigned short f2h(float f) {
    __half h = __float2half(f);
    return __half_as_ushort(h);
}
__device__ __forceinline__ h2f u2h2(unsigned int u) {
    h2f r; __builtin_memcpy(&r, &u, 4); return r;
}

// ============ k0: pack weights (fp16 B-frags) + tsum baselines ============
__global__ __launch_bounds__(256)
void k0_pack(const float* __restrict__ w_h1, const float* __restrict__ wd1,
             const float* __restrict__ wm1,  const float* __restrict__ ws1,
             const float* __restrict__ wd2,  const float* __restrict__ digit,
             unsigned short* __restrict__ wsu, float* __restrict__ tsum)
{
    const int tid = threadIdx.x;
    if (blockIdx.x >= 3136) {            // tsum blocks: 4 sbk per block
        const int sbk = (blockIdx.x - 3136) * 4 + (tid >> 6);
        const int l = tid & 63;
        const float* tp = digit + (size_t)sbk * 784;
        float s = 0.f;
        for (int i = l; i < 784; i += 64) s += tp[i];
        for (int o = 32; o; o >>= 1) s += __shfl_xor(s, o, 64);
        if (l == 0) tsum[sbk] = 0.5f * s;
        return;
    }
    int idx = blockIdx.x * 256 + tid;      // 0..802815
    int local, mode;
    unsigned short* dst;
    if (idx < 352256)      { mode = 0; local = idx;          dst = wsu + PWH_OFF; }
    else if (idx < 704512) { mode = 1; local = idx - 352256; dst = wsu + PWD_OFF; }
    else if (idx < 770048) { mode = 2; local = idx - 704512; dst = wsu + PW2_OFF; }
    else                   { mode = 3; local = idx - 770048; dst = wsu + PWD2_OFF; }
    int j = local & 7, lane = (local >> 3) & 63, rest = local >> 9;
    int NTn = (mode == 3) ? 8 : 16;
    int nt = rest % NTn, kt = rest / NTn;
    int k = kt * 32 + ((lane >> 4) << 3) + j;
    int n = nt * 16 + (lane & 15);
    float v = 0.f;
    if (mode == 0)      { if (k < NP) v = w_h1[k * 256 + n]; }
    else if (mode == 1) { if (k < NP) v = wd1[k * 256 + n]; }
    else if (mode == 2) { v = (n < 128) ? wm1[k * 128 + n] : ws1[k * 128 + (n - 128)]; }
    else                { v = wd2[k * 128 + n]; }
    dst[local] = f2h(v);
}

// ============ k1a: im2col MFMA correlation, N=48, split-B restaging ============
// grid 640 = (b 16) x (t 20) x (M-half 2); block 512 (8 waves). LDS 52.4KB.
__global__ __launch_bounds__(512)
void k1a_corr(const float* __restrict__ frames, const float* __restrict__ digit,
              const float* __restrict__ tsum, unsigned short* __restrict__ wsu)
{
    __shared__ __align__(16) unsigned short Bs[14 * 3 * 512];  // 43,008 B (half the kt range)
    __shared__ __align__(16) unsigned int frd[64 * 36];        // 9,216 B
    __shared__ float Cn[48];

    const int tid = threadIdx.x, l = tid & 63, w = tid >> 6;
    const int mh = blockIdx.x & 1;
    const int bt = blockIdx.x >> 1;
    const int t  = bt % 20;
    const int bb = bt / 20;

    if (tid < 48) {
        int sbk_n = ((tid / 3) * 16 + bb) * 3 + (tid % 3);
        Cn[tid] = tsum[sbk_n];
    }
    if (tid < 256) frd[(tid >> 2) * 36 + 32 + (tid & 3)] = 0u;
    {
        const float4* fp4 = (const float4*)(frames + (size_t)(bb * 20 + t) * 4096);
        for (int idx = tid; idx < 1024; idx += 512) {
            float4 v = fp4[idx];
            int r = idx >> 4, c4 = idx & 15;
            unsigned lo = (unsigned)f2h(v.x) | ((unsigned)f2h(v.y) << 16);
            unsigned hi = (unsigned)f2h(v.z) | ((unsigned)f2h(v.w) << 16);
            *(uint2*)&frd[r * 36 + c4 * 2] = make_uint2(lo, hi);
        }
    }

    const int c15 = l & 15, quad = l >> 4, v0q = quad << 3;
    const int cnt = (50 - w) / 8;        // waves 0-2: 6 tiles, 3-7: 5 tiles (43 total)

    int baseb[6]; unsigned shv[6];
#pragma unroll
    for (int it = 0; it < 6; ++it) {
        int tI = mh * 43 + w + 8 * it;
        int p  = tI * 16 + c15;
        int pc = p > 1368 ? 1368 : p;
        int i  = pc / 37;
        int jj = pc - i * 37;
        int c  = jj + v0q;
        baseb[it] = i * 144 + (c >> 1) * 4;
        shv[it]   = (unsigned)((c & 1) << 4);
    }
    f32x4 acc[6][3];
#pragma unroll
    for (int it = 0; it < 6; ++it)
#pragma unroll
        for (int nt = 0; nt < 3; ++nt) acc[it][nt] = (f32x4){0.f, 0.f, 0.f, 0.f};

    for (int ph = 0; ph < 2; ++ph) {
        __syncthreads();   // frd/Cn ready (ph0); Bs consumers done (ph1)
        // ---- stage B for kt = ph*14 .. ph*14+13 ----
        for (int s = tid; s < 2688; s += 512) {
            int ktl = s / 192;
            int rem = s - ktl * 192;
            int nt = rem >> 6, sl = rem & 63;
            int nl = nt * 16 + (sl & 15);
            int v0 = (sl >> 4) << 3;
            int kt = ph * 14 + ktl;
            int sbk_n = ((nl / 3) * 16 + bb) * 3 + (nl % 3);
            const float* tp = digit + (size_t)sbk_n * 784 + kt * 28 + v0;
            float4 fa = *(const float4*)tp;
            float4 fb = (v0 <= 16) ? *(const float4*)(tp + 4) : make_float4(0.f, 0.f, 0.f, 0.f);
            uint4 pk;
            pk.x = (unsigned)f2h(fa.x) | ((unsigned)f2h(fa.y) << 16);
            pk.y = (unsigned)f2h(fa.z) | ((unsigned)f2h(fa.w) << 16);
            pk.z = (unsigned)f2h(fb.x) | ((unsigned)f2h(fb.y) << 16);
            pk.w = (unsigned)f2h(fb.z) | ((unsigned)f2h(fb.w) << 16);
            *(uint4*)(Bs + s * 8) = pk;
        }
        __syncthreads();

        for (int ktl = 0; ktl < 14; ++ktl) {
            const int kt = ph * 14 + ktl;
            half8 bf0 = *(const half8*)(Bs + ktl * 1536 + 0 * 512 + l * 8);
            half8 bf1 = *(const half8*)(Bs + ktl * 1536 + 1 * 512 + l * 8);
            half8 bf2 = *(const half8*)(Bs + ktl * 1536 + 2 * 512 + l * 8);
            const char* fbase = (const char*)frd + kt * 144;
#pragma unroll
            for (int it = 0; it < 6; ++it) {
                if (it < cnt) {
                    const char* ap = fbase + baseb[it];
                    unsigned w0 = *(const unsigned*)(ap);
                    unsigned w1 = *(const unsigned*)(ap + 4);
                    unsigned w2 = *(const unsigned*)(ap + 8);
                    unsigned w3 = *(const unsigned*)(ap + 12);
                    unsigned w4 = *(const unsigned*)(ap + 16);
                    unsigned sh = shv[it];
                    union { unsigned u[4]; half8 h8; } af;
                    af.u[0] = (unsigned)(((((unsigned long long)w1) << 32) | w0) >> sh);
                    af.u[1] = (unsigned)(((((unsigned long long)w2) << 32) | w1) >> sh);
                    af.u[2] = (unsigned)(((((unsigned long long)w3) << 32) | w2) >> sh);
                    af.u[3] = (unsigned)(((((unsigned long long)w4) << 32) | w3) >> sh);
                    acc[it][0] = __builtin_amdgcn_mfma_f32_16x16x32_f16(af.h8, bf0, acc[it][0], 0, 0, 0);
                    acc[it][1] = __builtin_amdgcn_mfma_f32_16x16x32_f16(af.h8, bf1, acc[it][1], 0, 0, 0);
                    acc[it][2] = __builtin_amdgcn_mfma_f32_16x16x32_f16(af.h8, bf2, acc[it][2], 0, 0, 0);
                }
            }
        }
    }
    // ---- epilogue: conv - C -> fp16 rows of PA ----
#pragma unroll
    for (int it = 0; it < 6; ++it) {
        if (it < cnt) {
            int tI = mh * 43 + w + 8 * it;
            int p0 = tI * 16 + quad * 4;
#pragma unroll
            for (int nt = 0; nt < 3; ++nt) {
                int nl = nt * 16 + c15;
                int sbk_n = ((nl / 3) * 16 + bb) * 3 + (nl % 3);
                const float C = Cn[nl];
                unsigned short* orow = wsu + PA_OFF + (size_t)(sbk_n * 20 + t) * KP;
                if (p0 + 3 <= 1368) {
                    ushort4 st;
                    st.x = f2h(acc[it][nt][0] - C); st.y = f2h(acc[it][nt][1] - C);
                    st.z = f2h(acc[it][nt][2] - C); st.w = f2h(acc[it][nt][3] - C);
                    *(ushort4*)(orow + p0) = st;
                } else {
#pragma unroll
                    for (int r = 0; r < 4; ++r)
                        if (p0 + r <= 1368) orow[p0 + r] = f2h(acc[it][nt][r] - C);
                }
            }
        }
    }
}

// ============ k1b_stats: per-row softmax stats (mx, 1/sum) -> stats buf ============
__global__ __launch_bounds__(256)
void k1b_stats(const unsigned short* __restrict__ wsu, float2* __restrict__ stats)
{
    const int l = threadIdx.x & 63, wv = threadIdx.x >> 6;
    const int row = blockIdx.x * 4 + wv;
    const unsigned* rp = (const unsigned*)(wsu + PA_OFF + (size_t)row * KP);

    float f0[11], f1[11];
    float mx = -3.0e38f;
#pragma unroll
    for (int i = 0; i < 11; ++i) {
        int q = l + i * 64;
        unsigned u = (q < 685) ? rp[q] : 0u;
        h2f h = u2h2(u);
        f0[i] = (q < 685) ? (float)h[0] : -3.0e38f;
        f1[i] = (q < 684) ? (float)h[1] : -3.0e38f;
        mx = fmaxf(mx, fmaxf(f0[i], f1[i]));
    }
    for (int o = 32; o; o >>= 1) mx = fmaxf(mx, __shfl_xor(mx, o, 64));
    float sum = 0.f;
#pragma unroll
    for (int i = 0; i < 11; ++i)
        sum += __expf(f0[i] - mx) + __expf(f1[i] - mx);
    for (int o = 32; o; o >>= 1) sum += __shfl_xor(sum, o, 64);
    if (l == 0) stats[row] = make_float2(mx, 1.0f / sum);
}

// ============ k2_gemmAB: merged GEMMs, 2 row-tiles/wave, A from global, B dbuf ============
// grid 240, block 256 (4 waves). Waves 0-1: H (softmax@w_h1); 2-3: D (raw@wd1 -> Hraw).
__global__ __launch_bounds__(256)
void k2_gemmAB(unsigned short* __restrict__ wsu, const float* __restrict__ b_h1,
               const float2* __restrict__ stats)
{
    __shared__ __align__(16) unsigned short Bbuf[2][2 * 8192];   // [dbuf][{H,D} tiles] 64KB

    const int tid = threadIdx.x, l = tid & 63, w = tid >> 6;
    const int c15 = l & 15, quad = l >> 4;
    const int M0 = blockIdx.x * 64;
    unsigned short* Abase = wsu + PA_OFF;
    const unsigned short* PWH = wsu + PWH_OFF;
    const unsigned short* PWD = wsu + PWD_OFF;
    float* HR = (float*)(wsu + PD_OFF);

    const bool isH = (w < 2);
    const int rt0 = M0 + (w & 1) * 32;
    const int row0 = rt0 + c15, row1 = rt0 + 16 + c15;
    const unsigned short* a0p = Abase + (size_t)row0 * KP + quad * 8;
    const unsigned short* a1p = Abase + (size_t)row1 * KP + quad * 8;
    float2 st0 = make_float2(0.f, 0.f), st1 = make_float2(0.f, 0.f);
    if (isH) { st0 = stats[row0]; st1 = stats[row1]; }

    f32x4 acc[2][16];
#pragma unroll
    for (int m = 0; m < 2; ++m)
#pragma unroll
        for (int n = 0; n < 16; ++n) acc[m][n] = (f32x4){0.f, 0.f, 0.f, 0.f};

    // prologue: stage B(kt=0) into buf 0 (64B per thread per matrix)
    {
        const int4* sH = (const int4*)(PWH + tid * 32);
        const int4* sD = (const int4*)(PWD + tid * 32);
        int4* dH = (int4*)(Bbuf[0] + tid * 32);
        int4* dD = (int4*)(Bbuf[0] + 8192 + tid * 32);
#pragma unroll
        for (int c = 0; c < 4; ++c) { dH[c] = sH[c]; dD[c] = sD[c]; }
    }
    __syncthreads();

    for (int kt = 0; kt < NKT; ++kt) {
        const int db = kt & 1;
        // ---- A fragments for this kt (global, 16B/lane) ----
        half8 afA = *(const half8*)(a0p + kt * 32);
        half8 afB = *(const half8*)(a1p + kt * 32);
        if (isH) {   // exp transform in registers (same numerics as staged version)
            union { half8 h8; unsigned u[4]; } ia, ib, oa, ob;
            ia.h8 = afA; ib.h8 = afB;
#pragma unroll
            for (int q = 0; q < 4; ++q) {
                h2f ha = u2h2(ia.u[q]);
                h2f hb = u2h2(ib.u[q]);
                float a0 = __expf((float)ha[0] - st0.x) * st0.y;
                float a1 = __expf((float)ha[1] - st0.x) * st0.y;
                float b0 = __expf((float)hb[0] - st1.x) * st1.y;
                float b1 = __expf((float)hb[1] - st1.x) * st1.y;
                oa.u[q] = (unsigned)f2h(a0) | ((unsigned)f2h(a1) << 16);
                ob.u[q] = (unsigned)f2h(b0) | ((unsigned)f2h(b1) << 16);
            }
            afA = oa.h8; afB = ob.h8;
        }
        // ---- prefetch next kt's B tiles into registers ----
        int4 rH[4], rD[4];
        if (kt + 1 < NKT) {
            const int4* sH = (const int4*)(PWH + (size_t)(kt + 1) * 8192 + tid * 32);
            const int4* sD = (const int4*)(PWD + (size_t)(kt + 1) * 8192 + tid * 32);
#pragma unroll
            for (int c = 0; c < 4; ++c) { rH[c] = sH[c]; rD[c] = sD[c]; }
        }
        // ---- MFMA: 16 bf reads feed 32 MFMAs (2 row-tiles) ----
        const unsigned short* bb = Bbuf[db] + (isH ? 0 : 8192);
#pragma unroll
        for (int nt = 0; nt < 16; ++nt) {
            half8 bf = *(const half8*)(bb + nt * 512 + l * 8);
            acc[0][nt] = __builtin_amdgcn_mfma_f32_16x16x32_f16(afA, bf, acc[0][nt], 0, 0, 0);
            acc[1][nt] = __builtin_amdgcn_mfma_f32_16x16x32_f16(afB, bf, acc[1][nt], 0, 0, 0);
        }
        // ---- write staged B to the other buffer ----
        if (kt + 1 < NKT) {
            int4* dH = (int4*)(Bbuf[db ^ 1] + tid * 32);
            int4* dD = (int4*)(Bbuf[db ^ 1] + 8192 + tid * 32);
#pragma unroll
            for (int c = 0; c < 4; ++c) { dH[c] = rH[c]; dD[c] = rD[c]; }
        }
        __syncthreads();
    }

    // ---- epilogue ----
    if (isH) {
#pragma unroll
        for (int nt = 0; nt < 16; ++nt) {
            const int col = nt * 16 + c15;
            const float bv = b_h1[col];
#pragma unroll
            for (int m = 0; m < 2; ++m)
#pragma unroll
                for (int r = 0; r < 4; ++r) {
                    const int row = rt0 + m * 16 + quad * 4 + r;
                    float v = acc[m][nt][r] + bv;
                    Abase[(size_t)row * KP + col] = f2h(v > 0.f ? v : 0.f);
                }
        }
    } else {
#pragma unroll
        for (int nt = 0; nt < 16; ++nt) {
            const int col = nt * 16 + c15;
#pragma unroll
            for (int m = 0; m < 2; ++m)
#pragma unroll
                for (int r = 0; r < 4; ++r) {
                    const int row = rt0 + m * 16 + quad * 4 + r;
                    HR[(size_t)row * 256 + col] = acc[m][nt][r];
                }
        }
    }
}

// ============ k2_heads: second GEMM (K=256, B LDS-staged) + in-register heads ============
template <bool PATHA>
__global__ __launch_bounds__(256)
void k2_heads(unsigned short* __restrict__ wsu,
              const float* __restrict__ b1a, const float* __restrict__ b1b,
              const float* __restrict__ w2a, const float* __restrict__ b2a,
              const float* __restrict__ w2b, const float* __restrict__ b2b,
              const float* __restrict__ bd1, float* __restrict__ out)
{
    constexpr int NT2 = PATHA ? 16 : 8;
    __shared__ __align__(16) unsigned short Bsh[NT2 * 512];
    const int tid = threadIdx.x, l = tid & 63, w = tid >> 6;
    const int c = l & 15, quad = l >> 4;
    const int M0 = blockIdx.x * 64;
    const unsigned short* PW = wsu + (PATHA ? PW2_OFF : PWD2_OFF);

    f32x4 acc[NT2];
#pragma unroll
    for (int n = 0; n < NT2; ++n) acc[n] = (f32x4){0.f, 0.f, 0.f, 0.f};

    const int row = M0 + w * 16 + c;
    const unsigned short* arow = nullptr;
    const float* h1p = nullptr; const float* h0p = nullptr;
    if (PATHA) {
        arow = wsu + PA_OFF + (size_t)row * KP + quad * 8;
    } else {
        const float* HR = (const float*)(wsu + PD_OFF);
        const int sbk = row / 19, dt = row % 19;
        h0p = HR + (size_t)(sbk * 20 + dt) * 256 + quad * 8;
        h1p = h0p + 256;
    }

    for (int kt = 0; kt < 8; ++kt) {
        __syncthreads();
        {
            const int4* src = (const int4*)(PW + (size_t)kt * (NT2 * 512) + tid * (NT2 * 2));
            int4* dst = (int4*)(Bsh + tid * (NT2 * 2));
#pragma unroll
            for (int cc = 0; cc < NT2 / 4; ++cc) dst[cc] = src[cc];
        }
        __syncthreads();
        half8 af;
        if (PATHA) {
            af = *(const half8*)(arow + kt * 32);
        } else {
            float4 a1 = *(const float4*)(h1p + kt * 32);
            float4 a1b = *(const float4*)(h1p + kt * 32 + 4);
            float4 a0 = *(const float4*)(h0p + kt * 32);
            float4 a0b = *(const float4*)(h0p + kt * 32 + 4);
            float4 bb = *(const float4*)(bd1 + kt * 32 + quad * 8);
            float4 bb2 = *(const float4*)(bd1 + kt * 32 + quad * 8 + 4);
            float v0 = fmaxf(a1.x - a0.x + bb.x, 0.f);
            float v1 = fmaxf(a1.y - a0.y + bb.y, 0.f);
            float v2 = fmaxf(a1.z - a0.z + bb.z, 0.f);
            float v3 = fmaxf(a1.w - a0.w + bb.w, 0.f);
            float v4 = fmaxf(a1b.x - a0b.x + bb2.x, 0.f);
            float v5 = fmaxf(a1b.y - a0b.y + bb2.y, 0.f);
            float v6 = fmaxf(a1b.z - a0b.z + bb2.z, 0.f);
            float v7 = fmaxf(a1b.w - a0b.w + bb2.w, 0.f);
            union { unsigned u[4]; half8 h8; } pk;
            pk.u[0] = (unsigned)f2h(v0) | ((unsigned)f2h(v1) << 16);
            pk.u[1] = (unsigned)f2h(v2) | ((unsigned)f2h(v3) << 16);
            pk.u[2] = (unsigned)f2h(v4) | ((unsigned)f2h(v5) << 16);
            pk.u[3] = (unsigned)f2h(v6) | ((unsigned)f2h(v7) << 16);
            af = pk.h8;
        }
#pragma unroll
        for (int nt = 0; nt < NT2; ++nt) {
            half8 bf = *(const half8*)(Bsh + nt * 512 + l * 8);
            acc[nt] = __builtin_amdgcn_mfma_f32_16x16x32_f16(af, bf, acc[nt], 0, 0, 0);
        }
    }
#pragma unroll
    for (int nt = 0; nt < NT2; ++nt) {
        float bv;
        if (PATHA) bv = (nt < 8) ? b1a[nt * 16 + c] : b1b[(nt - 8) * 16 + c];
        else       bv = b1a[nt * 16 + c];
#pragma unroll
        for (int r = 0; r < 4; ++r) {
            float v = acc[nt][r] + bv;
            acc[nt][r] = v > 0.f ? v : 0.f;
        }
    }
    float pm[2][4], ps[2][4];
#pragma unroll
    for (int d = 0; d < 2; ++d)
#pragma unroll
        for (int r = 0; r < 4; ++r) { pm[d][r] = 0.f; ps[d][r] = 0.f; }
#pragma unroll
    for (int d = 0; d < 2; ++d)
#pragma unroll
        for (int nt = 0; nt < 8; ++nt) {
            const float wmv = w2a[(nt * 16 + c) * 2 + d];
            float wsv = 0.f;
            if (PATHA) wsv = w2b[(nt * 16 + c) * 2 + d];
#pragma unroll
            for (int r = 0; r < 4; ++r) {
                pm[d][r] = fmaf(acc[nt][r], wmv, pm[d][r]);
                if (PATHA) ps[d][r] = fmaf(acc[nt + 8][r], wsv, ps[d][r]);
            }
        }
#pragma unroll
    for (int o = 1; o < 16; o <<= 1)
#pragma unroll
        for (int d = 0; d < 2; ++d)
#pragma unroll
            for (int r = 0; r < 4; ++r) {
                pm[d][r] += __shfl_xor(pm[d][r], o, 64);
                if (PATHA) ps[d][r] += __shfl_xor(ps[d][r], o, 64);
            }
    if (c == 0) {
#pragma unroll
        for (int r = 0; r < 4; ++r) {
            const int orow = M0 + w * 16 + quad * 4 + r;
            if (PATHA) {
                const int sbk = orow / 20, t = orow % 20;
                const int sb = sbk / 3, kk = sbk % 3;
                const int oi = ((sb * 20 + t) * 3 + kk) * 2;
                out[oi + 0] = tanhf(pm[0][r] + b2a[0]);
                out[oi + 1] = tanhf(pm[1][r] + b2a[1]);
                out[30720 + oi + 0] = __expf(ps[0][r] + b2b[0]);
                out[30720 + oi + 1] = __expf(ps[1][r] + b2b[1]);
            } else {
                const int sbk = orow / 19, dt = orow % 19;
                const int sb = sbk / 3, kk = sbk % 3;
                const int oi = 61440 + ((sb * 19 + dt) * 3 + kk) * 2;
                out[oi + 0] = tanhf(pm[0][r] + b2a[0]);
                out[oi + 1] = tanhf(pm[1][r] + b2a[1]);
            }
        }
    }
}

extern "C" void kernel_launch(void* const* d_in, const int* in_sizes, int n_in,
                              void* d_out, int out_size, void* d_ws, size_t ws_size,
                              hipStream_t stream) {
    const float* frames = (const float*)d_in[0];
    const float* digit  = (const float*)d_in[1];
    const float* w_h1   = (const float*)d_in[2];
    const float* b_h1   = (const float*)d_in[3];
    const float* wm1    = (const float*)d_in[4];
    const float* bm1    = (const float*)d_in[5];
    const float* wm2    = (const float*)d_in[6];
    const float* bm2    = (const float*)d_in[7];
    const float* ws1    = (const float*)d_in[8];
    const float* bs1    = (const float*)d_in[9];
    const float* ws2    = (const float*)d_in[10];
    const float* bs2    = (const float*)d_in[11];
    const float* wd1    = (const float*)d_in[12];
    const float* bd1    = (const float*)d_in[13];
    const float* wd2    = (const float*)d_in[14];
    const float* bd2    = (const float*)d_in[15];
    const float* wd3    = (const float*)d_in[16];
    const float* bd3    = (const float*)d_in[17];

    unsigned short* wsu = (unsigned short*)d_ws;
    float* tsum = (float*)(wsu + TSUM_OFF);
    float2* stats = (float2*)(wsu + STAT_OFF);
    float* o = (float*)d_out;

    k0_pack<<<dim3(3328), dim3(256), 0, stream>>>(w_h1, wd1, wm1, ws1, wd2, digit, wsu, tsum);
    k1a_corr<<<dim3(640), dim3(512), 0, stream>>>(frames, digit, tsum, wsu);
    k1b_stats<<<dim3(3840), dim3(256), 0, stream>>>(wsu, stats);               // softmax stats
    k2_gemmAB<<<dim3(240), dim3(256), 0, stream>>>(wsu, b_h1, stats);          // fused hidden+Hraw
    k2_heads<true><<<dim3(240), dim3(256), 0, stream>>>(wsu, bm1, bs1, wm2, bm2, ws2, bs2, nullptr, o);
    k2_heads<false><<<dim3(228), dim3(256), 0, stream>>>(wsu, bd2, nullptr, wd3, bd3, nullptr, nullptr, bd1, o);
}

// Round 15
// 174.071 us; speedup vs baseline: 2.1054x; 1.0091x over previous
//
#include <hip/hip_runtime.h>
#include <hip/hip_fp16.h>

typedef __attribute__((ext_vector_type(8))) _Float16 half8;
typedef __attribute__((ext_vector_type(2))) _Float16 h2f;
typedef __attribute__((ext_vector_type(4))) float f32x4;

#define NP 1369
#define KP 1376          /* padded row stride: 43 tiles of 32 */
#define NKT 43
#define ROWS_A 15360     /* 768 sbk * 20 t  */
#define ROWS_D 14592     /* 768 sbk * 19 dt */

/* ws layout (ushort units). total = 84,119,488 B <= 84.25MB proven */
#define PA_OFF   0
#define PD_OFF   (ROWS_A * KP)          /* holds Hraw fp32 15360x256 */
#define PWH_OFF  (PD_OFF + ROWS_D * KP)
#define PWD_OFF  (PWH_OFF + NKT * 16 * 512)
#define PW2_OFF  (PWD_OFF + NKT * 16 * 512)
#define PWD2_OFF (PW2_OFF + 8 * 16 * 512)
#define TSUM_OFF (PWD2_OFF + 8 * 8 * 512)   /* 768 floats */
#define STAT_OFF (TSUM_OFF + 1536)          /* 15360 float2 */

__device__ __forceinline__ unsigned short f2h(float f) {
    __half h = __float2half(f);
    return __half_as_ushort(h);
}
__device__ __forceinline__ h2f u2h2(unsigned int u) {
    h2f r; __builtin_memcpy(&r, &u, 4); return r;
}

// ============ k0: pack weights (fp16 B-frags) + tsum baselines ============
__global__ __launch_bounds__(256)
void k0_pack(const float* __restrict__ w_h1, const float* __restrict__ wd1,
             const float* __restrict__ wm1,  const float* __restrict__ ws1,
             const float* __restrict__ wd2,  const float* __restrict__ digit,
             unsigned short* __restrict__ wsu, float* __restrict__ tsum)
{
    const int tid = threadIdx.x;
    if (blockIdx.x >= 3136) {            // tsum blocks: 4 sbk per block
        const int sbk = (blockIdx.x - 3136) * 4 + (tid >> 6);
        const int l = tid & 63;
        const float* tp = digit + (size_t)sbk * 784;
        float s = 0.f;
        for (int i = l; i < 784; i += 64) s += tp[i];
        for (int o = 32; o; o >>= 1) s += __shfl_xor(s, o, 64);
        if (l == 0) tsum[sbk] = 0.5f * s;
        return;
    }
    int idx = blockIdx.x * 256 + tid;      // 0..802815
    int local, mode;
    unsigned short* dst;
    if (idx < 352256)      { mode = 0; local = idx;          dst = wsu + PWH_OFF; }
    else if (idx < 704512) { mode = 1; local = idx - 352256; dst = wsu + PWD_OFF; }
    else if (idx < 770048) { mode = 2; local = idx - 704512; dst = wsu + PW2_OFF; }
    else                   { mode = 3; local = idx - 770048; dst = wsu + PWD2_OFF; }
    int j = local & 7, lane = (local >> 3) & 63, rest = local >> 9;
    int NTn = (mode == 3) ? 8 : 16;
    int nt = rest % NTn, kt = rest / NTn;
    int k = kt * 32 + ((lane >> 4) << 3) + j;
    int n = nt * 16 + (lane & 15);
    float v = 0.f;
    if (mode == 0)      { if (k < NP) v = w_h1[k * 256 + n]; }
    else if (mode == 1) { if (k < NP) v = wd1[k * 256 + n]; }
    else if (mode == 2) { v = (n < 128) ? wm1[k * 128 + n] : ws1[k * 128 + (n - 128)]; }
    else                { v = wd2[k * 128 + n]; }
    dst[local] = f2h(v);
}

// ============ k1a: im2col MFMA correlation, N=48, split-B restaging ============
// grid 640 = (b 16) x (t 20) x (M-half 2); block 512 (8 waves). LDS 52.4KB.
__global__ __launch_bounds__(512)
void k1a_corr(const float* __restrict__ frames, const float* __restrict__ digit,
              const float* __restrict__ tsum, unsigned short* __restrict__ wsu)
{
    __shared__ __align__(16) unsigned short Bs[14 * 3 * 512];  // 43,008 B (half the kt range)
    __shared__ __align__(16) unsigned int frd[64 * 36];        // 9,216 B
    __shared__ float Cn[48];

    const int tid = threadIdx.x, l = tid & 63, w = tid >> 6;
    const int mh = blockIdx.x & 1;
    const int bt = blockIdx.x >> 1;
    const int t  = bt % 20;
    const int bb = bt / 20;

    if (tid < 48) {
        int sbk_n = ((tid / 3) * 16 + bb) * 3 + (tid % 3);
        Cn[tid] = tsum[sbk_n];
    }
    if (tid < 256) frd[(tid >> 2) * 36 + 32 + (tid & 3)] = 0u;
    {
        const float4* fp4 = (const float4*)(frames + (size_t)(bb * 20 + t) * 4096);
        for (int idx = tid; idx < 1024; idx += 512) {
            float4 v = fp4[idx];
            int r = idx >> 4, c4 = idx & 15;
            unsigned lo = (unsigned)f2h(v.x) | ((unsigned)f2h(v.y) << 16);
            unsigned hi = (unsigned)f2h(v.z) | ((unsigned)f2h(v.w) << 16);
            *(uint2*)&frd[r * 36 + c4 * 2] = make_uint2(lo, hi);
        }
    }

    const int c15 = l & 15, quad = l >> 4, v0q = quad << 3;
    const int cnt = (50 - w) / 8;        // waves 0-2: 6 tiles, 3-7: 5 tiles (43 total)

    int baseb[6]; unsigned shv[6];
#pragma unroll
    for (int it = 0; it < 6; ++it) {
        int tI = mh * 43 + w + 8 * it;
        int p  = tI * 16 + c15;
        int pc = p > 1368 ? 1368 : p;
        int i  = pc / 37;
        int jj = pc - i * 37;
        int c  = jj + v0q;
        baseb[it] = i * 144 + (c >> 1) * 4;
        shv[it]   = (unsigned)((c & 1) << 4);
    }
    f32x4 acc[6][3];
#pragma unroll
    for (int it = 0; it < 6; ++it)
#pragma unroll
        for (int nt = 0; nt < 3; ++nt) acc[it][nt] = (f32x4){0.f, 0.f, 0.f, 0.f};

    for (int ph = 0; ph < 2; ++ph) {
        __syncthreads();   // frd/Cn ready (ph0); Bs consumers done (ph1)
        // ---- stage B for kt = ph*14 .. ph*14+13 ----
        for (int s = tid; s < 2688; s += 512) {
            int ktl = s / 192;
            int rem = s - ktl * 192;
            int nt = rem >> 6, sl = rem & 63;
            int nl = nt * 16 + (sl & 15);
            int v0 = (sl >> 4) << 3;
            int kt = ph * 14 + ktl;
            int sbk_n = ((nl / 3) * 16 + bb) * 3 + (nl % 3);
            const float* tp = digit + (size_t)sbk_n * 784 + kt * 28 + v0;
            float4 fa = *(const float4*)tp;
            float4 fb = (v0 <= 16) ? *(const float4*)(tp + 4) : make_float4(0.f, 0.f, 0.f, 0.f);
            uint4 pk;
            pk.x = (unsigned)f2h(fa.x) | ((unsigned)f2h(fa.y) << 16);
            pk.y = (unsigned)f2h(fa.z) | ((unsigned)f2h(fa.w) << 16);
            pk.z = (unsigned)f2h(fb.x) | ((unsigned)f2h(fb.y) << 16);
            pk.w = (unsigned)f2h(fb.z) | ((unsigned)f2h(fb.w) << 16);
            *(uint4*)(Bs + s * 8) = pk;
        }
        __syncthreads();

        for (int ktl = 0; ktl < 14; ++ktl) {
            const int kt = ph * 14 + ktl;
            half8 bf0 = *(const half8*)(Bs + ktl * 1536 + 0 * 512 + l * 8);
            half8 bf1 = *(const half8*)(Bs + ktl * 1536 + 1 * 512 + l * 8);
            half8 bf2 = *(const half8*)(Bs + ktl * 1536 + 2 * 512 + l * 8);
            const char* fbase = (const char*)frd + kt * 144;
#pragma unroll
            for (int it = 0; it < 6; ++it) {
                if (it < cnt) {
                    const char* ap = fbase + baseb[it];
                    unsigned w0 = *(const unsigned*)(ap);
                    unsigned w1 = *(const unsigned*)(ap + 4);
                    unsigned w2 = *(const unsigned*)(ap + 8);
                    unsigned w3 = *(const unsigned*)(ap + 12);
                    unsigned w4 = *(const unsigned*)(ap + 16);
                    unsigned sh = shv[it];
                    union { unsigned u[4]; half8 h8; } af;
                    af.u[0] = (unsigned)(((((unsigned long long)w1) << 32) | w0) >> sh);
                    af.u[1] = (unsigned)(((((unsigned long long)w2) << 32) | w1) >> sh);
                    af.u[2] = (unsigned)(((((unsigned long long)w3) << 32) | w2) >> sh);
                    af.u[3] = (unsigned)(((((unsigned long long)w4) << 32) | w3) >> sh);
                    acc[it][0] = __builtin_amdgcn_mfma_f32_16x16x32_f16(af.h8, bf0, acc[it][0], 0, 0, 0);
                    acc[it][1] = __builtin_amdgcn_mfma_f32_16x16x32_f16(af.h8, bf1, acc[it][1], 0, 0, 0);
                    acc[it][2] = __builtin_amdgcn_mfma_f32_16x16x32_f16(af.h8, bf2, acc[it][2], 0, 0, 0);
                }
            }
        }
    }
    // ---- epilogue: conv - C -> fp16 rows of PA ----
#pragma unroll
    for (int it = 0; it < 6; ++it) {
        if (it < cnt) {
            int tI = mh * 43 + w + 8 * it;
            int p0 = tI * 16 + quad * 4;
#pragma unroll
            for (int nt = 0; nt < 3; ++nt) {
                int nl = nt * 16 + c15;
                int sbk_n = ((nl / 3) * 16 + bb) * 3 + (nl % 3);
                const float C = Cn[nl];
                unsigned short* orow = wsu + PA_OFF + (size_t)(sbk_n * 20 + t) * KP;
                if (p0 + 3 <= 1368) {
                    ushort4 st;
                    st.x = f2h(acc[it][nt][0] - C); st.y = f2h(acc[it][nt][1] - C);
                    st.z = f2h(acc[it][nt][2] - C); st.w = f2h(acc[it][nt][3] - C);
                    *(ushort4*)(orow + p0) = st;
                } else {
#pragma unroll
                    for (int r = 0; r < 4; ++r)
                        if (p0 + r <= 1368) orow[p0 + r] = f2h(acc[it][nt][r] - C);
                }
            }
        }
    }
}

// ============ k1b_stats: per-row softmax stats (mx, 1/sum) -> stats buf ============
__global__ __launch_bounds__(256)
void k1b_stats(const unsigned short* __restrict__ wsu, float2* __restrict__ stats)
{
    const int l = threadIdx.x & 63, wv = threadIdx.x >> 6;
    const int row = blockIdx.x * 4 + wv;
    const unsigned* rp = (const unsigned*)(wsu + PA_OFF + (size_t)row * KP);

    float f0[11], f1[11];
    float mx = -3.0e38f;
#pragma unroll
    for (int i = 0; i < 11; ++i) {
        int q = l + i * 64;
        unsigned u = (q < 685) ? rp[q] : 0u;
        h2f h = u2h2(u);
        f0[i] = (q < 685) ? (float)h[0] : -3.0e38f;
        f1[i] = (q < 684) ? (float)h[1] : -3.0e38f;
        mx = fmaxf(mx, fmaxf(f0[i], f1[i]));
    }
    for (int o = 32; o; o >>= 1) mx = fmaxf(mx, __shfl_xor(mx, o, 64));
    float sum = 0.f;
#pragma unroll
    for (int i = 0; i < 11; ++i)
        sum += __expf(f0[i] - mx) + __expf(f1[i] - mx);
    for (int o = 32; o; o >>= 1) sum += __shfl_xor(sum, o, 64);
    if (l == 0) stats[row] = make_float2(mx, 1.0f / sum);
}

// ============ k2_gemmAB: merged GEMMs, 2 row-tiles/wave, A from global, B dbuf ============
// grid 240, block 256 (4 waves). Waves 0-1: H (softmax@w_h1); 2-3: D (raw@wd1 -> Hraw).
// B-staging uses CONFLICT-FREE linear copy (lane-consecutive 16B).
__global__ __launch_bounds__(256)
void k2_gemmAB(unsigned short* __restrict__ wsu, const float* __restrict__ b_h1,
               const float2* __restrict__ stats)
{
    __shared__ __align__(16) unsigned short Bbuf[2][2 * 8192];   // [dbuf][{H,D} tiles] 64KB

    const int tid = threadIdx.x, l = tid & 63, w = tid >> 6;
    const int c15 = l & 15, quad = l >> 4;
    const int M0 = blockIdx.x * 64;
    unsigned short* Abase = wsu + PA_OFF;
    const unsigned short* PWH = wsu + PWH_OFF;
    const unsigned short* PWD = wsu + PWD_OFF;
    float* HR = (float*)(wsu + PD_OFF);

    const bool isH = (w < 2);
    const int rt0 = M0 + (w & 1) * 32;
    const int row0 = rt0 + c15, row1 = rt0 + 16 + c15;
    const unsigned short* a0p = Abase + (size_t)row0 * KP + quad * 8;
    const unsigned short* a1p = Abase + (size_t)row1 * KP + quad * 8;
    float2 st0 = make_float2(0.f, 0.f), st1 = make_float2(0.f, 0.f);
    if (isH) { st0 = stats[row0]; st1 = stats[row1]; }

    f32x4 acc[2][16];
#pragma unroll
    for (int m = 0; m < 2; ++m)
#pragma unroll
        for (int n = 0; n < 16; ++n) acc[m][n] = (f32x4){0.f, 0.f, 0.f, 0.f};

    // prologue: stage B(kt=0) into buf 0 -- conflict-free linear copy
    {
        const int4* sH = (const int4*)(PWH);
        const int4* sD = (const int4*)(PWD);
        int4* dH = (int4*)(Bbuf[0]);
        int4* dD = (int4*)(Bbuf[0] + 8192);
#pragma unroll
        for (int c = 0; c < 4; ++c) {
            dH[tid + 256 * c] = sH[tid + 256 * c];
            dD[tid + 256 * c] = sD[tid + 256 * c];
        }
    }
    __syncthreads();

    for (int kt = 0; kt < NKT; ++kt) {
        const int db = kt & 1;
        // ---- A fragments for this kt (global, 16B/lane) ----
        half8 afA = *(const half8*)(a0p + kt * 32);
        half8 afB = *(const half8*)(a1p + kt * 32);
        if (isH) {   // exp transform in registers
            union { half8 h8; unsigned u[4]; } ia, ib, oa, ob;
            ia.h8 = afA; ib.h8 = afB;
#pragma unroll
            for (int q = 0; q < 4; ++q) {
                h2f ha = u2h2(ia.u[q]);
                h2f hb = u2h2(ib.u[q]);
                float a0 = __expf((float)ha[0] - st0.x) * st0.y;
                float a1 = __expf((float)ha[1] - st0.x) * st0.y;
                float b0 = __expf((float)hb[0] - st1.x) * st1.y;
                float b1 = __expf((float)hb[1] - st1.x) * st1.y;
                oa.u[q] = (unsigned)f2h(a0) | ((unsigned)f2h(a1) << 16);
                ob.u[q] = (unsigned)f2h(b0) | ((unsigned)f2h(b1) << 16);
            }
            afA = oa.h8; afB = ob.h8;
        }
        // ---- prefetch next kt's B tiles into registers (linear) ----
        int4 rH[4], rD[4];
        if (kt + 1 < NKT) {
            const int4* sH = (const int4*)(PWH + (size_t)(kt + 1) * 8192);
            const int4* sD = (const int4*)(PWD + (size_t)(kt + 1) * 8192);
#pragma unroll
            for (int c = 0; c < 4; ++c) {
                rH[c] = sH[tid + 256 * c];
                rD[c] = sD[tid + 256 * c];
            }
        }
        // ---- MFMA: 16 bf reads feed 32 MFMAs (2 row-tiles) ----
        const unsigned short* bb = Bbuf[db] + (isH ? 0 : 8192);
#pragma unroll
        for (int nt = 0; nt < 16; ++nt) {
            half8 bf = *(const half8*)(bb + nt * 512 + l * 8);
            acc[0][nt] = __builtin_amdgcn_mfma_f32_16x16x32_f16(afA, bf, acc[0][nt], 0, 0, 0);
            acc[1][nt] = __builtin_amdgcn_mfma_f32_16x16x32_f16(afB, bf, acc[1][nt], 0, 0, 0);
        }
        // ---- write staged B to the other buffer (conflict-free linear) ----
        if (kt + 1 < NKT) {
            int4* dH = (int4*)(Bbuf[db ^ 1]);
            int4* dD = (int4*)(Bbuf[db ^ 1] + 8192);
#pragma unroll
            for (int c = 0; c < 4; ++c) {
                dH[tid + 256 * c] = rH[c];
                dD[tid + 256 * c] = rD[c];
            }
        }
        __syncthreads();
    }

    // ---- epilogue ----
    if (isH) {
#pragma unroll
        for (int nt = 0; nt < 16; ++nt) {
            const int col = nt * 16 + c15;
            const float bv = b_h1[col];
#pragma unroll
            for (int m = 0; m < 2; ++m)
#pragma unroll
                for (int r = 0; r < 4; ++r) {
                    const int row = rt0 + m * 16 + quad * 4 + r;
                    float v = acc[m][nt][r] + bv;
                    Abase[(size_t)row * KP + col] = f2h(v > 0.f ? v : 0.f);
                }
        }
    } else {
#pragma unroll
        for (int nt = 0; nt < 16; ++nt) {
            const int col = nt * 16 + c15;
#pragma unroll
            for (int m = 0; m < 2; ++m)
#pragma unroll
                for (int r = 0; r < 4; ++r) {
                    const int row = rt0 + m * 16 + quad * 4 + r;
                    HR[(size_t)row * 256 + col] = acc[m][nt][r];
                }
        }
    }
}

// ============ k2_heads: second GEMM (K=256, B LDS-staged conflict-free) + heads ============
template <bool PATHA>
__global__ __launch_bounds__(256)
void k2_heads(unsigned short* __restrict__ wsu,
              const float* __restrict__ b1a, const float* __restrict__ b1b,
              const float* __restrict__ w2a, const float* __restrict__ b2a,
              const float* __restrict__ w2b, const float* __restrict__ b2b,
              const float* __restrict__ bd1, float* __restrict__ out)
{
    constexpr int NT2 = PATHA ? 16 : 8;
    __shared__ __align__(16) unsigned short Bsh[NT2 * 512];
    const int tid = threadIdx.x, l = tid & 63, w = tid >> 6;
    const int c = l & 15, quad = l >> 4;
    const int M0 = blockIdx.x * 64;
    const unsigned short* PW = wsu + (PATHA ? PW2_OFF : PWD2_OFF);

    f32x4 acc[NT2];
#pragma unroll
    for (int n = 0; n < NT2; ++n) acc[n] = (f32x4){0.f, 0.f, 0.f, 0.f};

    const int row = M0 + w * 16 + c;
    const unsigned short* arow = nullptr;
    const float* h1p = nullptr; const float* h0p = nullptr;
    if (PATHA) {
        arow = wsu + PA_OFF + (size_t)row * KP + quad * 8;
    } else {
        const float* HR = (const float*)(wsu + PD_OFF);
        const int sbk = row / 19, dt = row % 19;
        h0p = HR + (size_t)(sbk * 20 + dt) * 256 + quad * 8;
        h1p = h0p + 256;
    }

    for (int kt = 0; kt < 8; ++kt) {
        __syncthreads();
        {   // conflict-free linear copy of the B tile
            const int4* src = (const int4*)(PW + (size_t)kt * (NT2 * 512));
            int4* dst = (int4*)Bsh;
#pragma unroll
            for (int cc = 0; cc < NT2 / 4; ++cc)
                dst[tid + 256 * cc] = src[tid + 256 * cc];
        }
        __syncthreads();
        half8 af;
        if (PATHA) {
            af = *(const half8*)(arow + kt * 32);
        } else {
            float4 a1 = *(const float4*)(h1p + kt * 32);
            float4 a1b = *(const float4*)(h1p + kt * 32 + 4);
            float4 a0 = *(const float4*)(h0p + kt * 32);
            float4 a0b = *(const float4*)(h0p + kt * 32 + 4);
            float4 bb = *(const float4*)(bd1 + kt * 32 + quad * 8);
            float4 bb2 = *(const float4*)(bd1 + kt * 32 + quad * 8 + 4);
            float v0 = fmaxf(a1.x - a0.x + bb.x, 0.f);
            float v1 = fmaxf(a1.y - a0.y + bb.y, 0.f);
            float v2 = fmaxf(a1.z - a0.z + bb.z, 0.f);
            float v3 = fmaxf(a1.w - a0.w + bb.w, 0.f);
            float v4 = fmaxf(a1b.x - a0b.x + bb2.x, 0.f);
            float v5 = fmaxf(a1b.y - a0b.y + bb2.y, 0.f);
            float v6 = fmaxf(a1b.z - a0b.z + bb2.z, 0.f);
            float v7 = fmaxf(a1b.w - a0b.w + bb2.w, 0.f);
            union { unsigned u[4]; half8 h8; } pk;
            pk.u[0] = (unsigned)f2h(v0) | ((unsigned)f2h(v1) << 16);
            pk.u[1] = (unsigned)f2h(v2) | ((unsigned)f2h(v3) << 16);
            pk.u[2] = (unsigned)f2h(v4) | ((unsigned)f2h(v5) << 16);
            pk.u[3] = (unsigned)f2h(v6) | ((unsigned)f2h(v7) << 16);
            af = pk.h8;
        }
#pragma unroll
        for (int nt = 0; nt < NT2; ++nt) {
            half8 bf = *(const half8*)(Bsh + nt * 512 + l * 8);
            acc[nt] = __builtin_amdgcn_mfma_f32_16x16x32_f16(af, bf, acc[nt], 0, 0, 0);
        }
    }
#pragma unroll
    for (int nt = 0; nt < NT2; ++nt) {
        float bv;
        if (PATHA) bv = (nt < 8) ? b1a[nt * 16 + c] : b1b[(nt - 8) * 16 + c];
        else       bv = b1a[nt * 16 + c];
#pragma unroll
        for (int r = 0; r < 4; ++r) {
            float v = acc[nt][r] + bv;
            acc[nt][r] = v > 0.f ? v : 0.f;
        }
    }
    float pm[2][4], ps[2][4];
#pragma unroll
    for (int d = 0; d < 2; ++d)
#pragma unroll
        for (int r = 0; r < 4; ++r) { pm[d][r] = 0.f; ps[d][r] = 0.f; }
#pragma unroll
    for (int d = 0; d < 2; ++d)
#pragma unroll
        for (int nt = 0; nt < 8; ++nt) {
            const float wmv = w2a[(nt * 16 + c) * 2 + d];
            float wsv = 0.f;
            if (PATHA) wsv = w2b[(nt * 16 + c) * 2 + d];
#pragma unroll
            for (int r = 0; r < 4; ++r) {
                pm[d][r] = fmaf(acc[nt][r], wmv, pm[d][r]);
                if (PATHA) ps[d][r] = fmaf(acc[nt + 8][r], wsv, ps[d][r]);
            }
        }
#pragma unroll
    for (int o = 1; o < 16; o <<= 1)
#pragma unroll
        for (int d = 0; d < 2; ++d)
#pragma unroll
            for (int r = 0; r < 4; ++r) {
                pm[d][r] += __shfl_xor(pm[d][r], o, 64);
                if (PATHA) ps[d][r] += __shfl_xor(ps[d][r], o, 64);
            }
    if (c == 0) {
#pragma unroll
        for (int r = 0; r < 4; ++r) {
            const int orow = M0 + w * 16 + quad * 4 + r;
            if (PATHA) {
                const int sbk = orow / 20, t = orow % 20;
                const int sb = sbk / 3, kk = sbk % 3;
                const int oi = ((sb * 20 + t) * 3 + kk) * 2;
                out[oi + 0] = tanhf(pm[0][r] + b2a[0]);
                out[oi + 1] = tanhf(pm[1][r] + b2a[1]);
                out[30720 + oi + 0] = __expf(ps[0][r] + b2b[0]);
                out[30720 + oi + 1] = __expf(ps[1][r] + b2b[1]);
            } else {
                const int sbk = orow / 19, dt = orow % 19;
                const int sb = sbk / 3, kk = sbk % 3;
                const int oi = 61440 + ((sb * 19 + dt) * 3 + kk) * 2;
                out[oi + 0] = tanhf(pm[0][r] + b2a[0]);
                out[oi + 1] = tanhf(pm[1][r] + b2a[1]);
            }
        }
    }
}

extern "C" void kernel_launch(void* const* d_in, const int* in_sizes, int n_in,
                              void* d_out, int out_size, void* d_ws, size_t ws_size,
                              hipStream_t stream) {
    const float* frames = (const float*)d_in[0];
    const float* digit  = (const float*)d_in[1];
    const float* w_h1   = (const float*)d_in[2];
    const float* b_h1   = (const float*)d_in[3];
    const float* wm1    = (const float*)d_in[4];
    const float* bm1    = (const float*)d_in[5];
    const float* wm2    = (const float*)d_in[6];
    const float* bm2    = (const float*)d_in[7];
    const float* ws1    = (const float*)d_in[8];
    const float* bs1    = (const float*)d_in[9];
    const float* ws2    = (const float*)d_in[10];
    const float* bs2    = (const float*)d_in[11];
    const float* wd1    = (const float*)d_in[12];
    const float* bd1    = (const float*)d_in[13];
    const float* wd2    = (const float*)d_in[14];
    const float* bd2    = (const float*)d_in[15];
    const float* wd3    = (const float*)d_in[16];
    const float* bd3    = (const float*)d_in[17];

    unsigned short* wsu = (unsigned short*)d_ws;
    float* tsum = (float*)(wsu + TSUM_OFF);
    float2* stats = (float2*)(wsu + STAT_OFF);
    float* o = (float*)d_out;

    k0_pack<<<dim3(3328), dim3(256), 0, stream>>>(w_h1, wd1, wm1, ws1, wd2, digit, wsu, tsum);
    k1a_corr<<<dim3(640), dim3(512), 0, stream>>>(frames, digit, tsum, wsu);
    k1b_stats<<<dim3(3840), dim3(256), 0, stream>>>(wsu, stats);               // softmax stats
    k2_gemmAB<<<dim3(240), dim3(256), 0, stream>>>(wsu, b_h1, stats);          // fused hidden+Hraw
    k2_heads<true><<<dim3(240), dim3(256), 0, stream>>>(wsu, bm1, bs1, wm2, bm2, ws2, bs2, nullptr, o);
    k2_heads<false><<<dim3(228), dim3(256), 0, stream>>>(wsu, bd2, nullptr, wd3, bd3, nullptr, nullptr, bd1, o);
}

// Round 16
// 149.366 us; speedup vs baseline: 2.4536x; 1.1654x over previous
//
#include <hip/hip_runtime.h>
#include <hip/hip_fp16.h>

typedef __attribute__((ext_vector_type(8))) _Float16 half8;
typedef __attribute__((ext_vector_type(2))) _Float16 h2f;
typedef __attribute__((ext_vector_type(4))) float f32x4;

#define NP 1369
#define KP 1376          /* padded row stride: 43 tiles of 32 */
#define NKT 43
#define ROWS_A 15360     /* 768 sbk * 20 t  */
#define ROWS_D 14592     /* 768 sbk * 19 dt */

/* ws layout (ushort units). total = 84,119,488 B <= 84.25MB proven */
#define PA_OFF   0
#define PD_OFF   (ROWS_A * KP)          /* holds Hraw fp32 15360x256 */
#define PWH_OFF  (PD_OFF + ROWS_D * KP)
#define PWD_OFF  (PWH_OFF + NKT * 16 * 512)
#define PW2_OFF  (PWD_OFF + NKT * 16 * 512)
#define PWD2_OFF (PW2_OFF + 8 * 16 * 512)
#define TSUM_OFF (PWD2_OFF + 8 * 8 * 512)   /* 768 floats */
#define STAT_OFF (TSUM_OFF + 1536)          /* 15360 float2 */

__device__ __forceinline__ unsigned short f2h(float f) {
    __half h = __float2half(f);
    return __half_as_ushort(h);
}
__device__ __forceinline__ h2f u2h2(unsigned int u) {
    h2f r; __builtin_memcpy(&r, &u, 4); return r;
}

// ============ k0: pack weights (fp16 B-frags) + tsum baselines ============
__global__ __launch_bounds__(256)
void k0_pack(const float* __restrict__ w_h1, const float* __restrict__ wd1,
             const float* __restrict__ wm1,  const float* __restrict__ ws1,
             const float* __restrict__ wd2,  const float* __restrict__ digit,
             unsigned short* __restrict__ wsu, float* __restrict__ tsum)
{
    const int tid = threadIdx.x;
    if (blockIdx.x >= 3136) {            // tsum blocks: 4 sbk per block
        const int sbk = (blockIdx.x - 3136) * 4 + (tid >> 6);
        const int l = tid & 63;
        const float* tp = digit + (size_t)sbk * 784;
        float s = 0.f;
        for (int i = l; i < 784; i += 64) s += tp[i];
        for (int o = 32; o; o >>= 1) s += __shfl_xor(s, o, 64);
        if (l == 0) tsum[sbk] = 0.5f * s;
        return;
    }
    int idx = blockIdx.x * 256 + tid;      // 0..802815
    int local, mode;
    unsigned short* dst;
    if (idx < 352256)      { mode = 0; local = idx;          dst = wsu + PWH_OFF; }
    else if (idx < 704512) { mode = 1; local = idx - 352256; dst = wsu + PWD_OFF; }
    else if (idx < 770048) { mode = 2; local = idx - 704512; dst = wsu + PW2_OFF; }
    else                   { mode = 3; local = idx - 770048; dst = wsu + PWD2_OFF; }
    int j = local & 7, lane = (local >> 3) & 63, rest = local >> 9;
    int NTn = (mode == 3) ? 8 : 16;
    int nt = rest % NTn, kt = rest / NTn;
    int k = kt * 32 + ((lane >> 4) << 3) + j;
    int n = nt * 16 + (lane & 15);
    float v = 0.f;
    if (mode == 0)      { if (k < NP) v = w_h1[k * 256 + n]; }
    else if (mode == 1) { if (k < NP) v = wd1[k * 256 + n]; }
    else if (mode == 2) { v = (n < 128) ? wm1[k * 128 + n] : ws1[k * 128 + (n - 128)]; }
    else                { v = wd2[k * 128 + n]; }
    dst[local] = f2h(v);
}

// ============ k1a: im2col MFMA correlation, N=48, split-B restaging ============
// grid 640 = (b 16) x (t 20) x (M-half 2); block 512 (8 waves). LDS 52.4KB.
__global__ __launch_bounds__(512)
void k1a_corr(const float* __restrict__ frames, const float* __restrict__ digit,
              const float* __restrict__ tsum, unsigned short* __restrict__ wsu)
{
    __shared__ __align__(16) unsigned short Bs[14 * 3 * 512];  // 43,008 B (half the kt range)
    __shared__ __align__(16) unsigned int frd[64 * 36];        // 9,216 B
    __shared__ float Cn[48];

    const int tid = threadIdx.x, l = tid & 63, w = tid >> 6;
    const int mh = blockIdx.x & 1;
    const int bt = blockIdx.x >> 1;
    const int t  = bt % 20;
    const int bb = bt / 20;

    if (tid < 48) {
        int sbk_n = ((tid / 3) * 16 + bb) * 3 + (tid % 3);
        Cn[tid] = tsum[sbk_n];
    }
    if (tid < 256) frd[(tid >> 2) * 36 + 32 + (tid & 3)] = 0u;
    {
        const float4* fp4 = (const float4*)(frames + (size_t)(bb * 20 + t) * 4096);
        for (int idx = tid; idx < 1024; idx += 512) {
            float4 v = fp4[idx];
            int r = idx >> 4, c4 = idx & 15;
            unsigned lo = (unsigned)f2h(v.x) | ((unsigned)f2h(v.y) << 16);
            unsigned hi = (unsigned)f2h(v.z) | ((unsigned)f2h(v.w) << 16);
            *(uint2*)&frd[r * 36 + c4 * 2] = make_uint2(lo, hi);
        }
    }

    const int c15 = l & 15, quad = l >> 4, v0q = quad << 3;
    const int cnt = (50 - w) / 8;        // waves 0-2: 6 tiles, 3-7: 5 tiles (43 total)

    int baseb[6]; unsigned shv[6];
#pragma unroll
    for (int it = 0; it < 6; ++it) {
        int tI = mh * 43 + w + 8 * it;
        int p  = tI * 16 + c15;
        int pc = p > 1368 ? 1368 : p;
        int i  = pc / 37;
        int jj = pc - i * 37;
        int c  = jj + v0q;
        baseb[it] = i * 144 + (c >> 1) * 4;
        shv[it]   = (unsigned)((c & 1) << 4);
    }
    f32x4 acc[6][3];
#pragma unroll
    for (int it = 0; it < 6; ++it)
#pragma unroll
        for (int nt = 0; nt < 3; ++nt) acc[it][nt] = (f32x4){0.f, 0.f, 0.f, 0.f};

    for (int ph = 0; ph < 2; ++ph) {
        __syncthreads();   // frd/Cn ready (ph0); Bs consumers done (ph1)
        // ---- stage B for kt = ph*14 .. ph*14+13 ----
        for (int s = tid; s < 2688; s += 512) {
            int ktl = s / 192;
            int rem = s - ktl * 192;
            int nt = rem >> 6, sl = rem & 63;
            int nl = nt * 16 + (sl & 15);
            int v0 = (sl >> 4) << 3;
            int kt = ph * 14 + ktl;
            int sbk_n = ((nl / 3) * 16 + bb) * 3 + (nl % 3);
            const float* tp = digit + (size_t)sbk_n * 784 + kt * 28 + v0;
            float4 fa = *(const float4*)tp;
            float4 fb = (v0 <= 16) ? *(const float4*)(tp + 4) : make_float4(0.f, 0.f, 0.f, 0.f);
            uint4 pk;
            pk.x = (unsigned)f2h(fa.x) | ((unsigned)f2h(fa.y) << 16);
            pk.y = (unsigned)f2h(fa.z) | ((unsigned)f2h(fa.w) << 16);
            pk.z = (unsigned)f2h(fb.x) | ((unsigned)f2h(fb.y) << 16);
            pk.w = (unsigned)f2h(fb.z) | ((unsigned)f2h(fb.w) << 16);
            *(uint4*)(Bs + s * 8) = pk;
        }
        __syncthreads();

        for (int ktl = 0; ktl < 14; ++ktl) {
            const int kt = ph * 14 + ktl;
            half8 bf0 = *(const half8*)(Bs + ktl * 1536 + 0 * 512 + l * 8);
            half8 bf1 = *(const half8*)(Bs + ktl * 1536 + 1 * 512 + l * 8);
            half8 bf2 = *(const half8*)(Bs + ktl * 1536 + 2 * 512 + l * 8);
            const char* fbase = (const char*)frd + kt * 144;
#pragma unroll
            for (int it = 0; it < 6; ++it) {
                if (it < cnt) {
                    const char* ap = fbase + baseb[it];
                    unsigned w0 = *(const unsigned*)(ap);
                    unsigned w1 = *(const unsigned*)(ap + 4);
                    unsigned w2 = *(const unsigned*)(ap + 8);
                    unsigned w3 = *(const unsigned*)(ap + 12);
                    unsigned w4 = *(const unsigned*)(ap + 16);
                    unsigned sh = shv[it];
                    union { unsigned u[4]; half8 h8; } af;
                    af.u[0] = (unsigned)(((((unsigned long long)w1) << 32) | w0) >> sh);
                    af.u[1] = (unsigned)(((((unsigned long long)w2) << 32) | w1) >> sh);
                    af.u[2] = (unsigned)(((((unsigned long long)w3) << 32) | w2) >> sh);
                    af.u[3] = (unsigned)(((((unsigned long long)w4) << 32) | w3) >> sh);
                    acc[it][0] = __builtin_amdgcn_mfma_f32_16x16x32_f16(af.h8, bf0, acc[it][0], 0, 0, 0);
                    acc[it][1] = __builtin_amdgcn_mfma_f32_16x16x32_f16(af.h8, bf1, acc[it][1], 0, 0, 0);
                    acc[it][2] = __builtin_amdgcn_mfma_f32_16x16x32_f16(af.h8, bf2, acc[it][2], 0, 0, 0);
                }
            }
        }
    }
    // ---- epilogue: conv - C -> fp16 rows of PA ----
#pragma unroll
    for (int it = 0; it < 6; ++it) {
        if (it < cnt) {
            int tI = mh * 43 + w + 8 * it;
            int p0 = tI * 16 + quad * 4;
#pragma unroll
            for (int nt = 0; nt < 3; ++nt) {
                int nl = nt * 16 + c15;
                int sbk_n = ((nl / 3) * 16 + bb) * 3 + (nl % 3);
                const float C = Cn[nl];
                unsigned short* orow = wsu + PA_OFF + (size_t)(sbk_n * 20 + t) * KP;
                if (p0 + 3 <= 1368) {
                    ushort4 st;
                    st.x = f2h(acc[it][nt][0] - C); st.y = f2h(acc[it][nt][1] - C);
                    st.z = f2h(acc[it][nt][2] - C); st.w = f2h(acc[it][nt][3] - C);
                    *(ushort4*)(orow + p0) = st;
                } else {
#pragma unroll
                    for (int r = 0; r < 4; ++r)
                        if (p0 + r <= 1368) orow[p0 + r] = f2h(acc[it][nt][r] - C);
                }
            }
        }
    }
}

// ============ k1b_stats: per-row softmax stats (mx, 1/sum) -> stats buf ============
__global__ __launch_bounds__(256)
void k1b_stats(const unsigned short* __restrict__ wsu, float2* __restrict__ stats)
{
    const int l = threadIdx.x & 63, wv = threadIdx.x >> 6;
    const int row = blockIdx.x * 4 + wv;
    const unsigned* rp = (const unsigned*)(wsu + PA_OFF + (size_t)row * KP);

    float f0[11], f1[11];
    float mx = -3.0e38f;
#pragma unroll
    for (int i = 0; i < 11; ++i) {
        int q = l + i * 64;
        unsigned u = (q < 685) ? rp[q] : 0u;
        h2f h = u2h2(u);
        f0[i] = (q < 685) ? (float)h[0] : -3.0e38f;
        f1[i] = (q < 684) ? (float)h[1] : -3.0e38f;
        mx = fmaxf(mx, fmaxf(f0[i], f1[i]));
    }
    for (int o = 32; o; o >>= 1) mx = fmaxf(mx, __shfl_xor(mx, o, 64));
    float sum = 0.f;
#pragma unroll
    for (int i = 0; i < 11; ++i)
        sum += __expf(f0[i] - mx) + __expf(f1[i] - mx);
    for (int o = 32; o; o >>= 1) sum += __shfl_xor(sum, o, 64);
    if (l == 0) stats[row] = make_float2(mx, 1.0f / sum);
}

// ============ k2_gemmAB: merged GEMMs, A+B both software-pipelined ============
// grid 240, block 256 (4 waves). Waves 0-1: H; 2-3: D. Conflict-free staging.
__global__ __launch_bounds__(256)
void k2_gemmAB(unsigned short* __restrict__ wsu, const float* __restrict__ b_h1,
               const float2* __restrict__ stats)
{
    __shared__ __align__(16) unsigned short Bbuf[2][2 * 8192];   // [dbuf][{H,D}] 64KB

    const int tid = threadIdx.x, l = tid & 63, w = tid >> 6;
    const int c15 = l & 15, quad = l >> 4;
    const int M0 = blockIdx.x * 64;
    unsigned short* Abase = wsu + PA_OFF;
    const unsigned short* PWH = wsu + PWH_OFF;
    const unsigned short* PWD = wsu + PWD_OFF;
    float* HR = (float*)(wsu + PD_OFF);

    const bool isH = (w < 2);
    const int rt0 = M0 + (w & 1) * 32;
    const int row0 = rt0 + c15, row1 = rt0 + 16 + c15;
    const unsigned short* a0p = Abase + (size_t)row0 * KP + quad * 8;
    const unsigned short* a1p = Abase + (size_t)row1 * KP + quad * 8;
    float2 st0 = make_float2(0.f, 0.f), st1 = make_float2(0.f, 0.f);
    if (isH) { st0 = stats[row0]; st1 = stats[row1]; }

    f32x4 acc[2][16];
#pragma unroll
    for (int m = 0; m < 2; ++m)
#pragma unroll
        for (int n = 0; n < 16; ++n) acc[m][n] = (f32x4){0.f, 0.f, 0.f, 0.f};

    // prologue: stage B(0) -> buf0 (conflict-free); load A(0) into registers
    {
        const int4* sH = (const int4*)(PWH);
        const int4* sD = (const int4*)(PWD);
        int4* dH = (int4*)(Bbuf[0]);
        int4* dD = (int4*)(Bbuf[0] + 8192);
#pragma unroll
        for (int c = 0; c < 4; ++c) {
            dH[tid + 256 * c] = sH[tid + 256 * c];
            dD[tid + 256 * c] = sD[tid + 256 * c];
        }
    }
    half8 curA0 = *(const half8*)(a0p);
    half8 curA1 = *(const half8*)(a1p);
    __syncthreads();

    for (int kt = 0; kt < NKT; ++kt) {
        const int db = kt & 1;
        // ---- issue NEXT A loads (latency hides under this kt's MFMA) ----
        half8 nxtA0 = curA0, nxtA1 = curA1;
        if (kt + 1 < NKT) {
            nxtA0 = *(const half8*)(a0p + (kt + 1) * 32);
            nxtA1 = *(const half8*)(a1p + (kt + 1) * 32);
        }
        // ---- issue NEXT B loads into registers (linear, conflict-free) ----
        int4 rH[4], rD[4];
        if (kt + 1 < NKT) {
            const int4* sH = (const int4*)(PWH + (size_t)(kt + 1) * 8192);
            const int4* sD = (const int4*)(PWD + (size_t)(kt + 1) * 8192);
#pragma unroll
            for (int c = 0; c < 4; ++c) {
                rH[c] = sH[tid + 256 * c];
                rD[c] = sD[tid + 256 * c];
            }
        }
        // ---- transform current A (registers already resident) ----
        half8 afA = curA0, afB = curA1;
        if (isH) {
            union { half8 h8; unsigned u[4]; } ia, ib, oa, ob;
            ia.h8 = afA; ib.h8 = afB;
#pragma unroll
            for (int q = 0; q < 4; ++q) {
                h2f ha = u2h2(ia.u[q]);
                h2f hb = u2h2(ib.u[q]);
                float a0 = __expf((float)ha[0] - st0.x) * st0.y;
                float a1 = __expf((float)ha[1] - st0.x) * st0.y;
                float b0 = __expf((float)hb[0] - st1.x) * st1.y;
                float b1 = __expf((float)hb[1] - st1.x) * st1.y;
                oa.u[q] = (unsigned)f2h(a0) | ((unsigned)f2h(a1) << 16);
                ob.u[q] = (unsigned)f2h(b0) | ((unsigned)f2h(b1) << 16);
            }
            afA = oa.h8; afB = ob.h8;
        }
        // ---- MFMA: 16 bf reads feed 32 MFMAs ----
        const unsigned short* bb = Bbuf[db] + (isH ? 0 : 8192);
#pragma unroll
        for (int nt = 0; nt < 16; ++nt) {
            half8 bf = *(const half8*)(bb + nt * 512 + l * 8);
            acc[0][nt] = __builtin_amdgcn_mfma_f32_16x16x32_f16(afA, bf, acc[0][nt], 0, 0, 0);
            acc[1][nt] = __builtin_amdgcn_mfma_f32_16x16x32_f16(afB, bf, acc[1][nt], 0, 0, 0);
        }
        // ---- write staged B to the other buffer ----
        if (kt + 1 < NKT) {
            int4* dH = (int4*)(Bbuf[db ^ 1]);
            int4* dD = (int4*)(Bbuf[db ^ 1] + 8192);
#pragma unroll
            for (int c = 0; c < 4; ++c) {
                dH[tid + 256 * c] = rH[c];
                dD[tid + 256 * c] = rD[c];
            }
        }
        curA0 = nxtA0; curA1 = nxtA1;
        __syncthreads();
    }

    // ---- epilogue ----
    if (isH) {
#pragma unroll
        for (int nt = 0; nt < 16; ++nt) {
            const int col = nt * 16 + c15;
            const float bv = b_h1[col];
#pragma unroll
            for (int m = 0; m < 2; ++m)
#pragma unroll
                for (int r = 0; r < 4; ++r) {
                    const int row = rt0 + m * 16 + quad * 4 + r;
                    float v = acc[m][nt][r] + bv;
                    Abase[(size_t)row * KP + col] = f2h(v > 0.f ? v : 0.f);
                }
        }
    } else {
#pragma unroll
        for (int nt = 0; nt < 16; ++nt) {
            const int col = nt * 16 + c15;
#pragma unroll
            for (int m = 0; m < 2; ++m)
#pragma unroll
                for (int r = 0; r < 4; ++r) {
                    const int row = rt0 + m * 16 + quad * 4 + r;
                    HR[(size_t)row * 256 + col] = acc[m][nt][r];
                }
        }
    }
}

// ============ k2_heads: second GEMM, A+B pipelined, B dbuf (1 barrier/kt) ============
template <bool PATHA>
__global__ __launch_bounds__(256)
void k2_heads(unsigned short* __restrict__ wsu,
              const float* __restrict__ b1a, const float* __restrict__ b1b,
              const float* __restrict__ w2a, const float* __restrict__ b2a,
              const float* __restrict__ w2b, const float* __restrict__ b2b,
              const float* __restrict__ bd1, float* __restrict__ out)
{
    constexpr int NT2 = PATHA ? 16 : 8;
    constexpr int NI4 = NT2 / 4;             // int4s per thread per tile
    __shared__ __align__(16) unsigned short Bsh[2][NT2 * 512];
    const int tid = threadIdx.x, l = tid & 63, w = tid >> 6;
    const int c = l & 15, quad = l >> 4;
    const int M0 = blockIdx.x * 64;
    const unsigned short* PW = wsu + (PATHA ? PW2_OFF : PWD2_OFF);

    f32x4 acc[NT2];
#pragma unroll
    for (int n = 0; n < NT2; ++n) acc[n] = (f32x4){0.f, 0.f, 0.f, 0.f};

    const int row = M0 + w * 16 + c;
    const unsigned short* arow = nullptr;
    const float* h1p = nullptr; const float* h0p = nullptr;
    if (PATHA) {
        arow = wsu + PA_OFF + (size_t)row * KP + quad * 8;
    } else {
        const float* HR = (const float*)(wsu + PD_OFF);
        const int sbk = row / 19, dt = row % 19;
        h0p = HR + (size_t)(sbk * 20 + dt) * 256 + quad * 8;
        h1p = h0p + 256;
    }

    // prologue: stage B(0) -> buf0; load A(0)
    {
        const int4* src = (const int4*)(PW);
        int4* dst = (int4*)Bsh[0];
#pragma unroll
        for (int cc = 0; cc < NI4; ++cc)
            dst[tid + 256 * cc] = src[tid + 256 * cc];
    }
    half8 curPA = {};
    float4 c1a = {}, c1b = {}, c0a = {}, c0b = {};
    if (PATHA) {
        curPA = *(const half8*)(arow);
    } else {
        c1a = *(const float4*)(h1p); c1b = *(const float4*)(h1p + 4);
        c0a = *(const float4*)(h0p); c0b = *(const float4*)(h0p + 4);
    }
    __syncthreads();

    for (int kt = 0; kt < 8; ++kt) {
        const int db = kt & 1;
        // ---- next A / HR loads ----
        half8 nxtPA = curPA;
        float4 n1a = c1a, n1b = c1b, n0a = c0a, n0b = c0b;
        if (kt + 1 < 8) {
            if (PATHA) {
                nxtPA = *(const half8*)(arow + (kt + 1) * 32);
            } else {
                n1a = *(const float4*)(h1p + (kt + 1) * 32);
                n1b = *(const float4*)(h1p + (kt + 1) * 32 + 4);
                n0a = *(const float4*)(h0p + (kt + 1) * 32);
                n0b = *(const float4*)(h0p + (kt + 1) * 32 + 4);
            }
        }
        // ---- next B prefetch into registers ----
        int4 rB[NI4];
        if (kt + 1 < 8) {
            const int4* src = (const int4*)(PW + (size_t)(kt + 1) * (NT2 * 512));
#pragma unroll
            for (int cc = 0; cc < NI4; ++cc) rB[cc] = src[tid + 256 * cc];
        }
        // ---- build A fragment from current registers ----
        half8 af;
        if (PATHA) {
            af = curPA;
        } else {
            float4 bb = *(const float4*)(bd1 + kt * 32 + quad * 8);
            float4 bb2 = *(const float4*)(bd1 + kt * 32 + quad * 8 + 4);
            float v0 = fmaxf(c1a.x - c0a.x + bb.x, 0.f);
            float v1 = fmaxf(c1a.y - c0a.y + bb.y, 0.f);
            float v2 = fmaxf(c1a.z - c0a.z + bb.z, 0.f);
            float v3 = fmaxf(c1a.w - c0a.w + bb.w, 0.f);
            float v4 = fmaxf(c1b.x - c0b.x + bb2.x, 0.f);
            float v5 = fmaxf(c1b.y - c0b.y + bb2.y, 0.f);
            float v6 = fmaxf(c1b.z - c0b.z + bb2.z, 0.f);
            float v7 = fmaxf(c1b.w - c0b.w + bb2.w, 0.f);
            union { unsigned u[4]; half8 h8; } pk;
            pk.u[0] = (unsigned)f2h(v0) | ((unsigned)f2h(v1) << 16);
            pk.u[1] = (unsigned)f2h(v2) | ((unsigned)f2h(v3) << 16);
            pk.u[2] = (unsigned)f2h(v4) | ((unsigned)f2h(v5) << 16);
            pk.u[3] = (unsigned)f2h(v6) | ((unsigned)f2h(v7) << 16);
            af = pk.h8;
        }
#pragma unroll
        for (int nt = 0; nt < NT2; ++nt) {
            half8 bf = *(const half8*)(Bsh[db] + nt * 512 + l * 8);
            acc[nt] = __builtin_amdgcn_mfma_f32_16x16x32_f16(af, bf, acc[nt], 0, 0, 0);
        }
        if (kt + 1 < 8) {
            int4* dst = (int4*)Bsh[db ^ 1];
#pragma unroll
            for (int cc = 0; cc < NI4; ++cc) dst[tid + 256 * cc] = rB[cc];
        }
        curPA = nxtPA;
        c1a = n1a; c1b = n1b; c0a = n0a; c0b = n0b;
        __syncthreads();
    }
#pragma unroll
    for (int nt = 0; nt < NT2; ++nt) {
        float bv;
        if (PATHA) bv = (nt < 8) ? b1a[nt * 16 + c] : b1b[(nt - 8) * 16 + c];
        else       bv = b1a[nt * 16 + c];
#pragma unroll
        for (int r = 0; r < 4; ++r) {
            float v = acc[nt][r] + bv;
            acc[nt][r] = v > 0.f ? v : 0.f;
        }
    }
    float pm[2][4], ps[2][4];
#pragma unroll
    for (int d = 0; d < 2; ++d)
#pragma unroll
        for (int r = 0; r < 4; ++r) { pm[d][r] = 0.f; ps[d][r] = 0.f; }
#pragma unroll
    for (int d = 0; d < 2; ++d)
#pragma unroll
        for (int nt = 0; nt < 8; ++nt) {
            const float wmv = w2a[(nt * 16 + c) * 2 + d];
            float wsv = 0.f;
            if (PATHA) wsv = w2b[(nt * 16 + c) * 2 + d];
#pragma unroll
            for (int r = 0; r < 4; ++r) {
                pm[d][r] = fmaf(acc[nt][r], wmv, pm[d][r]);
                if (PATHA) ps[d][r] = fmaf(acc[nt + 8][r], wsv, ps[d][r]);
            }
        }
#pragma unroll
    for (int o = 1; o < 16; o <<= 1)
#pragma unroll
        for (int d = 0; d < 2; ++d)
#pragma unroll
            for (int r = 0; r < 4; ++r) {
                pm[d][r] += __shfl_xor(pm[d][r], o, 64);
                if (PATHA) ps[d][r] += __shfl_xor(ps[d][r], o, 64);
            }
    if (c == 0) {
#pragma unroll
        for (int r = 0; r < 4; ++r) {
            const int orow = M0 + w * 16 + quad * 4 + r;
            if (PATHA) {
                const int sbk = orow / 20, t = orow % 20;
                const int sb = sbk / 3, kk = sbk % 3;
                const int oi = ((sb * 20 + t) * 3 + kk) * 2;
                out[oi + 0] = tanhf(pm[0][r] + b2a[0]);
                out[oi + 1] = tanhf(pm[1][r] + b2a[1]);
                out[30720 + oi + 0] = __expf(ps[0][r] + b2b[0]);
                out[30720 + oi + 1] = __expf(ps[1][r] + b2b[1]);
            } else {
                const int sbk = orow / 19, dt = orow % 19;
                const int sb = sbk / 3, kk = sbk % 3;
                const int oi = 61440 + ((sb * 19 + dt) * 3 + kk) * 2;
                out[oi + 0] = tanhf(pm[0][r] + b2a[0]);
                out[oi + 1] = tanhf(pm[1][r] + b2a[1]);
            }
        }
    }
}

extern "C" void kernel_launch(void* const* d_in, const int* in_sizes, int n_in,
                              void* d_out, int out_size, void* d_ws, size_t ws_size,
                              hipStream_t stream) {
    const float* frames = (const float*)d_in[0];
    const float* digit  = (const float*)d_in[1];
    const float* w_h1   = (const float*)d_in[2];
    const float* b_h1   = (const float*)d_in[3];
    const float* wm1    = (const float*)d_in[4];
    const float* bm1    = (const float*)d_in[5];
    const float* wm2    = (const float*)d_in[6];
    const float* bm2    = (const float*)d_in[7];
    const float* ws1    = (const float*)d_in[8];
    const float* bs1    = (const float*)d_in[9];
    const float* ws2    = (const float*)d_in[10];
    const float* bs2    = (const float*)d_in[11];
    const float* wd1    = (const float*)d_in[12];
    const float* bd1    = (const float*)d_in[13];
    const float* wd2    = (const float*)d_in[14];
    const float* bd2    = (const float*)d_in[15];
    const float* wd3    = (const float*)d_in[16];
    const float* bd3    = (const float*)d_in[17];

    unsigned short* wsu = (unsigned short*)d_ws;
    float* tsum = (float*)(wsu + TSUM_OFF);
    float2* stats = (float2*)(wsu + STAT_OFF);
    float* o = (float*)d_out;

    k0_pack<<<dim3(3328), dim3(256), 0, stream>>>(w_h1, wd1, wm1, ws1, wd2, digit, wsu, tsum);
    k1a_corr<<<dim3(640), dim3(512), 0, stream>>>(frames, digit, tsum, wsu);
    k1b_stats<<<dim3(3840), dim3(256), 0, stream>>>(wsu, stats);               // softmax stats
    k2_gemmAB<<<dim3(240), dim3(256), 0, stream>>>(wsu, b_h1, stats);          // fused hidden+Hraw
    k2_heads<true><<<dim3(240), dim3(256), 0, stream>>>(wsu, bm1, bs1, wm2, bm2, ws2, bs2, nullptr, o);
    k2_heads<false><<<dim3(228), dim3(256), 0, stream>>>(wsu, bd2, nullptr, wd3, bd3, nullptr, nullptr, bd1, o);
}

// Round 18
// 138.722 us; speedup vs baseline: 2.6419x; 1.0767x over previous
//
#include <hip/hip_runtime.h>
#include <hip/hip_fp16.h>

typedef __attribute__((ext_vector_type(8))) _Float16 half8;
typedef __attribute__((ext_vector_type(2))) _Float16 h2f;
typedef __attribute__((ext_vector_type(4))) float f32x4;

#define NP 1369
#define KP 1376          /* padded row stride: 43 tiles of 32 */
#define NKT 43
#define ROWS_A 15360     /* 768 sbk * 20 t  */
#define ROWS_D 14592     /* 768 sbk * 19 dt */

/* ws layout (ushort units). total = 84,119,488 B <= 84.25MB proven */
#define PA_OFF   0
#define PD_OFF   (ROWS_A * KP)          /* holds Hraw fp32 15360x256 */
#define PWH_OFF  (PD_OFF + ROWS_D * KP)
#define PWD_OFF  (PWH_OFF + NKT * 16 * 512)
#define PW2_OFF  (PWD_OFF + NKT * 16 * 512)
#define PWD2_OFF (PW2_OFF + 8 * 16 * 512)
#define TSUM_OFF (PWD2_OFF + 8 * 8 * 512)   /* 768 floats */
#define STAT_OFF (TSUM_OFF + 1536)          /* 15360 float2 */

__device__ __forceinline__ unsigned short f2h(float f) {
    __half h = __float2half(f);
    return __half_as_ushort(h);
}
__device__ __forceinline__ h2f u2h2(unsigned int u) {
    h2f r; __builtin_memcpy(&r, &u, 4); return r;
}

// ============ k0: pack weights (fp16 B-frags) + tsum baselines ============
__global__ __launch_bounds__(256)
void k0_pack(const float* __restrict__ w_h1, const float* __restrict__ wd1,
             const float* __restrict__ wm1,  const float* __restrict__ ws1,
             const float* __restrict__ wd2,  const float* __restrict__ digit,
             unsigned short* __restrict__ wsu, float* __restrict__ tsum)
{
    const int tid = threadIdx.x;
    if (blockIdx.x >= 3136) {            // tsum blocks: 4 sbk per block
        const int sbk = (blockIdx.x - 3136) * 4 + (tid >> 6);
        const int l = tid & 63;
        const float* tp = digit + (size_t)sbk * 784;
        float s = 0.f;
        for (int i = l; i < 784; i += 64) s += tp[i];
        for (int o = 32; o; o >>= 1) s += __shfl_xor(s, o, 64);
        if (l == 0) tsum[sbk] = 0.5f * s;
        return;
    }
    int idx = blockIdx.x * 256 + tid;      // 0..802815
    int local, mode;
    unsigned short* dst;
    if (idx < 352256)      { mode = 0; local = idx;          dst = wsu + PWH_OFF; }
    else if (idx < 704512) { mode = 1; local = idx - 352256; dst = wsu + PWD_OFF; }
    else if (idx < 770048) { mode = 2; local = idx - 704512; dst = wsu + PW2_OFF; }
    else                   { mode = 3; local = idx - 770048; dst = wsu + PWD2_OFF; }
    int j = local & 7, lane = (local >> 3) & 63, rest = local >> 9;
    int NTn = (mode == 3) ? 8 : 16;
    int nt = rest % NTn, kt = rest / NTn;
    int k = kt * 32 + ((lane >> 4) << 3) + j;
    int n = nt * 16 + (lane & 15);
    float v = 0.f;
    if (mode == 0)      { if (k < NP) v = w_h1[k * 256 + n]; }
    else if (mode == 1) { if (k < NP) v = wd1[k * 256 + n]; }
    else if (mode == 2) { v = (n < 128) ? wm1[k * 128 + n] : ws1[k * 128 + (n - 128)]; }
    else                { v = wd2[k * 128 + n]; }
    dst[local] = f2h(v);
}

// ============ k1a: im2col MFMA correlation, N=48, split-B restaging ============
// grid 640 = (b 16) x (t 20) x (M-half 2); block 512 (8 waves). LDS 52.4KB.
// Epilogue: LDS-transpose (aliased onto Bs) -> coalesced 256B-per-row PA writes.
__global__ __launch_bounds__(512)
void k1a_corr(const float* __restrict__ frames, const float* __restrict__ digit,
              const float* __restrict__ tsum, unsigned short* __restrict__ wsu)
{
    __shared__ __align__(16) unsigned short Bs[14 * 3 * 512];  // 43,008 B; aliased as TT[48][136]
    __shared__ __align__(16) unsigned int frd[64 * 36];        // 9,216 B
    __shared__ float Cn[48];

    const int tid = threadIdx.x, l = tid & 63, w = tid >> 6;
    const int mh = blockIdx.x & 1;
    const int bt = blockIdx.x >> 1;
    const int t  = bt % 20;
    const int bb = bt / 20;

    if (tid < 48) {
        int sbk_n = ((tid / 3) * 16 + bb) * 3 + (tid % 3);
        Cn[tid] = tsum[sbk_n];
    }
    if (tid < 256) frd[(tid >> 2) * 36 + 32 + (tid & 3)] = 0u;
    {
        const float4* fp4 = (const float4*)(frames + (size_t)(bb * 20 + t) * 4096);
        for (int idx = tid; idx < 1024; idx += 512) {
            float4 v = fp4[idx];
            int r = idx >> 4, c4 = idx & 15;
            unsigned lo = (unsigned)f2h(v.x) | ((unsigned)f2h(v.y) << 16);
            unsigned hi = (unsigned)f2h(v.z) | ((unsigned)f2h(v.w) << 16);
            *(uint2*)&frd[r * 36 + c4 * 2] = make_uint2(lo, hi);
        }
    }

    const int c15 = l & 15, quad = l >> 4, v0q = quad << 3;
    const int cnt = (50 - w) / 8;        // waves 0-2: 6 tiles, 3-7: 5 tiles (43 total)

    int baseb[6]; unsigned shv[6];
#pragma unroll
    for (int it = 0; it < 6; ++it) {
        int tI = mh * 43 + w + 8 * it;
        int p  = tI * 16 + c15;
        int pc = p > 1368 ? 1368 : p;
        int i  = pc / 37;
        int jj = pc - i * 37;
        int c  = jj + v0q;
        baseb[it] = i * 144 + (c >> 1) * 4;
        shv[it]   = (unsigned)((c & 1) << 4);
    }
    f32x4 acc[6][3];
#pragma unroll
    for (int it = 0; it < 6; ++it)
#pragma unroll
        for (int nt = 0; nt < 3; ++nt) acc[it][nt] = (f32x4){0.f, 0.f, 0.f, 0.f};

    for (int ph = 0; ph < 2; ++ph) {
        __syncthreads();   // frd/Cn ready (ph0); Bs consumers done (ph1)
        // ---- stage B for kt = ph*14 .. ph*14+13 ----
        for (int s = tid; s < 2688; s += 512) {
            int ktl = s / 192;
            int rem = s - ktl * 192;
            int nt = rem >> 6, sl = rem & 63;
            int nl = nt * 16 + (sl & 15);
            int v0 = (sl >> 4) << 3;
            int kt = ph * 14 + ktl;
            int sbk_n = ((nl / 3) * 16 + bb) * 3 + (nl % 3);
            const float* tp = digit + (size_t)sbk_n * 784 + kt * 28 + v0;
            float4 fa = *(const float4*)tp;
            float4 fb = (v0 <= 16) ? *(const float4*)(tp + 4) : make_float4(0.f, 0.f, 0.f, 0.f);
            uint4 pk;
            pk.x = (unsigned)f2h(fa.x) | ((unsigned)f2h(fa.y) << 16);
            pk.y = (unsigned)f2h(fa.z) | ((unsigned)f2h(fa.w) << 16);
            pk.z = (unsigned)f2h(fb.x) | ((unsigned)f2h(fb.y) << 16);
            pk.w = (unsigned)f2h(fb.z) | ((unsigned)f2h(fb.w) << 16);
            *(uint4*)(Bs + s * 8) = pk;
        }
        __syncthreads();

        for (int ktl = 0; ktl < 14; ++ktl) {
            const int kt = ph * 14 + ktl;
            half8 bf0 = *(const half8*)(Bs + ktl * 1536 + 0 * 512 + l * 8);
            half8 bf1 = *(const half8*)(Bs + ktl * 1536 + 1 * 512 + l * 8);
            half8 bf2 = *(const half8*)(Bs + ktl * 1536 + 2 * 512 + l * 8);
            const char* fbase = (const char*)frd + kt * 144;
#pragma unroll
            for (int it = 0; it < 6; ++it) {
                if (it < cnt) {
                    const char* ap = fbase + baseb[it];
                    unsigned w0 = *(const unsigned*)(ap);
                    unsigned w1 = *(const unsigned*)(ap + 4);
                    unsigned w2 = *(const unsigned*)(ap + 8);
                    unsigned w3 = *(const unsigned*)(ap + 12);
                    unsigned w4 = *(const unsigned*)(ap + 16);
                    unsigned sh = shv[it];
                    union { unsigned u[4]; half8 h8; } af;
                    af.u[0] = (unsigned)(((((unsigned long long)w1) << 32) | w0) >> sh);
                    af.u[1] = (unsigned)(((((unsigned long long)w2) << 32) | w1) >> sh);
                    af.u[2] = (unsigned)(((((unsigned long long)w3) << 32) | w2) >> sh);
                    af.u[3] = (unsigned)(((((unsigned long long)w4) << 32) | w3) >> sh);
                    acc[it][0] = __builtin_amdgcn_mfma_f32_16x16x32_f16(af.h8, bf0, acc[it][0], 0, 0, 0);
                    acc[it][1] = __builtin_amdgcn_mfma_f32_16x16x32_f16(af.h8, bf1, acc[it][1], 0, 0, 0);
                    acc[it][2] = __builtin_amdgcn_mfma_f32_16x16x32_f16(af.h8, bf2, acc[it][2], 0, 0, 0);
                }
            }
        }
    }

    // ---- epilogue: per it-group, LDS transpose (TT=Bs alias) -> coalesced writes ----
    // TT row stride 136 halfs. Group itg covers within-half cols [itg*128, +128)
    // (48 cols for itg==5). Copy-out in 8-half (uint4) segments.
    for (int itg = 0; itg < 6; ++itg) {
        __syncthreads();   // previous itg copy (or main-loop Bs reads) done
        if (itg < cnt) {
#pragma unroll
            for (int nt = 0; nt < 3; ++nt) {
                const int nl = nt * 16 + c15;
                const float C = Cn[nl];
                ushort4 st;
                st.x = f2h(acc[itg][nt][0] - C);
                st.y = f2h(acc[itg][nt][1] - C);
                st.z = f2h(acc[itg][nt][2] - C);
                st.w = f2h(acc[itg][nt][3] - C);
                *(ushort4*)(Bs + nl * 136 + w * 16 + quad * 4) = st;
            }
        }
        __syncthreads();
        const int nseg = (itg == 5) ? 6 : 16;   // 8-half segments per row
        for (int i = tid; i < 48 * nseg; i += 512) {
            int rowl = i / nseg, seg = i - rowl * nseg;
            int sbk_n = ((rowl / 3) * 16 + bb) * 3 + (rowl % 3);
            uint4 v = *(const uint4*)(Bs + rowl * 136 + seg * 8);
            *(uint4*)(wsu + PA_OFF + (size_t)(sbk_n * 20 + t) * KP
                      + mh * 688 + itg * 128 + seg * 8) = v;
        }
    }
}

// ============ k1b_stats: per-row softmax stats (mx, 1/sum) -> stats buf ============
__global__ __launch_bounds__(256)
void k1b_stats(const unsigned short* __restrict__ wsu, float2* __restrict__ stats)
{
    const int l = threadIdx.x & 63, wv = threadIdx.x >> 6;
    const int row = blockIdx.x * 4 + wv;
    const unsigned* rp = (const unsigned*)(wsu + PA_OFF + (size_t)row * KP);

    float f0[11], f1[11];
    float mx = -3.0e38f;
#pragma unroll
    for (int i = 0; i < 11; ++i) {
        int q = l + i * 64;
        unsigned u = (q < 685) ? rp[q] : 0u;
        h2f h = u2h2(u);
        f0[i] = (q < 685) ? (float)h[0] : -3.0e38f;
        f1[i] = (q < 684) ? (float)h[1] : -3.0e38f;
        mx = fmaxf(mx, fmaxf(f0[i], f1[i]));
    }
    for (int o = 32; o; o >>= 1) mx = fmaxf(mx, __shfl_xor(mx, o, 64));
    float sum = 0.f;
#pragma unroll
    for (int i = 0; i < 11; ++i)
        sum += __expf(f0[i] - mx) + __expf(f1[i] - mx);
    for (int o = 32; o; o >>= 1) sum += __shfl_xor(sum, o, 64);
    if (l == 0) stats[row] = make_float2(mx, 1.0f / sum);
}

// ============ k2_gemmAB: merged GEMMs, 8 waves (4H+4D), A+B pipelined ============
// grid 240, block 512. Waves 0-3: H rows M0+wl*16; waves 4-7: D same rows.
__global__ __launch_bounds__(512)
void k2_gemmAB(unsigned short* __restrict__ wsu, const float* __restrict__ b_h1,
               const float2* __restrict__ stats)
{
    __shared__ __align__(16) unsigned short Bbuf[2][2 * 8192];   // [dbuf][{H,D}] 64KB

    const int tid = threadIdx.x, l = tid & 63, w = tid >> 6;
    const int c15 = l & 15, quad = l >> 4;
    const int M0 = blockIdx.x * 64;
    unsigned short* Abase = wsu + PA_OFF;
    const unsigned short* PWH = wsu + PWH_OFF;
    const unsigned short* PWD = wsu + PWD_OFF;
    float* HR = (float*)(wsu + PD_OFF);

    const bool isH = (w < 4);
    const int wl = w & 3;
    const int row0 = M0 + wl * 16 + c15;
    const unsigned short* a0p = Abase + (size_t)row0 * KP + quad * 8;
    float2 st0 = make_float2(0.f, 0.f);
    if (isH) st0 = stats[row0];

    f32x4 acc[16];
#pragma unroll
    for (int n = 0; n < 16; ++n) acc[n] = (f32x4){0.f, 0.f, 0.f, 0.f};

    // prologue: stage B(0) -> buf0 (512 thr x 2 int4 per matrix); load A(0)
    {
        const int4* sH = (const int4*)(PWH);
        const int4* sD = (const int4*)(PWD);
        int4* dH = (int4*)(Bbuf[0]);
        int4* dD = (int4*)(Bbuf[0] + 8192);
#pragma unroll
        for (int c = 0; c < 2; ++c) {
            dH[tid + 512 * c] = sH[tid + 512 * c];
            dD[tid + 512 * c] = sD[tid + 512 * c];
        }
    }
    half8 curA = *(const half8*)(a0p);
    __syncthreads();

    for (int kt = 0; kt < NKT; ++kt) {
        const int db = kt & 1;
        // ---- issue NEXT A load ----
        half8 nxtA = curA;
        if (kt + 1 < NKT) nxtA = *(const half8*)(a0p + (kt + 1) * 32);
        // ---- issue NEXT B loads into registers ----
        int4 rH[2], rD[2];
        if (kt + 1 < NKT) {
            const int4* sH = (const int4*)(PWH + (size_t)(kt + 1) * 8192);
            const int4* sD = (const int4*)(PWD + (size_t)(kt + 1) * 8192);
#pragma unroll
            for (int c = 0; c < 2; ++c) {
                rH[c] = sH[tid + 512 * c];
                rD[c] = sD[tid + 512 * c];
            }
        }
        // ---- transform current A ----
        half8 af = curA;
        if (isH) {
            union { half8 h8; unsigned u[4]; } ia, oa;
            ia.h8 = af;
#pragma unroll
            for (int q = 0; q < 4; ++q) {
                h2f ha = u2h2(ia.u[q]);
                float a0 = __expf((float)ha[0] - st0.x) * st0.y;
                float a1 = __expf((float)ha[1] - st0.x) * st0.y;
                oa.u[q] = (unsigned)f2h(a0) | ((unsigned)f2h(a1) << 16);
            }
            af = oa.h8;
        }
        // ---- MFMA ----
        const unsigned short* bb = Bbuf[db] + (isH ? 0 : 8192);
#pragma unroll
        for (int nt = 0; nt < 16; ++nt) {
            half8 bf = *(const half8*)(bb + nt * 512 + l * 8);
            acc[nt] = __builtin_amdgcn_mfma_f32_16x16x32_f16(af, bf, acc[nt], 0, 0, 0);
        }
        // ---- write staged B to the other buffer ----
        if (kt + 1 < NKT) {
            int4* dH = (int4*)(Bbuf[db ^ 1]);
            int4* dD = (int4*)(Bbuf[db ^ 1] + 8192);
#pragma unroll
            for (int c = 0; c < 2; ++c) {
                dH[tid + 512 * c] = rH[c];
                dD[tid + 512 * c] = rD[c];
            }
        }
        curA = nxtA;
        __syncthreads();
    }

    // ---- epilogue ----
    if (isH) {
#pragma unroll
        for (int nt = 0; nt < 16; ++nt) {
            const int col = nt * 16 + c15;
            const float bv = b_h1[col];
#pragma unroll
            for (int r = 0; r < 4; ++r) {
                const int row = M0 + wl * 16 + quad * 4 + r;
                float v = acc[nt][r] + bv;
                Abase[(size_t)row * KP + col] = f2h(v > 0.f ? v : 0.f);
            }
        }
    } else {
#pragma unroll
        for (int nt = 0; nt < 16; ++nt) {
            const int col = nt * 16 + c15;
#pragma unroll
            for (int r = 0; r < 4; ++r) {
                const int row = M0 + wl * 16 + quad * 4 + r;
                HR[(size_t)row * 256 + col] = acc[nt][r];
            }
        }
    }
}

// ============ k2_heads: second GEMM, A+B pipelined, B dbuf (1 barrier/kt) ============
template <bool PATHA>
__global__ __launch_bounds__(256)
void k2_heads(unsigned short* __restrict__ wsu,
              const float* __restrict__ b1a, const float* __restrict__ b1b,
              const float* __restrict__ w2a, const float* __restrict__ b2a,
              const float* __restrict__ w2b, const float* __restrict__ b2b,
              const float* __restrict__ bd1, float* __restrict__ out)
{
    constexpr int NT2 = PATHA ? 16 : 8;
    constexpr int NI4 = NT2 / 4;             // int4s per thread per tile
    __shared__ __align__(16) unsigned short Bsh[2][NT2 * 512];
    const int tid = threadIdx.x, l = tid & 63, w = tid >> 6;
    const int c = l & 15, quad = l >> 4;
    const int M0 = blockIdx.x * 64;
    const unsigned short* PW = wsu + (PATHA ? PW2_OFF : PWD2_OFF);

    f32x4 acc[NT2];
#pragma unroll
    for (int n = 0; n < NT2; ++n) acc[n] = (f32x4){0.f, 0.f, 0.f, 0.f};

    const int row = M0 + w * 16 + c;
    const unsigned short* arow = nullptr;
    const float* h1p = nullptr; const float* h0p = nullptr;
    if (PATHA) {
        arow = wsu + PA_OFF + (size_t)row * KP + quad * 8;
    } else {
        const float* HR = (const float*)(wsu + PD_OFF);
        const int sbk = row / 19, dt = row % 19;
        h0p = HR + (size_t)(sbk * 20 + dt) * 256 + quad * 8;
        h1p = h0p + 256;
    }

    // prologue: stage B(0) -> buf0; load A(0)
    {
        const int4* src = (const int4*)(PW);
        int4* dst = (int4*)Bsh[0];
#pragma unroll
        for (int cc = 0; cc < NI4; ++cc)
            dst[tid + 256 * cc] = src[tid + 256 * cc];
    }
    half8 curPA = {};
    float4 c1a = {}, c1b = {}, c0a = {}, c0b = {};
    if (PATHA) {
        curPA = *(const half8*)(arow);
    } else {
        c1a = *(const float4*)(h1p); c1b = *(const float4*)(h1p + 4);
        c0a = *(const float4*)(h0p); c0b = *(const float4*)(h0p + 4);
    }
    __syncthreads();

    for (int kt = 0; kt < 8; ++kt) {
        const int db = kt & 1;
        // ---- next A / HR loads ----
        half8 nxtPA = curPA;
        float4 n1a = c1a, n1b = c1b, n0a = c0a, n0b = c0b;
        if (kt + 1 < 8) {
            if (PATHA) {
                nxtPA = *(const half8*)(arow + (kt + 1) * 32);
            } else {
                n1a = *(const float4*)(h1p + (kt + 1) * 32);
                n1b = *(const float4*)(h1p + (kt + 1) * 32 + 4);
                n0a = *(const float4*)(h0p + (kt + 1) * 32);
                n0b = *(const float4*)(h0p + (kt + 1) * 32 + 4);
            }
        }
        // ---- next B prefetch into registers ----
        int4 rB[NI4];
        if (kt + 1 < 8) {
            const int4* src = (const int4*)(PW + (size_t)(kt + 1) * (NT2 * 512));
#pragma unroll
            for (int cc = 0; cc < NI4; ++cc) rB[cc] = src[tid + 256 * cc];
        }
        // ---- build A fragment from current registers ----
        half8 af;
        if (PATHA) {
            af = curPA;
        } else {
            float4 bb = *(const float4*)(bd1 + kt * 32 + quad * 8);
            float4 bb2 = *(const float4*)(bd1 + kt * 32 + quad * 8 + 4);
            float v0 = fmaxf(c1a.x - c0a.x + bb.x, 0.f);
            float v1 = fmaxf(c1a.y - c0a.y + bb.y, 0.f);
            float v2 = fmaxf(c1a.z - c0a.z + bb.z, 0.f);
            float v3 = fmaxf(c1a.w - c0a.w + bb.w, 0.f);
            float v4 = fmaxf(c1b.x - c0b.x + bb2.x, 0.f);
            float v5 = fmaxf(c1b.y - c0b.y + bb2.y, 0.f);
            float v6 = fmaxf(c1b.z - c0b.z + bb2.z, 0.f);
            float v7 = fmaxf(c1b.w - c0b.w + bb2.w, 0.f);
            union { unsigned u[4]; half8 h8; } pk;
            pk.u[0] = (unsigned)f2h(v0) | ((unsigned)f2h(v1) << 16);
            pk.u[1] = (unsigned)f2h(v2) | ((unsigned)f2h(v3) << 16);
            pk.u[2] = (unsigned)f2h(v4) | ((unsigned)f2h(v5) << 16);
            pk.u[3] = (unsigned)f2h(v6) | ((unsigned)f2h(v7) << 16);
            af = pk.h8;
        }
#pragma unroll
        for (int nt = 0; nt < NT2; ++nt) {
            half8 bf = *(const half8*)(Bsh[db] + nt * 512 + l * 8);
            acc[nt] = __builtin_amdgcn_mfma_f32_16x16x32_f16(af, bf, acc[nt], 0, 0, 0);
        }
        if (kt + 1 < 8) {
            int4* dst = (int4*)Bsh[db ^ 1];
#pragma unroll
            for (int cc = 0; cc < NI4; ++cc) dst[tid + 256 * cc] = rB[cc];
        }
        curPA = nxtPA;
        c1a = n1a; c1b = n1b; c0a = n0a; c0b = n0b;
        __syncthreads();
    }
#pragma unroll
    for (int nt = 0; nt < NT2; ++nt) {
        float bv;
        if (PATHA) bv = (nt < 8) ? b1a[nt * 16 + c] : b1b[(nt - 8) * 16 + c];
        else       bv = b1a[nt * 16 + c];
#pragma unroll
        for (int r = 0; r < 4; ++r) {
            float v = acc[nt][r] + bv;
            acc[nt][r] = v > 0.f ? v : 0.f;
        }
    }
    float pm[2][4], ps[2][4];
#pragma unroll
    for (int d = 0; d < 2; ++d)
#pragma unroll
        for (int r = 0; r < 4; ++r) { pm[d][r] = 0.f; ps[d][r] = 0.f; }
#pragma unroll
    for (int d = 0; d < 2; ++d)
#pragma unroll
        for (int nt = 0; nt < 8; ++nt) {
            const float wmv = w2a[(nt * 16 + c) * 2 + d];
            float wsv = 0.f;
            if (PATHA) wsv = w2b[(nt * 16 + c) * 2 + d];
#pragma unroll
            for (int r = 0; r < 4; ++r) {
                pm[d][r] = fmaf(acc[nt][r], wmv, pm[d][r]);
                if (PATHA) ps[d][r] = fmaf(acc[nt + 8][r], wsv, ps[d][r]);
            }
        }
#pragma unroll
    for (int o = 1; o < 16; o <<= 1)
#pragma unroll
        for (int d = 0; d < 2; ++d)
#pragma unroll
            for (int r = 0; r < 4; ++r) {
                pm[d][r] += __shfl_xor(pm[d][r], o, 64);
                if (PATHA) ps[d][r] += __shfl_xor(ps[d][r], o, 64);
            }
    if (c == 0) {
#pragma unroll
        for (int r = 0; r < 4; ++r) {
            const int orow = M0 + w * 16 + quad * 4 + r;
            if (PATHA) {
                const int sbk = orow / 20, t = orow % 20;
                const int sb = sbk / 3, kk = sbk % 3;
                const int oi = ((sb * 20 + t) * 3 + kk) * 2;
                out[oi + 0] = tanhf(pm[0][r] + b2a[0]);
                out[oi + 1] = tanhf(pm[1][r] + b2a[1]);
                out[30720 + oi + 0] = __expf(ps[0][r] + b2b[0]);
                out[30720 + oi + 1] = __expf(ps[1][r] + b2b[1]);
            } else {
                const int sbk = orow / 19, dt = orow % 19;
                const int sb = sbk / 3, kk = sbk % 3;
                const int oi = 61440 + ((sb * 19 + dt) * 3 + kk) * 2;
                out[oi + 0] = tanhf(pm[0][r] + b2a[0]);
                out[oi + 1] = tanhf(pm[1][r] + b2a[1]);
            }
        }
    }
}

extern "C" void kernel_launch(void* const* d_in, const int* in_sizes, int n_in,
                              void* d_out, int out_size, void* d_ws, size_t ws_size,
                              hipStream_t stream) {
    const float* frames = (const float*)d_in[0];
    const float* digit  = (const float*)d_in[1];
    const float* w_h1   = (const float*)d_in[2];
    const float* b_h1   = (const float*)d_in[3];
    const float* wm1    = (const float*)d_in[4];
    const float* bm1    = (const float*)d_in[5];
    const float* wm2    = (const float*)d_in[6];
    const float* bm2    = (const float*)d_in[7];
    const float* ws1    = (const float*)d_in[8];
    const float* bs1    = (const float*)d_in[9];
    const float* ws2    = (const float*)d_in[10];
    const float* bs2    = (const float*)d_in[11];
    const float* wd1    = (const float*)d_in[12];
    const float* bd1    = (const float*)d_in[13];
    const float* wd2    = (const float*)d_in[14];
    const float* bd2    = (const float*)d_in[15];
    const float* wd3    = (const float*)d_in[16];
    const float* bd3    = (const float*)d_in[17];

    unsigned short* wsu = (unsigned short*)d_ws;
    float* tsum = (float*)(wsu + TSUM_OFF);
    float2* stats = (float2*)(wsu + STAT_OFF);
    float* o = (float*)d_out;

    k0_pack<<<dim3(3328), dim3(256), 0, stream>>>(w_h1, wd1, wm1, ws1, wd2, digit, wsu, tsum);
    k1a_corr<<<dim3(640), dim3(512), 0, stream>>>(frames, digit, tsum, wsu);
    k1b_stats<<<dim3(3840), dim3(256), 0, stream>>>(wsu, stats);               // softmax stats
    k2_gemmAB<<<dim3(240), dim3(512), 0, stream>>>(wsu, b_h1, stats);          // fused hidden+Hraw
    k2_heads<true><<<dim3(240), dim3(256), 0, stream>>>(wsu, bm1, bs1, wm2, bm2, ws2, bs2, nullptr, o);
    k2_heads<false><<<dim3(228), dim3(256), 0, stream>>>(wsu, bd2, nullptr, wd3, bd3, nullptr, nullptr, bd1, o);
}